// Round 1
// baseline (455.505 us; speedup 1.0000x reference)
//
#include <hip/hip_runtime.h>
#include <cstdint>
#include <cstddef>

#define B_ 32
#define L_ 512
#define HP_ 192
#define N_ 512
#define E_ 128
#define Z_ 64

// ---------------- threefry2x32 (JAX-compatible) ----------------
__host__ __device__ __forceinline__ uint32_t rotl32(uint32_t v, int r) {
    return (v << r) | (v >> (32 - r));
}

__host__ __device__ __forceinline__ void tf2x32(uint32_t k0, uint32_t k1,
                                                uint32_t c0, uint32_t c1,
                                                uint32_t& o0, uint32_t& o1) {
    uint32_t ks2 = k0 ^ k1 ^ 0x1BD11BDAu;
    uint32_t x0 = c0 + k0, x1 = c1 + k1;
    x0 += x1; x1 = rotl32(x1, 13); x1 ^= x0;
    x0 += x1; x1 = rotl32(x1, 15); x1 ^= x0;
    x0 += x1; x1 = rotl32(x1, 26); x1 ^= x0;
    x0 += x1; x1 = rotl32(x1, 6);  x1 ^= x0;
    x0 += k1; x1 += ks2 + 1u;
    x0 += x1; x1 = rotl32(x1, 17); x1 ^= x0;
    x0 += x1; x1 = rotl32(x1, 29); x1 ^= x0;
    x0 += x1; x1 = rotl32(x1, 16); x1 ^= x0;
    x0 += x1; x1 = rotl32(x1, 24); x1 ^= x0;
    x0 += ks2; x1 += k0 + 2u;
    x0 += x1; x1 = rotl32(x1, 13); x1 ^= x0;
    x0 += x1; x1 = rotl32(x1, 15); x1 ^= x0;
    x0 += x1; x1 = rotl32(x1, 26); x1 ^= x0;
    x0 += x1; x1 = rotl32(x1, 6);  x1 ^= x0;
    x0 += k0; x1 += k1 + 3u;
    x0 += x1; x1 = rotl32(x1, 17); x1 ^= x0;
    x0 += x1; x1 = rotl32(x1, 29); x1 ^= x0;
    x0 += x1; x1 = rotl32(x1, 16); x1 ^= x0;
    x0 += x1; x1 = rotl32(x1, 24); x1 ^= x0;
    x0 += k1; x1 += ks2 + 4u;
    x0 += x1; x1 = rotl32(x1, 13); x1 ^= x0;
    x0 += x1; x1 = rotl32(x1, 15); x1 ^= x0;
    x0 += x1; x1 = rotl32(x1, 26); x1 ^= x0;
    x0 += x1; x1 = rotl32(x1, 6);  x1 ^= x0;
    x0 += ks2; x1 += k0 + 5u;
    o0 = x0; o1 = x1;
}

// XLA ErfInv32 (Giles polynomial)
__device__ __forceinline__ float erfinv_f(float x) {
    float w = -log1pf(-x * x);
    float p;
    if (w < 5.0f) {
        w = w - 2.5f;
        p = 2.81022636e-08f;
        p = fmaf(p, w, 3.43273939e-07f);
        p = fmaf(p, w, -3.5233877e-06f);
        p = fmaf(p, w, -4.39150654e-06f);
        p = fmaf(p, w, 0.00021858087f);
        p = fmaf(p, w, -0.00125372503f);
        p = fmaf(p, w, -0.00417768164f);
        p = fmaf(p, w, 0.246640727f);
        p = fmaf(p, w, 1.50140941f);
    } else {
        w = sqrtf(w) - 3.0f;
        p = -0.000200214257f;
        p = fmaf(p, w, 0.000100950558f);
        p = fmaf(p, w, 0.00134934322f);
        p = fmaf(p, w, -0.00367342844f);
        p = fmaf(p, w, 0.00573950773f);
        p = fmaf(p, w, -0.0076224613f);
        p = fmaf(p, w, 0.00943887047f);
        p = fmaf(p, w, 1.00167406f);
        p = fmaf(p, w, 2.83297682f);
    }
    return p * x;
}

// jax.random.normal: u = uniform(lo=nextafter(-1,0), hi=1); sqrt(2)*erfinv(u)
__device__ __forceinline__ float bits_to_normal(uint32_t bits) {
    float f = __uint_as_float((bits >> 9) | 0x3f800000u) - 1.0f;  // [0,1)
    const float lo = -0.99999994f;
    float u = fmaxf(lo, f * 2.0f + lo);   // hi-lo rounds to exactly 2.0f
    return 1.41421354f * erfinv_f(u);
}

// ---------------- K1: t0 = time_x @ time_W + time_b  [B*L, E] ----------------
__global__ void k_time_embed(const float* __restrict__ tx, const float* __restrict__ tW,
                             const float* __restrict__ tb, float* __restrict__ t0) {
    int row = blockIdx.x;
    int e = threadIdx.x;
    __shared__ float s[8];
    if (e < 7) s[e] = tx[row * 7 + e];
    __syncthreads();
    float acc = tb[e];
#pragma unroll
    for (int k = 0; k < 7; ++k) acc = fmaf(s[k], tW[k * E_ + e], acc);
    t0[(size_t)row * E_ + e] = acc;
}

// ---------------- K_colsum: csum[z] = sum_e W[e,z] for mu_ht_W / var_ht_W ----
__global__ void k_colsum(const float* __restrict__ mW, const float* __restrict__ vW,
                         float* __restrict__ csum) {
    int t = threadIdx.x;  // 128
    const float* W = (t < 64) ? mW : vW;
    int zc = t & 63;
    float s = 0.0f;
    for (int e = 0; e < E_; ++e) s += W[e * Z_ + zc];
    csum[t] = s;
}

// ---------------- K2: fused gate (t) + series (h) GEMMs + h_hat -------------
// t[b,n,e]  = sum_l gate_W[l,n]  * t0[b,l,e]     + gate_b[n]
// h[b,n,e]  = sum_l batch_x[b,l,n] * ser_W[l,e]  + ser_b[e]
// hh = t + h
__global__ __launch_bounds__(256) void k_gate_series(
    const float* __restrict__ t0, const float* __restrict__ gW, const float* __restrict__ gb,
    const float* __restrict__ bx, const float* __restrict__ sW, const float* __restrict__ sb,
    float* __restrict__ t, float* __restrict__ h, float* __restrict__ hh) {
    __shared__ __align__(16) float sG[16][64];
    __shared__ __align__(16) float sX[16][64];
    __shared__ __align__(16) float sT0[16][64];
    __shared__ __align__(16) float sS[16][64];
    int b = blockIdx.z, n0 = blockIdx.x * 64, e0 = blockIdx.y * 64;
    int tid = threadIdx.x, ty = tid >> 4, txi = tid & 15;
    float at[4][4] = {}, ah[4][4] = {};
    for (int l0 = 0; l0 < L_; l0 += 16) {
        int idx = tid * 4;
        int kk = idx >> 6, c = idx & 63;
        *(float4*)&sG[kk][c]  = *(const float4*)&gW[(size_t)(l0 + kk) * N_ + n0 + c];
        *(float4*)&sX[kk][c]  = *(const float4*)&bx[((size_t)b * L_ + l0 + kk) * N_ + n0 + c];
        *(float4*)&sT0[kk][c] = *(const float4*)&t0[((size_t)b * L_ + l0 + kk) * E_ + e0 + c];
        *(float4*)&sS[kk][c]  = *(const float4*)&sW[(size_t)(l0 + kk) * E_ + e0 + c];
        __syncthreads();
#pragma unroll
        for (int k = 0; k < 16; ++k) {
            float4 g4 = *(const float4*)&sG[k][ty * 4];
            float4 x4 = *(const float4*)&sX[k][ty * 4];
            float4 bt4 = *(const float4*)&sT0[k][txi * 4];
            float4 bs4 = *(const float4*)&sS[k][txi * 4];
            float ag[4] = {g4.x, g4.y, g4.z, g4.w};
            float ax[4] = {x4.x, x4.y, x4.z, x4.w};
            float bt[4] = {bt4.x, bt4.y, bt4.z, bt4.w};
            float bs[4] = {bs4.x, bs4.y, bs4.z, bs4.w};
#pragma unroll
            for (int i = 0; i < 4; ++i)
#pragma unroll
                for (int j = 0; j < 4; ++j) {
                    at[i][j] = fmaf(ag[i], bt[j], at[i][j]);
                    ah[i][j] = fmaf(ax[i], bs[j], ah[i][j]);
                }
        }
        __syncthreads();
    }
#pragma unroll
    for (int i = 0; i < 4; ++i) {
        int n = n0 + ty * 4 + i;
        float gbn = gb[n];
        size_t base = ((size_t)b * N_ + n) * E_ + e0 + txi * 4;
        float4 tv, hv, hhv;
        float* ptv = (float*)&tv; float* phv = (float*)&hv; float* phh = (float*)&hhv;
#pragma unroll
        for (int j = 0; j < 4; ++j) {
            int e = e0 + txi * 4 + j;
            float tval = at[i][j] + gbn;
            float hval = ah[i][j] + sb[e];
            ptv[j] = tval; phv[j] = hval; phh[j] = tval + hval;
        }
        *(float4*)&t[base] = tv;
        *(float4*)&h[base] = hv;
        *(float4*)&hh[base] = hhv;
    }
}

// ---------------- K3a: dual projection from t -> mu_t, var_t ----------------
__global__ __launch_bounds__(256) void k_proj_t(
    const float* __restrict__ A,
    const float* __restrict__ Wm, const float* __restrict__ bm,
    const float* __restrict__ Wv, const float* __restrict__ bv,
    float* __restrict__ Om, float* __restrict__ Ov) {
    __shared__ float sA[64][17];
    __shared__ __align__(16) float sM[16][64];
    __shared__ __align__(16) float sV[16][64];
    int r0 = blockIdx.x * 64;
    int tid = threadIdx.x, ty = tid >> 4, txi = tid & 15;
    float am[4][4] = {}, av[4][4] = {};
    for (int k0 = 0; k0 < E_; k0 += 16) {
        int idx = tid * 4;
        {
            int rr = idx >> 4, kb = idx & 15;
            float4 v = *(const float4*)&A[((size_t)(r0 + rr)) * E_ + k0 + kb];
            sA[rr][kb] = v.x; sA[rr][kb + 1] = v.y; sA[rr][kb + 2] = v.z; sA[rr][kb + 3] = v.w;
        }
        {
            int kk = idx >> 6, c = idx & 63;
            *(float4*)&sM[kk][c] = *(const float4*)&Wm[(size_t)(k0 + kk) * Z_ + c];
            *(float4*)&sV[kk][c] = *(const float4*)&Wv[(size_t)(k0 + kk) * Z_ + c];
        }
        __syncthreads();
#pragma unroll
        for (int k = 0; k < 16; ++k) {
            float a_[4];
#pragma unroll
            for (int i = 0; i < 4; ++i) a_[i] = sA[ty * 4 + i][k];
            float4 wm4 = *(const float4*)&sM[k][txi * 4];
            float4 wv4 = *(const float4*)&sV[k][txi * 4];
            float wm[4] = {wm4.x, wm4.y, wm4.z, wm4.w};
            float wv[4] = {wv4.x, wv4.y, wv4.z, wv4.w};
#pragma unroll
            for (int i = 0; i < 4; ++i)
#pragma unroll
                for (int j = 0; j < 4; ++j) {
                    am[i][j] = fmaf(a_[i], wm[j], am[i][j]);
                    av[i][j] = fmaf(a_[i], wv[j], av[i][j]);
                }
        }
        __syncthreads();
    }
#pragma unroll
    for (int i = 0; i < 4; ++i) {
        int r = r0 + ty * 4 + i;
        size_t base = (size_t)r * Z_ + txi * 4;
        float4 m4, v4; float* pm = (float*)&m4; float* pv = (float*)&v4;
#pragma unroll
        for (int j = 0; j < 4; ++j) {
            int zc = txi * 4 + j;
            pm[j] = am[i][j] + bm[zc];
            pv[j] = av[i][j] + bv[zc];
        }
        *(float4*)&Om[base] = m4;
        *(float4*)&Ov[base] = v4;
    }
}

// ---------------- K3b: quad projection from h_hat ---------------------------
// mu_h = hh@Wmh + bmh ; var_h = hh@Wvh + bvh
// mu_ht = w0*(hh@Wmt) + b0*csum_m + bmt ; var_ht likewise (h_tilde = w0*hh + b0)
__global__ __launch_bounds__(256) void k_proj_h(
    const float* __restrict__ A,
    const float* __restrict__ Wmh, const float* __restrict__ bmh,
    const float* __restrict__ Wvh, const float* __restrict__ bvh,
    const float* __restrict__ Wmt, const float* __restrict__ bmt,
    const float* __restrict__ Wvt, const float* __restrict__ bvt,
    const float* __restrict__ mlpW, const float* __restrict__ mlpb,
    const float* __restrict__ csum,
    float* __restrict__ Omh, float* __restrict__ Ovh,
    float* __restrict__ Omt, float* __restrict__ Ovt) {
    __shared__ float sA[64][17];
    __shared__ __align__(16) float s1[16][64];
    __shared__ __align__(16) float s2[16][64];
    __shared__ __align__(16) float s3[16][64];
    __shared__ __align__(16) float s4[16][64];
    int r0 = blockIdx.x * 64;
    int tid = threadIdx.x, ty = tid >> 4, txi = tid & 15;
    float a1[4][4] = {}, a2[4][4] = {}, a3[4][4] = {}, a4[4][4] = {};
    for (int k0 = 0; k0 < E_; k0 += 16) {
        int idx = tid * 4;
        {
            int rr = idx >> 4, kb = idx & 15;
            float4 v = *(const float4*)&A[((size_t)(r0 + rr)) * E_ + k0 + kb];
            sA[rr][kb] = v.x; sA[rr][kb + 1] = v.y; sA[rr][kb + 2] = v.z; sA[rr][kb + 3] = v.w;
        }
        {
            int kk = idx >> 6, c = idx & 63;
            *(float4*)&s1[kk][c] = *(const float4*)&Wmh[(size_t)(k0 + kk) * Z_ + c];
            *(float4*)&s2[kk][c] = *(const float4*)&Wvh[(size_t)(k0 + kk) * Z_ + c];
            *(float4*)&s3[kk][c] = *(const float4*)&Wmt[(size_t)(k0 + kk) * Z_ + c];
            *(float4*)&s4[kk][c] = *(const float4*)&Wvt[(size_t)(k0 + kk) * Z_ + c];
        }
        __syncthreads();
#pragma unroll
        for (int k = 0; k < 16; ++k) {
            float a_[4];
#pragma unroll
            for (int i = 0; i < 4; ++i) a_[i] = sA[ty * 4 + i][k];
            float4 w1 = *(const float4*)&s1[k][txi * 4];
            float4 w2 = *(const float4*)&s2[k][txi * 4];
            float4 w3 = *(const float4*)&s3[k][txi * 4];
            float4 w4 = *(const float4*)&s4[k][txi * 4];
            float p1[4] = {w1.x, w1.y, w1.z, w1.w};
            float p2[4] = {w2.x, w2.y, w2.z, w2.w};
            float p3[4] = {w3.x, w3.y, w3.z, w3.w};
            float p4[4] = {w4.x, w4.y, w4.z, w4.w};
#pragma unroll
            for (int i = 0; i < 4; ++i)
#pragma unroll
                for (int j = 0; j < 4; ++j) {
                    a1[i][j] = fmaf(a_[i], p1[j], a1[i][j]);
                    a2[i][j] = fmaf(a_[i], p2[j], a2[i][j]);
                    a3[i][j] = fmaf(a_[i], p3[j], a3[i][j]);
                    a4[i][j] = fmaf(a_[i], p4[j], a4[i][j]);
                }
        }
        __syncthreads();
    }
    float w0 = mlpW[0], b0 = mlpb[0];
#pragma unroll
    for (int i = 0; i < 4; ++i) {
        int r = r0 + ty * 4 + i;
        size_t base = (size_t)r * Z_ + txi * 4;
        float4 o1, o2, o3, o4;
        float* q1 = (float*)&o1; float* q2 = (float*)&o2;
        float* q3 = (float*)&o3; float* q4 = (float*)&o4;
#pragma unroll
        for (int j = 0; j < 4; ++j) {
            int zc = txi * 4 + j;
            q1[j] = a1[i][j] + bmh[zc];
            q2[j] = a2[i][j] + bvh[zc];
            q3[j] = fmaf(w0, a3[i][j], fmaf(b0, csum[zc], bmt[zc]));
            q4[j] = fmaf(w0, a4[i][j], fmaf(b0, csum[64 + zc], bvt[zc]));
        }
        *(float4*)&Omh[base] = o1;
        *(float4*)&Ovh[base] = o2;
        *(float4*)&Omt[base] = o3;
        *(float4*)&Ovt[base] = o4;
    }
}

// ---------------- K4: reparam + blend (threefry normals) --------------------
__global__ void k_reparam(const float* __restrict__ muh, const float* __restrict__ vah,
                          const float* __restrict__ muht, const float* __restrict__ vaht,
                          float* __restrict__ z, float* __restrict__ omu, float* __restrict__ ova,
                          uint32_t k1a, uint32_t k1b, uint32_t k2a, uint32_t k2b) {
    int i = blockIdx.x * 256 + threadIdx.x;
    uint32_t a0, a1;
    tf2x32(k1a, k1b, 0u, (uint32_t)i, a0, a1);
    float e1 = bits_to_normal(a0 ^ a1);
    tf2x32(k2a, k2b, 0u, (uint32_t)i, a0, a1);
    float e2 = bits_to_normal(a0 ^ a1);
    float m1 = muh[i], v1 = vah[i], m2 = muht[i], v2 = vaht[i];
    float zh = m1 + e1 * expf(0.5f * v1);
    float zt = m2 + e2 * expf(0.5f * v2);
    z[i] = 0.5f * (zh + zt);
    omu[i] = 0.5f * (m1 + m2);
    ova[i] = 0.5f * (v1 + v2);
}

// ---------------- K5: zt = z@inf_W+ib ; mu_zt, var_zt -----------------------
__global__ __launch_bounds__(256) void k_zt(
    const float* __restrict__ z,
    const float* __restrict__ iW, const float* __restrict__ ib,
    const float* __restrict__ mW, const float* __restrict__ mb,
    const float* __restrict__ vW, const float* __restrict__ vb,
    float* __restrict__ Om, float* __restrict__ Ov) {
    __shared__ float sZ[64][69];
    __shared__ float sZT[64][69];
    __shared__ __align__(16) float sWa[16][64];
    __shared__ __align__(16) float sWb[16][64];
    int r0 = blockIdx.x * 64;
    int tid = threadIdx.x, ty = tid >> 4, txi = tid & 15;
    for (int i = tid * 4; i < 4096; i += 1024) {
        int rr = i >> 6, c = i & 63;
        float4 v = *(const float4*)&z[((size_t)(r0 + rr)) * Z_ + c];
        sZ[rr][c] = v.x; sZ[rr][c + 1] = v.y; sZ[rr][c + 2] = v.z; sZ[rr][c + 3] = v.w;
    }
    float acc[4][4] = {};
    for (int k0 = 0; k0 < Z_; k0 += 16) {
        int idx = tid * 4;
        int kk = idx >> 6, c = idx & 63;
        *(float4*)&sWa[kk][c] = *(const float4*)&iW[(size_t)(k0 + kk) * Z_ + c];
        __syncthreads();
#pragma unroll
        for (int k = 0; k < 16; ++k) {
            float a_[4];
#pragma unroll
            for (int i = 0; i < 4; ++i) a_[i] = sZ[ty * 4 + i][k0 + k];
            float4 w4 = *(const float4*)&sWa[k][txi * 4];
            float w[4] = {w4.x, w4.y, w4.z, w4.w};
#pragma unroll
            for (int i = 0; i < 4; ++i)
#pragma unroll
                for (int j = 0; j < 4; ++j) acc[i][j] = fmaf(a_[i], w[j], acc[i][j]);
        }
        __syncthreads();
    }
#pragma unroll
    for (int i = 0; i < 4; ++i)
#pragma unroll
        for (int j = 0; j < 4; ++j)
            sZT[ty * 4 + i][txi * 4 + j] = acc[i][j] + ib[txi * 4 + j];
    __syncthreads();
    float am[4][4] = {}, av[4][4] = {};
    for (int k0 = 0; k0 < Z_; k0 += 16) {
        int idx = tid * 4;
        int kk = idx >> 6, c = idx & 63;
        *(float4*)&sWa[kk][c] = *(const float4*)&mW[(size_t)(k0 + kk) * Z_ + c];
        *(float4*)&sWb[kk][c] = *(const float4*)&vW[(size_t)(k0 + kk) * Z_ + c];
        __syncthreads();
#pragma unroll
        for (int k = 0; k < 16; ++k) {
            float a_[4];
#pragma unroll
            for (int i = 0; i < 4; ++i) a_[i] = sZT[ty * 4 + i][k0 + k];
            float4 wm4 = *(const float4*)&sWa[k][txi * 4];
            float4 wv4 = *(const float4*)&sWb[k][txi * 4];
            float wm[4] = {wm4.x, wm4.y, wm4.z, wm4.w};
            float wv[4] = {wv4.x, wv4.y, wv4.z, wv4.w};
#pragma unroll
            for (int i = 0; i < 4; ++i)
#pragma unroll
                for (int j = 0; j < 4; ++j) {
                    am[i][j] = fmaf(a_[i], wm[j], am[i][j]);
                    av[i][j] = fmaf(a_[i], wv[j], av[i][j]);
                }
        }
        __syncthreads();
    }
#pragma unroll
    for (int i = 0; i < 4; ++i) {
        int r = r0 + ty * 4 + i;
        size_t base = (size_t)r * Z_ + txi * 4;
        float4 m4, v4; float* pm = (float*)&m4; float* pv = (float*)&v4;
#pragma unroll
        for (int j = 0; j < 4; ++j) {
            int zc = txi * 4 + j;
            pm[j] = am[i][j] + mb[zc];
            pv[j] = av[i][j] + vb[zc];
        }
        *(float4*)&Om[base] = m4;
        *(float4*)&Ov[base] = v4;
    }
}

// ---------------- K6: head: out[b,d,n] = (leaky(z@W1+b1)+h) @ W2 + b2 -------
__global__ __launch_bounds__(256) void k_head(
    const float* __restrict__ z, const float* __restrict__ h,
    const float* __restrict__ W1, const float* __restrict__ b1,
    const float* __restrict__ W2, const float* __restrict__ b2,
    float* __restrict__ out, int Dout) {
    __shared__ __align__(16) float smem[14976];
    float* tmpS = smem;                  // [64][133]
    float* sZ = smem + 8512;             // [64][69]
    float* sW = smem + 8512 + 4416;      // [16][128] / [16][64]
    int b = blockIdx.y;
    int n0 = blockIdx.x * 64;
    int tid = threadIdx.x, ty = tid >> 4, txi = tid & 15;
    for (int i = tid * 4; i < 4096; i += 1024) {
        int rr = i >> 6, c = i & 63;
        float4 v = *(const float4*)&z[((size_t)b * N_ + n0 + rr) * Z_ + c];
        sZ[rr * 69 + c] = v.x; sZ[rr * 69 + c + 1] = v.y;
        sZ[rr * 69 + c + 2] = v.z; sZ[rr * 69 + c + 3] = v.w;
    }
    float acc1[4][8] = {};
    for (int k0 = 0; k0 < Z_; k0 += 16) {
        for (int i = tid * 4; i < 2048; i += 1024) {
            int kk = i >> 7, c = i & 127;
            *(float4*)&sW[kk * 128 + c] = *(const float4*)&W1[(size_t)(k0 + kk) * E_ + c];
        }
        __syncthreads();
#pragma unroll
        for (int k = 0; k < 16; ++k) {
            float a_[4];
#pragma unroll
            for (int i = 0; i < 4; ++i) a_[i] = sZ[(ty * 4 + i) * 69 + k0 + k];
            float4 wA4 = *(const float4*)&sW[k * 128 + txi * 4];
            float4 wB4 = *(const float4*)&sW[k * 128 + 64 + txi * 4];
            float wA[4] = {wA4.x, wA4.y, wA4.z, wA4.w};
            float wB[4] = {wB4.x, wB4.y, wB4.z, wB4.w};
#pragma unroll
            for (int i = 0; i < 4; ++i)
#pragma unroll
                for (int j = 0; j < 4; ++j) {
                    acc1[i][j] = fmaf(a_[i], wA[j], acc1[i][j]);
                    acc1[i][4 + j] = fmaf(a_[i], wB[j], acc1[i][4 + j]);
                }
        }
        __syncthreads();
    }
    // epilogue phase 1: tmp = leaky(acc1 + b1) + h
#pragma unroll
    for (int i = 0; i < 4; ++i) {
        int n = n0 + ty * 4 + i;
        const float* hrow = &h[((size_t)b * N_ + n) * E_];
#pragma unroll
        for (int jh = 0; jh < 2; ++jh)
#pragma unroll
            for (int jj = 0; jj < 4; ++jj) {
                int e = jh * 64 + txi * 4 + jj;
                float v = acc1[i][jh * 4 + jj] + b1[e];
                v = (v > 0.0f) ? v : 0.01f * v;
                v += hrow[e];
                tmpS[(ty * 4 + i) * 133 + e] = v;
            }
    }
    __syncthreads();
    // phase 2: out tiles of 64 columns
    for (int d0 = 0; d0 < Dout; d0 += 64) {
        float acc2[4][4] = {};
        for (int k0 = 0; k0 < E_; k0 += 16) {
            {
                int i = tid * 4;
                int kk = i >> 6, c = i & 63;
                *(float4*)&sW[kk * 64 + c] = *(const float4*)&W2[(size_t)(k0 + kk) * Dout + d0 + c];
            }
            __syncthreads();
#pragma unroll
            for (int k = 0; k < 16; ++k) {
                float a_[4];
#pragma unroll
                for (int i = 0; i < 4; ++i) a_[i] = tmpS[(txi * 4 + i) * 133 + k0 + k];
                float4 w4 = *(const float4*)&sW[k * 64 + ty * 4];
                float w[4] = {w4.x, w4.y, w4.z, w4.w};
#pragma unroll
                for (int i = 0; i < 4; ++i)
#pragma unroll
                    for (int j = 0; j < 4; ++j) acc2[i][j] = fmaf(a_[i], w[j], acc2[i][j]);
            }
            __syncthreads();
        }
#pragma unroll
        for (int j = 0; j < 4; ++j) {
            int d = d0 + ty * 4 + j;
            float bb = b2[d];
            float4 vv;
            float* pv = (float*)&vv;
            pv[0] = acc2[0][j] + bb; pv[1] = acc2[1][j] + bb;
            pv[2] = acc2[2][j] + bb; pv[3] = acc2[3][j] + bb;
            *(float4*)&out[((size_t)b * Dout + d) * N_ + n0 + txi * 4] = vv;
        }
    }
}

// ---------------- launch ----------------------------------------------------
extern "C" void kernel_launch(void* const* d_in, const int* in_sizes, int n_in,
                              void* d_out, int out_size, void* d_ws, size_t ws_size,
                              hipStream_t stream) {
    (void)in_sizes; (void)n_in; (void)out_size; (void)ws_size;
    const float* batch_x = (const float*)d_in[0];
    const float* time_x  = (const float*)d_in[1];
    const float* time_W  = (const float*)d_in[2];
    const float* time_b  = (const float*)d_in[3];
    const float* gate_W  = (const float*)d_in[4];
    const float* gate_b  = (const float*)d_in[5];
    const float* mu_t_W  = (const float*)d_in[6];
    const float* mu_t_b  = (const float*)d_in[7];
    const float* var_t_W = (const float*)d_in[8];
    const float* var_t_b = (const float*)d_in[9];
    const float* ser_W   = (const float*)d_in[10];
    const float* ser_b   = (const float*)d_in[11];
    const float* mu_h_W  = (const float*)d_in[12];
    const float* mu_h_b  = (const float*)d_in[13];
    const float* var_h_W = (const float*)d_in[14];
    const float* var_h_b = (const float*)d_in[15];
    const float* mlp_W   = (const float*)d_in[18];
    const float* mlp_b   = (const float*)d_in[19];
    const float* mu_ht_W = (const float*)d_in[20];
    const float* mu_ht_b = (const float*)d_in[21];
    const float* var_ht_W = (const float*)d_in[22];
    const float* var_ht_b = (const float*)d_in[23];
    const float* inf_W   = (const float*)d_in[24];
    const float* inf_b   = (const float*)d_in[25];
    const float* mu_zt_W = (const float*)d_in[26];
    const float* mu_zt_b = (const float*)d_in[27];
    const float* var_zt_W = (const float*)d_in[28];
    const float* var_zt_b = (const float*)d_in[29];
    const float* fW1 = (const float*)d_in[30];
    const float* fb1 = (const float*)d_in[31];
    const float* fW2 = (const float*)d_in[32];
    const float* fb2 = (const float*)d_in[33];
    const float* rW1 = (const float*)d_in[34];
    const float* rb1 = (const float*)d_in[35];
    const float* rW2 = (const float*)d_in[36];
    const float* rb2 = (const float*)d_in[37];

    float* out = (float*)d_out;
    float* ws = (float*)d_ws;

    // ws layout (floats), with lifetime-based overlap:
    const size_t off_t0   = 0;         // [B*L*E] dead after k_gate_series
    const size_t off_muh  = 0;         // [B*N*Z]
    const size_t off_varh = 1048576;   // [B*N*Z]
    const size_t off_t    = 2097152;   // [B*N*E] dead after k_proj_t
    const size_t off_muht = 2097152;   // [B*N*Z]
    const size_t off_varht= 3145728;   // [B*N*Z]
    const size_t off_h    = 4194304;   // [B*N*E] live to the end
    const size_t off_hh   = 6291456;   // [B*N*E] dead after k_proj_h
    const size_t off_z    = 6291456;   // [B*N*Z]
    const size_t off_csum = 8388608;   // [128]

    // out layout (floats): x, y, mu_t, var_t, mu_zt, var_zt, mu_z, var_z
    float* o_x     = out;
    float* o_y     = out + 8388608;
    float* o_mu_t  = out + 11534336;
    float* o_var_t = out + 12582912;
    float* o_mu_zt = out + 13631488;
    float* o_var_zt= out + 14680064;
    float* o_mu_z  = out + 15728640;
    float* o_var_z = out + 16777216;

    // JAX key(42) -> split(3) (threefry_partitionable / foldlike split):
    // kz1 = threefry((0,42), (0,0)); kz2 = threefry((0,42), (0,1))
    uint32_t kz1a, kz1b, kz2a, kz2b;
    tf2x32(0u, 42u, 0u, 0u, kz1a, kz1b);
    tf2x32(0u, 42u, 0u, 1u, kz2a, kz2b);

    k_time_embed<<<B_ * L_, 128, 0, stream>>>(time_x, time_W, time_b, ws + off_t0);
    k_colsum<<<1, 128, 0, stream>>>(mu_ht_W, var_ht_W, ws + off_csum);
    k_gate_series<<<dim3(8, 2, B_), 256, 0, stream>>>(ws + off_t0, gate_W, gate_b,
                                                      batch_x, ser_W, ser_b,
                                                      ws + off_t, ws + off_h, ws + off_hh);
    k_proj_t<<<256, 256, 0, stream>>>(ws + off_t, mu_t_W, mu_t_b, var_t_W, var_t_b,
                                      o_mu_t, o_var_t);
    k_proj_h<<<256, 256, 0, stream>>>(ws + off_hh, mu_h_W, mu_h_b, var_h_W, var_h_b,
                                      mu_ht_W, mu_ht_b, var_ht_W, var_ht_b,
                                      mlp_W, mlp_b, ws + off_csum,
                                      ws + off_muh, ws + off_varh,
                                      ws + off_muht, ws + off_varht);
    k_reparam<<<4096, 256, 0, stream>>>(ws + off_muh, ws + off_varh,
                                        ws + off_muht, ws + off_varht,
                                        ws + off_z, o_mu_z, o_var_z,
                                        kz1a, kz1b, kz2a, kz2b);
    k_zt<<<256, 256, 0, stream>>>(ws + off_z, inf_W, inf_b, mu_zt_W, mu_zt_b,
                                  var_zt_W, var_zt_b, o_mu_zt, o_var_zt);
    k_head<<<dim3(8, B_), 256, 0, stream>>>(ws + off_z, ws + off_h, fW1, fb1, fW2, fb2,
                                            o_y, HP_);
    k_head<<<dim3(8, B_), 256, 0, stream>>>(ws + off_z, ws + off_h, rW1, rb1, rW2, rb2,
                                            o_x, L_);
}

// Round 2
// 361.104 us; speedup vs baseline: 1.2614x; 1.2614x over previous
//
#include <hip/hip_runtime.h>
#include <cstdint>
#include <cstddef>

#define B_ 32
#define L_ 512
#define HP_ 192
#define N_ 512
#define E_ 128
#define Z_ 64

// ---------------- threefry2x32 (JAX-compatible) ----------------
__host__ __device__ __forceinline__ uint32_t rotl32(uint32_t v, int r) {
    return (v << r) | (v >> (32 - r));
}

__host__ __device__ __forceinline__ void tf2x32(uint32_t k0, uint32_t k1,
                                                uint32_t c0, uint32_t c1,
                                                uint32_t& o0, uint32_t& o1) {
    uint32_t ks2 = k0 ^ k1 ^ 0x1BD11BDAu;
    uint32_t x0 = c0 + k0, x1 = c1 + k1;
    x0 += x1; x1 = rotl32(x1, 13); x1 ^= x0;
    x0 += x1; x1 = rotl32(x1, 15); x1 ^= x0;
    x0 += x1; x1 = rotl32(x1, 26); x1 ^= x0;
    x0 += x1; x1 = rotl32(x1, 6);  x1 ^= x0;
    x0 += k1; x1 += ks2 + 1u;
    x0 += x1; x1 = rotl32(x1, 17); x1 ^= x0;
    x0 += x1; x1 = rotl32(x1, 29); x1 ^= x0;
    x0 += x1; x1 = rotl32(x1, 16); x1 ^= x0;
    x0 += x1; x1 = rotl32(x1, 24); x1 ^= x0;
    x0 += ks2; x1 += k0 + 2u;
    x0 += x1; x1 = rotl32(x1, 13); x1 ^= x0;
    x0 += x1; x1 = rotl32(x1, 15); x1 ^= x0;
    x0 += x1; x1 = rotl32(x1, 26); x1 ^= x0;
    x0 += x1; x1 = rotl32(x1, 6);  x1 ^= x0;
    x0 += k0; x1 += k1 + 3u;
    x0 += x1; x1 = rotl32(x1, 17); x1 ^= x0;
    x0 += x1; x1 = rotl32(x1, 29); x1 ^= x0;
    x0 += x1; x1 = rotl32(x1, 16); x1 ^= x0;
    x0 += x1; x1 = rotl32(x1, 24); x1 ^= x0;
    x0 += k1; x1 += ks2 + 4u;
    x0 += x1; x1 = rotl32(x1, 13); x1 ^= x0;
    x0 += x1; x1 = rotl32(x1, 15); x1 ^= x0;
    x0 += x1; x1 = rotl32(x1, 26); x1 ^= x0;
    x0 += x1; x1 = rotl32(x1, 6);  x1 ^= x0;
    x0 += ks2; x1 += k0 + 5u;
    o0 = x0; o1 = x1;
}

// XLA ErfInv32 (Giles polynomial)
__device__ __forceinline__ float erfinv_f(float x) {
    float w = -log1pf(-x * x);
    float p;
    if (w < 5.0f) {
        w = w - 2.5f;
        p = 2.81022636e-08f;
        p = fmaf(p, w, 3.43273939e-07f);
        p = fmaf(p, w, -3.5233877e-06f);
        p = fmaf(p, w, -4.39150654e-06f);
        p = fmaf(p, w, 0.00021858087f);
        p = fmaf(p, w, -0.00125372503f);
        p = fmaf(p, w, -0.00417768164f);
        p = fmaf(p, w, 0.246640727f);
        p = fmaf(p, w, 1.50140941f);
    } else {
        w = sqrtf(w) - 3.0f;
        p = -0.000200214257f;
        p = fmaf(p, w, 0.000100950558f);
        p = fmaf(p, w, 0.00134934322f);
        p = fmaf(p, w, -0.00367342844f);
        p = fmaf(p, w, 0.00573950773f);
        p = fmaf(p, w, -0.0076224613f);
        p = fmaf(p, w, 0.00943887047f);
        p = fmaf(p, w, 1.00167406f);
        p = fmaf(p, w, 2.83297682f);
    }
    return p * x;
}

__device__ __forceinline__ float bits_to_normal(uint32_t bits) {
    float f = __uint_as_float((bits >> 9) | 0x3f800000u) - 1.0f;  // [0,1)
    const float lo = -0.99999994f;
    float u = fmaxf(lo, f * 2.0f + lo);
    return 1.41421354f * erfinv_f(u);
}

// ---------------- K1: t0 = time_x @ time_W + time_b  [B*L, E] ----------------
__global__ void k_time_embed(const float* __restrict__ tx, const float* __restrict__ tW,
                             const float* __restrict__ tb, float* __restrict__ t0) {
    int row = blockIdx.x;
    int e = threadIdx.x;
    __shared__ float s[8];
    if (e < 7) s[e] = tx[row * 7 + e];
    __syncthreads();
    float acc = tb[e];
#pragma unroll
    for (int k = 0; k < 7; ++k) acc = fmaf(s[k], tW[k * E_ + e], acc);
    t0[(size_t)row * E_ + e] = acc;
}

// ---------------- K_colsum -------------------------------------------------
__global__ void k_colsum(const float* __restrict__ mW, const float* __restrict__ vW,
                         float* __restrict__ csum) {
    int t = threadIdx.x;  // 128
    const float* W = (t < 64) ? mW : vW;
    int zc = t & 63;
    float s = 0.0f;
    for (int e = 0; e < E_; ++e) s += W[e * Z_ + zc];
    csum[t] = s;
}

// ---------------- K2: fused gate (t) + series (h) GEMMs + h_hat -------------
__global__ __launch_bounds__(256) void k_gate_series(
    const float* __restrict__ t0, const float* __restrict__ gW, const float* __restrict__ gb,
    const float* __restrict__ bx, const float* __restrict__ sW, const float* __restrict__ sb,
    float* __restrict__ t, float* __restrict__ h, float* __restrict__ hh) {
    __shared__ __align__(16) float sG[16][64];
    __shared__ __align__(16) float sX[16][64];
    __shared__ __align__(16) float sT0[16][64];
    __shared__ __align__(16) float sS[16][64];
    int b = blockIdx.z, n0 = blockIdx.x * 64, e0 = blockIdx.y * 64;
    int tid = threadIdx.x, ty = tid >> 4, txi = tid & 15;
    float at[4][4] = {}, ah[4][4] = {};
    for (int l0 = 0; l0 < L_; l0 += 16) {
        int idx = tid * 4;
        int kk = idx >> 6, c = idx & 63;
        *(float4*)&sG[kk][c]  = *(const float4*)&gW[(size_t)(l0 + kk) * N_ + n0 + c];
        *(float4*)&sX[kk][c]  = *(const float4*)&bx[((size_t)b * L_ + l0 + kk) * N_ + n0 + c];
        *(float4*)&sT0[kk][c] = *(const float4*)&t0[((size_t)b * L_ + l0 + kk) * E_ + e0 + c];
        *(float4*)&sS[kk][c]  = *(const float4*)&sW[(size_t)(l0 + kk) * E_ + e0 + c];
        __syncthreads();
#pragma unroll
        for (int k = 0; k < 16; ++k) {
            float4 g4 = *(const float4*)&sG[k][ty * 4];
            float4 x4 = *(const float4*)&sX[k][ty * 4];
            float4 bt4 = *(const float4*)&sT0[k][txi * 4];
            float4 bs4 = *(const float4*)&sS[k][txi * 4];
            float ag[4] = {g4.x, g4.y, g4.z, g4.w};
            float ax[4] = {x4.x, x4.y, x4.z, x4.w};
            float bt[4] = {bt4.x, bt4.y, bt4.z, bt4.w};
            float bs[4] = {bs4.x, bs4.y, bs4.z, bs4.w};
#pragma unroll
            for (int i = 0; i < 4; ++i)
#pragma unroll
                for (int j = 0; j < 4; ++j) {
                    at[i][j] = fmaf(ag[i], bt[j], at[i][j]);
                    ah[i][j] = fmaf(ax[i], bs[j], ah[i][j]);
                }
        }
        __syncthreads();
    }
#pragma unroll
    for (int i = 0; i < 4; ++i) {
        int n = n0 + ty * 4 + i;
        float gbn = gb[n];
        size_t base = ((size_t)b * N_ + n) * E_ + e0 + txi * 4;
        float4 tv, hv, hhv;
        float* ptv = (float*)&tv; float* phv = (float*)&hv; float* phh = (float*)&hhv;
#pragma unroll
        for (int j = 0; j < 4; ++j) {
            int e = e0 + txi * 4 + j;
            float tval = at[i][j] + gbn;
            float hval = ah[i][j] + sb[e];
            ptv[j] = tval; phv[j] = hval; phh[j] = tval + hval;
        }
        *(float4*)&t[base] = tv;
        *(float4*)&h[base] = hv;
        *(float4*)&hh[base] = hhv;
    }
}

// ---------------- K_mega: proj_t + proj_h + reparam + zt chain --------------
// Per 64-row tile (rows of B*N): everything is row-local.
__global__ __launch_bounds__(256) void k_mega(
    const float* __restrict__ T, const float* __restrict__ HH,
    const float* __restrict__ Wmt, const float* __restrict__ bmt_,
    const float* __restrict__ Wvt, const float* __restrict__ bvt_,
    const float* __restrict__ Wmh, const float* __restrict__ bmh,
    const float* __restrict__ Wvh, const float* __restrict__ bvh,
    const float* __restrict__ Wmht, const float* __restrict__ bmht,
    const float* __restrict__ Wvht, const float* __restrict__ bvht,
    const float* __restrict__ mlpW, const float* __restrict__ mlpb,
    const float* __restrict__ csum,
    const float* __restrict__ iW, const float* __restrict__ ib,
    const float* __restrict__ mzW, const float* __restrict__ mzb,
    const float* __restrict__ vzW, const float* __restrict__ vzb,
    float* __restrict__ Omt, float* __restrict__ Ovt,
    float* __restrict__ Omz, float* __restrict__ Ovz,
    float* __restrict__ Omzt, float* __restrict__ Ovzt,
    float* __restrict__ Zout,
    uint32_t k1a, uint32_t k1b, uint32_t k2a, uint32_t k2b) {
    __shared__ float sA[64][17];
    __shared__ __align__(16) float sW[4][16][64];
    __shared__ float sZ[64 * 65];
    __shared__ float sZT[64 * 65];
    int r0 = blockIdx.x * 64;
    int tid = threadIdx.x, ty = tid >> 4, txi = tid & 15;
    int idx = tid * 4;
    int arr = idx >> 4, akb = idx & 15;     // A staging: row, k-base
    int wkk = idx >> 6, wc = idx & 63;      // W staging: k-row, col

    // ---------- Phase A1: mu_t / var_t from T ----------
    {
        float am[4][4] = {}, av[4][4] = {};
        for (int k0 = 0; k0 < E_; k0 += 16) {
            {
                float4 v = *(const float4*)&T[((size_t)(r0 + arr)) * E_ + k0 + akb];
                sA[arr][akb] = v.x; sA[arr][akb + 1] = v.y; sA[arr][akb + 2] = v.z; sA[arr][akb + 3] = v.w;
                *(float4*)&sW[0][wkk][wc] = *(const float4*)&Wmt[(size_t)(k0 + wkk) * Z_ + wc];
                *(float4*)&sW[1][wkk][wc] = *(const float4*)&Wvt[(size_t)(k0 + wkk) * Z_ + wc];
            }
            __syncthreads();
#pragma unroll
            for (int k = 0; k < 16; ++k) {
                float a_[4];
#pragma unroll
                for (int i = 0; i < 4; ++i) a_[i] = sA[ty * 4 + i][k];
                float4 wm4 = *(const float4*)&sW[0][k][txi * 4];
                float4 wv4 = *(const float4*)&sW[1][k][txi * 4];
                float wm[4] = {wm4.x, wm4.y, wm4.z, wm4.w};
                float wv[4] = {wv4.x, wv4.y, wv4.z, wv4.w};
#pragma unroll
                for (int i = 0; i < 4; ++i)
#pragma unroll
                    for (int j = 0; j < 4; ++j) {
                        am[i][j] = fmaf(a_[i], wm[j], am[i][j]);
                        av[i][j] = fmaf(a_[i], wv[j], av[i][j]);
                    }
            }
            __syncthreads();
        }
#pragma unroll
        for (int i = 0; i < 4; ++i) {
            int r = r0 + ty * 4 + i;
            size_t base = (size_t)r * Z_ + txi * 4;
            float4 m4, v4; float* pm = (float*)&m4; float* pv = (float*)&v4;
#pragma unroll
            for (int j = 0; j < 4; ++j) {
                int zc = txi * 4 + j;
                pm[j] = am[i][j] + bmt_[zc];
                pv[j] = av[i][j] + bvt_[zc];
            }
            *(float4*)&Omt[base] = m4;
            *(float4*)&Ovt[base] = v4;
        }
    }

    // ---------- Phase A2: 4 GEMMs from HH ----------
    float a1[4][4] = {}, a2[4][4] = {}, a3[4][4] = {}, a4[4][4] = {};
    for (int k0 = 0; k0 < E_; k0 += 16) {
        {
            float4 v = *(const float4*)&HH[((size_t)(r0 + arr)) * E_ + k0 + akb];
            sA[arr][akb] = v.x; sA[arr][akb + 1] = v.y; sA[arr][akb + 2] = v.z; sA[arr][akb + 3] = v.w;
            *(float4*)&sW[0][wkk][wc] = *(const float4*)&Wmh[(size_t)(k0 + wkk) * Z_ + wc];
            *(float4*)&sW[1][wkk][wc] = *(const float4*)&Wvh[(size_t)(k0 + wkk) * Z_ + wc];
            *(float4*)&sW[2][wkk][wc] = *(const float4*)&Wmht[(size_t)(k0 + wkk) * Z_ + wc];
            *(float4*)&sW[3][wkk][wc] = *(const float4*)&Wvht[(size_t)(k0 + wkk) * Z_ + wc];
        }
        __syncthreads();
#pragma unroll
        for (int k = 0; k < 16; ++k) {
            float a_[4];
#pragma unroll
            for (int i = 0; i < 4; ++i) a_[i] = sA[ty * 4 + i][k];
            float4 w1 = *(const float4*)&sW[0][k][txi * 4];
            float4 w2 = *(const float4*)&sW[1][k][txi * 4];
            float4 w3 = *(const float4*)&sW[2][k][txi * 4];
            float4 w4 = *(const float4*)&sW[3][k][txi * 4];
            float p1[4] = {w1.x, w1.y, w1.z, w1.w};
            float p2[4] = {w2.x, w2.y, w2.z, w2.w};
            float p3[4] = {w3.x, w3.y, w3.z, w3.w};
            float p4[4] = {w4.x, w4.y, w4.z, w4.w};
#pragma unroll
            for (int i = 0; i < 4; ++i)
#pragma unroll
                for (int j = 0; j < 4; ++j) {
                    a1[i][j] = fmaf(a_[i], p1[j], a1[i][j]);
                    a2[i][j] = fmaf(a_[i], p2[j], a2[i][j]);
                    a3[i][j] = fmaf(a_[i], p3[j], a3[i][j]);
                    a4[i][j] = fmaf(a_[i], p4[j], a4[i][j]);
                }
        }
        __syncthreads();
    }

    // ---------- Phase B: reparam + blend (in-register) ----------
    {
        float w0 = mlpW[0], b0 = mlpb[0];
#pragma unroll
        for (int i = 0; i < 4; ++i) {
            int row = ty * 4 + i;
            int r = r0 + row;
            size_t base = (size_t)r * Z_ + txi * 4;
            float4 zf, mf, vf;
            float* pz = (float*)&zf; float* pm = (float*)&mf; float* pv = (float*)&vf;
#pragma unroll
            for (int j = 0; j < 4; ++j) {
                int zc = txi * 4 + j;
                float m1 = a1[i][j] + bmh[zc];
                float v1 = a2[i][j] + bvh[zc];
                float m2 = fmaf(w0, a3[i][j], fmaf(b0, csum[zc], bmht[zc]));
                float v2 = fmaf(w0, a4[i][j], fmaf(b0, csum[64 + zc], bvht[zc]));
                uint32_t flat = (uint32_t)r * 64u + (uint32_t)zc;
                uint32_t o0, o1;
                tf2x32(k1a, k1b, 0u, flat, o0, o1);
                float e1 = bits_to_normal(o0 ^ o1);
                tf2x32(k2a, k2b, 0u, flat, o0, o1);
                float e2 = bits_to_normal(o0 ^ o1);
                float zh = m1 + e1 * expf(0.5f * v1);
                float zt = m2 + e2 * expf(0.5f * v2);
                float zv = 0.5f * (zh + zt);
                pz[j] = zv; pm[j] = 0.5f * (m1 + m2); pv[j] = 0.5f * (v1 + v2);
                sZ[row * 65 + zc] = zv;
            }
            *(float4*)&Zout[base] = zf;
            *(float4*)&Omz[base] = mf;
            *(float4*)&Ovz[base] = vf;
        }
    }

    // ---------- Phase C1: zt = z @ inf_W + ib  (into sZT) ----------
    {
        float ac[4][4] = {};
        for (int k0 = 0; k0 < Z_; k0 += 16) {
            *(float4*)&sW[0][wkk][wc] = *(const float4*)&iW[(size_t)(k0 + wkk) * Z_ + wc];
            __syncthreads();
#pragma unroll
            for (int k = 0; k < 16; ++k) {
                float a_[4];
#pragma unroll
                for (int i = 0; i < 4; ++i) a_[i] = sZ[(ty * 4 + i) * 65 + k0 + k];
                float4 w4 = *(const float4*)&sW[0][k][txi * 4];
                float w[4] = {w4.x, w4.y, w4.z, w4.w};
#pragma unroll
                for (int i = 0; i < 4; ++i)
#pragma unroll
                    for (int j = 0; j < 4; ++j) ac[i][j] = fmaf(a_[i], w[j], ac[i][j]);
            }
            __syncthreads();
        }
#pragma unroll
        for (int i = 0; i < 4; ++i)
#pragma unroll
            for (int j = 0; j < 4; ++j)
                sZT[(ty * 4 + i) * 65 + txi * 4 + j] = ac[i][j] + ib[txi * 4 + j];
        __syncthreads();
    }

    // ---------- Phase C2: mu_zt / var_zt from sZT ----------
    {
        float cm[4][4] = {}, cv[4][4] = {};
        for (int k0 = 0; k0 < Z_; k0 += 16) {
            *(float4*)&sW[0][wkk][wc] = *(const float4*)&mzW[(size_t)(k0 + wkk) * Z_ + wc];
            *(float4*)&sW[1][wkk][wc] = *(const float4*)&vzW[(size_t)(k0 + wkk) * Z_ + wc];
            __syncthreads();
#pragma unroll
            for (int k = 0; k < 16; ++k) {
                float a_[4];
#pragma unroll
                for (int i = 0; i < 4; ++i) a_[i] = sZT[(ty * 4 + i) * 65 + k0 + k];
                float4 wm4 = *(const float4*)&sW[0][k][txi * 4];
                float4 wv4 = *(const float4*)&sW[1][k][txi * 4];
                float wm[4] = {wm4.x, wm4.y, wm4.z, wm4.w};
                float wv[4] = {wv4.x, wv4.y, wv4.z, wv4.w};
#pragma unroll
                for (int i = 0; i < 4; ++i)
#pragma unroll
                    for (int j = 0; j < 4; ++j) {
                        cm[i][j] = fmaf(a_[i], wm[j], cm[i][j]);
                        cv[i][j] = fmaf(a_[i], wv[j], cv[i][j]);
                    }
            }
            __syncthreads();
        }
#pragma unroll
        for (int i = 0; i < 4; ++i) {
            int r = r0 + ty * 4 + i;
            size_t base = (size_t)r * Z_ + txi * 4;
            float4 m4, v4; float* pm = (float*)&m4; float* pv = (float*)&v4;
#pragma unroll
            for (int j = 0; j < 4; ++j) {
                int zc = txi * 4 + j;
                pm[j] = cm[i][j] + mzb[zc];
                pv[j] = cv[i][j] + vzb[zc];
            }
            *(float4*)&Omzt[base] = m4;
            *(float4*)&Ovzt[base] = v4;
        }
    }
}

// ---------------- K_tmp: tmp = leaky(z@W1+b1, .01) + h  (both heads) --------
__global__ __launch_bounds__(256) void k_tmp(
    const float* __restrict__ z, const float* __restrict__ h,
    const float* __restrict__ fW1, const float* __restrict__ fb1,
    const float* __restrict__ rW1, const float* __restrict__ rb1,
    float* __restrict__ tmpF, float* __restrict__ tmpR) {
    const float* W1 = blockIdx.y ? rW1 : fW1;
    const float* b1 = blockIdx.y ? rb1 : fb1;
    float* outp = blockIdx.y ? tmpR : tmpF;
    __shared__ float sZp[64][17];
    __shared__ __align__(16) float sW[16][128];
    int r0 = blockIdx.x * 64;
    int tid = threadIdx.x, ty = tid >> 4, txi = tid & 15;
    int idx = tid * 4;
    int arr = idx >> 4, akb = idx & 15;
    float acc[4][8] = {};
    for (int k0 = 0; k0 < Z_; k0 += 16) {
        {
            float4 v = *(const float4*)&z[((size_t)(r0 + arr)) * Z_ + k0 + akb];
            sZp[arr][akb] = v.x; sZp[arr][akb + 1] = v.y; sZp[arr][akb + 2] = v.z; sZp[arr][akb + 3] = v.w;
        }
        for (int i = idx; i < 2048; i += 1024) {
            int kk = i >> 7, c = i & 127;
            *(float4*)&sW[kk][c] = *(const float4*)&W1[(size_t)(k0 + kk) * E_ + c];
        }
        __syncthreads();
#pragma unroll
        for (int k = 0; k < 16; ++k) {
            float a_[4];
#pragma unroll
            for (int i = 0; i < 4; ++i) a_[i] = sZp[ty * 4 + i][k];
            float4 wA4 = *(const float4*)&sW[k][txi * 4];
            float4 wB4 = *(const float4*)&sW[k][64 + txi * 4];
            float wA[4] = {wA4.x, wA4.y, wA4.z, wA4.w};
            float wB[4] = {wB4.x, wB4.y, wB4.z, wB4.w};
#pragma unroll
            for (int i = 0; i < 4; ++i)
#pragma unroll
                for (int j = 0; j < 4; ++j) {
                    acc[i][j] = fmaf(a_[i], wA[j], acc[i][j]);
                    acc[i][4 + j] = fmaf(a_[i], wB[j], acc[i][4 + j]);
                }
        }
        __syncthreads();
    }
#pragma unroll
    for (int i = 0; i < 4; ++i) {
        size_t r = (size_t)(r0 + ty * 4 + i);
#pragma unroll
        for (int half = 0; half < 2; ++half) {
            size_t base = r * E_ + half * 64 + txi * 4;
            float4 hv = *(const float4*)&h[base];
            float* ph = (float*)&hv;
            float4 ov; float* po = (float*)&ov;
#pragma unroll
            for (int j = 0; j < 4; ++j) {
                int c = half * 64 + txi * 4 + j;
                float v = acc[i][half * 4 + j] + b1[c];
                v = (v > 0.0f) ? v : 0.01f * v;
                po[j] = v + ph[j];
            }
            *(float4*)&outp[base] = ov;
        }
    }
}

// ---------------- K_out: out[b,d,n] = tmp @ W2 + b2 (transposed write) ------
// tile: 128 rows (n) x 64 cols (d); A transposed in LDS for float4 inner reads
__global__ __launch_bounds__(256) void k_out(
    const float* __restrict__ tmp, const float* __restrict__ W2,
    const float* __restrict__ b2, float* __restrict__ out, int Dout) {
    __shared__ float sAT[16][132];
    __shared__ __align__(16) float sW[16][64];
    int r0 = blockIdx.x * 128;
    int b = r0 >> 9, n0 = r0 & 511;
    int d0 = blockIdx.y * 64;
    int tid = threadIdx.x, ty = tid >> 4, txi = tid & 15;
    int srr = tid >> 2, skb = (tid & 3) * 4;
    float acc[8][4] = {};  // [half*4+i][j]
    for (int k0 = 0; k0 < E_; k0 += 16) {
        // stage A transposed: sAT[k][row]
#pragma unroll
        for (int hrr = 0; hrr < 2; ++hrr) {
            int rr = srr + hrr * 64;
            float4 v = *(const float4*)&tmp[(size_t)(r0 + rr) * E_ + k0 + skb];
            sAT[skb + 0][rr] = v.x; sAT[skb + 1][rr] = v.y;
            sAT[skb + 2][rr] = v.z; sAT[skb + 3][rr] = v.w;
        }
        // stage W
        {
            int i4 = tid * 4;
            int kk = i4 >> 6, c = i4 & 63;
            *(float4*)&sW[kk][c] = *(const float4*)&W2[(size_t)(k0 + kk) * Dout + d0 + c];
        }
        __syncthreads();
#pragma unroll
        for (int k = 0; k < 16; ++k) {
            float4 a04 = *(const float4*)&sAT[k][txi * 4];
            float4 a14 = *(const float4*)&sAT[k][64 + txi * 4];
            float4 w4  = *(const float4*)&sW[k][ty * 4];
            float a0[4] = {a04.x, a04.y, a04.z, a04.w};
            float a1[4] = {a14.x, a14.y, a14.z, a14.w};
            float w[4]  = {w4.x, w4.y, w4.z, w4.w};
#pragma unroll
            for (int i = 0; i < 4; ++i)
#pragma unroll
                for (int j = 0; j < 4; ++j) {
                    acc[i][j]     = fmaf(a0[i], w[j], acc[i][j]);
                    acc[4 + i][j] = fmaf(a1[i], w[j], acc[4 + i][j]);
                }
        }
        __syncthreads();
    }
#pragma unroll
    for (int j = 0; j < 4; ++j) {
        int d = d0 + ty * 4 + j;
        float bb = b2[d];
        size_t base = ((size_t)b * Dout + d) * N_ + n0;
        float4 v0, v1; float* p0 = (float*)&v0; float* p1 = (float*)&v1;
#pragma unroll
        for (int i = 0; i < 4; ++i) { p0[i] = acc[i][j] + bb; p1[i] = acc[4 + i][j] + bb; }
        *(float4*)&out[base + txi * 4] = v0;
        *(float4*)&out[base + 64 + txi * 4] = v1;
    }
}

// ---------------- launch ----------------------------------------------------
extern "C" void kernel_launch(void* const* d_in, const int* in_sizes, int n_in,
                              void* d_out, int out_size, void* d_ws, size_t ws_size,
                              hipStream_t stream) {
    (void)in_sizes; (void)n_in; (void)out_size; (void)ws_size;
    const float* batch_x = (const float*)d_in[0];
    const float* time_x  = (const float*)d_in[1];
    const float* time_W  = (const float*)d_in[2];
    const float* time_b  = (const float*)d_in[3];
    const float* gate_W  = (const float*)d_in[4];
    const float* gate_b  = (const float*)d_in[5];
    const float* mu_t_W  = (const float*)d_in[6];
    const float* mu_t_b  = (const float*)d_in[7];
    const float* var_t_W = (const float*)d_in[8];
    const float* var_t_b = (const float*)d_in[9];
    const float* ser_W   = (const float*)d_in[10];
    const float* ser_b   = (const float*)d_in[11];
    const float* mu_h_W  = (const float*)d_in[12];
    const float* mu_h_b  = (const float*)d_in[13];
    const float* var_h_W = (const float*)d_in[14];
    const float* var_h_b = (const float*)d_in[15];
    const float* mlp_W   = (const float*)d_in[18];
    const float* mlp_b   = (const float*)d_in[19];
    const float* mu_ht_W = (const float*)d_in[20];
    const float* mu_ht_b = (const float*)d_in[21];
    const float* var_ht_W = (const float*)d_in[22];
    const float* var_ht_b = (const float*)d_in[23];
    const float* inf_W   = (const float*)d_in[24];
    const float* inf_b   = (const float*)d_in[25];
    const float* mu_zt_W = (const float*)d_in[26];
    const float* mu_zt_b = (const float*)d_in[27];
    const float* var_zt_W = (const float*)d_in[28];
    const float* var_zt_b = (const float*)d_in[29];
    const float* fW1 = (const float*)d_in[30];
    const float* fb1 = (const float*)d_in[31];
    const float* fW2 = (const float*)d_in[32];
    const float* fb2 = (const float*)d_in[33];
    const float* rW1 = (const float*)d_in[34];
    const float* rb1 = (const float*)d_in[35];
    const float* rW2 = (const float*)d_in[36];
    const float* rb2 = (const float*)d_in[37];

    float* out = (float*)d_out;
    float* ws = (float*)d_ws;

    // ws layout (floats), lifetime-overlapped:
    const size_t off_t0   = 0;         // [2M] dead after k_gate_series
    const size_t off_z    = 0;         // [1M] written by k_mega (after t0 dead)
    const size_t off_t    = 2097152;   // [2M] dead after k_mega
    const size_t off_tmpF = 2097152;   // [2M] overlays t
    const size_t off_h    = 4194304;   // [2M] live until k_tmp done
    const size_t off_hh   = 6291456;   // [2M] dead after k_mega
    const size_t off_tmpR = 6291456;   // [2M] overlays hh
    const size_t off_csum = 8388608;   // [128]

    // out layout (floats): x, y, mu_t, var_t, mu_zt, var_zt, mu_z, var_z
    float* o_x     = out;
    float* o_y     = out + 8388608;
    float* o_mu_t  = out + 11534336;
    float* o_var_t = out + 12582912;
    float* o_mu_zt = out + 13631488;
    float* o_var_zt= out + 14680064;
    float* o_mu_z  = out + 15728640;
    float* o_var_z = out + 16777216;

    uint32_t kz1a, kz1b, kz2a, kz2b;
    tf2x32(0u, 42u, 0u, 0u, kz1a, kz1b);
    tf2x32(0u, 42u, 0u, 1u, kz2a, kz2b);

    k_time_embed<<<B_ * L_, 128, 0, stream>>>(time_x, time_W, time_b, ws + off_t0);
    k_colsum<<<1, 128, 0, stream>>>(mu_ht_W, var_ht_W, ws + off_csum);
    k_gate_series<<<dim3(8, 2, B_), 256, 0, stream>>>(ws + off_t0, gate_W, gate_b,
                                                      batch_x, ser_W, ser_b,
                                                      ws + off_t, ws + off_h, ws + off_hh);
    k_mega<<<256, 256, 0, stream>>>(ws + off_t, ws + off_hh,
                                    mu_t_W, mu_t_b, var_t_W, var_t_b,
                                    mu_h_W, mu_h_b, var_h_W, var_h_b,
                                    mu_ht_W, mu_ht_b, var_ht_W, var_ht_b,
                                    mlp_W, mlp_b, ws + off_csum,
                                    inf_W, inf_b, mu_zt_W, mu_zt_b, var_zt_W, var_zt_b,
                                    o_mu_t, o_var_t, o_mu_z, o_var_z, o_mu_zt, o_var_zt,
                                    ws + off_z, kz1a, kz1b, kz2a, kz2b);
    k_tmp<<<dim3(256, 2), 256, 0, stream>>>(ws + off_z, ws + off_h,
                                            fW1, fb1, rW1, rb1,
                                            ws + off_tmpF, ws + off_tmpR);
    k_out<<<dim3(128, HP_ / 64), 256, 0, stream>>>(ws + off_tmpF, fW2, fb2, o_y, HP_);
    k_out<<<dim3(128, L_ / 64), 256, 0, stream>>>(ws + off_tmpR, rW2, rb2, o_x, L_);
}

// Round 3
// 320.745 us; speedup vs baseline: 1.4201x; 1.1258x over previous
//
#include <hip/hip_runtime.h>
#include <cstdint>
#include <cstddef>

#define B_ 32
#define L_ 512
#define HP_ 192
#define N_ 512
#define E_ 128
#define Z_ 64

typedef short bf16x8 __attribute__((ext_vector_type(8)));
typedef float f32x4 __attribute__((ext_vector_type(4)));

// ---------------- threefry2x32 (JAX-compatible) ----------------
__host__ __device__ __forceinline__ uint32_t rotl32(uint32_t v, int r) {
    return (v << r) | (v >> (32 - r));
}

__host__ __device__ __forceinline__ void tf2x32(uint32_t k0, uint32_t k1,
                                                uint32_t c0, uint32_t c1,
                                                uint32_t& o0, uint32_t& o1) {
    uint32_t ks2 = k0 ^ k1 ^ 0x1BD11BDAu;
    uint32_t x0 = c0 + k0, x1 = c1 + k1;
    x0 += x1; x1 = rotl32(x1, 13); x1 ^= x0;
    x0 += x1; x1 = rotl32(x1, 15); x1 ^= x0;
    x0 += x1; x1 = rotl32(x1, 26); x1 ^= x0;
    x0 += x1; x1 = rotl32(x1, 6);  x1 ^= x0;
    x0 += k1; x1 += ks2 + 1u;
    x0 += x1; x1 = rotl32(x1, 17); x1 ^= x0;
    x0 += x1; x1 = rotl32(x1, 29); x1 ^= x0;
    x0 += x1; x1 = rotl32(x1, 16); x1 ^= x0;
    x0 += x1; x1 = rotl32(x1, 24); x1 ^= x0;
    x0 += ks2; x1 += k0 + 2u;
    x0 += x1; x1 = rotl32(x1, 13); x1 ^= x0;
    x0 += x1; x1 = rotl32(x1, 15); x1 ^= x0;
    x0 += x1; x1 = rotl32(x1, 26); x1 ^= x0;
    x0 += x1; x1 = rotl32(x1, 6);  x1 ^= x0;
    x0 += k0; x1 += k1 + 3u;
    x0 += x1; x1 = rotl32(x1, 17); x1 ^= x0;
    x0 += x1; x1 = rotl32(x1, 29); x1 ^= x0;
    x0 += x1; x1 = rotl32(x1, 16); x1 ^= x0;
    x0 += x1; x1 = rotl32(x1, 24); x1 ^= x0;
    x0 += k1; x1 += ks2 + 4u;
    x0 += x1; x1 = rotl32(x1, 13); x1 ^= x0;
    x0 += x1; x1 = rotl32(x1, 15); x1 ^= x0;
    x0 += x1; x1 = rotl32(x1, 26); x1 ^= x0;
    x0 += x1; x1 = rotl32(x1, 6);  x1 ^= x0;
    x0 += ks2; x1 += k0 + 5u;
    o0 = x0; o1 = x1;
}

// XLA ErfInv32 (Giles polynomial)
__device__ __forceinline__ float erfinv_f(float x) {
    float w = -log1pf(-x * x);
    float p;
    if (w < 5.0f) {
        w = w - 2.5f;
        p = 2.81022636e-08f;
        p = fmaf(p, w, 3.43273939e-07f);
        p = fmaf(p, w, -3.5233877e-06f);
        p = fmaf(p, w, -4.39150654e-06f);
        p = fmaf(p, w, 0.00021858087f);
        p = fmaf(p, w, -0.00125372503f);
        p = fmaf(p, w, -0.00417768164f);
        p = fmaf(p, w, 0.246640727f);
        p = fmaf(p, w, 1.50140941f);
    } else {
        w = sqrtf(w) - 3.0f;
        p = -0.000200214257f;
        p = fmaf(p, w, 0.000100950558f);
        p = fmaf(p, w, 0.00134934322f);
        p = fmaf(p, w, -0.00367342844f);
        p = fmaf(p, w, 0.00573950773f);
        p = fmaf(p, w, -0.0076224613f);
        p = fmaf(p, w, 0.00943887047f);
        p = fmaf(p, w, 1.00167406f);
        p = fmaf(p, w, 2.83297682f);
    }
    return p * x;
}

__device__ __forceinline__ float bits_to_normal(uint32_t bits) {
    float f = __uint_as_float((bits >> 9) | 0x3f800000u) - 1.0f;  // [0,1)
    const float lo = -0.99999994f;
    float u = fmaxf(lo, f * 2.0f + lo);
    return 1.41421354f * erfinv_f(u);
}

// fp32 -> bf16 (RNE), packed helpers
__device__ __forceinline__ uint32_t f2bf1(float x) {
    uint32_t u = __float_as_uint(x);
    return (u + 0x7fffu + ((u >> 16) & 1u)) >> 16;
}
__device__ __forceinline__ uint32_t f2bf2(float lo, float hi) {
    return f2bf1(lo) | (f2bf1(hi) << 16);
}

// ---------------- K_colsum -------------------------------------------------
__global__ void k_colsum(const float* __restrict__ mW, const float* __restrict__ vW,
                         float* __restrict__ csum) {
    int t = threadIdx.x;  // 128
    const float* W = (t < 64) ? mW : vW;
    int zc = t & 63;
    float s = 0.0f;
    for (int e = 0; e < E_; ++e) s += W[e * Z_ + zc];
    csum[t] = s;
}

// ---------------- K_gate_mfma: fused time-embed + gate + series GEMMs -------
// t[b,n,e]  = sum_l gW[l,n]  * t0[b,l,e] + gb[n],  t0 = time_x@tW+tb (fused)
// h[b,n,e]  = sum_l bx[b,l,n] * sW[l,e]  + sb[e];  hh = t + h
// MFMA 16x16x32 bf16. Tile: BM=32 (n), BN=128 (e), BK=32 (l). 256 thr, 4 waves.
// Frag layout assumption: elem e of bf16x8 <-> k = 4*(lane>>4) + (e&3) + 16*(e>=4)
__global__ __launch_bounds__(256) void k_gate_mfma(
    const float* __restrict__ tx, const float* __restrict__ tW, const float* __restrict__ tb,
    const float* __restrict__ gW, const float* __restrict__ gb,
    const float* __restrict__ bx, const float* __restrict__ sW, const float* __restrict__ sb,
    float* __restrict__ t, float* __restrict__ h, float* __restrict__ hh) {
    __shared__ __align__(16) short sGW[4 * 32 * 8];    // [g][ncol][8]
    __shared__ __align__(16) short sBX[4 * 32 * 8];
    __shared__ __align__(16) short sT0[4 * 128 * 8];   // [g][ecol][8]
    __shared__ __align__(16) short sSW[4 * 128 * 8];
    const int b = blockIdx.y, n0 = blockIdx.x * 32;
    const int tid = threadIdx.x;
    const int lane = tid & 63, wave = tid >> 6;
    const int mw = wave & 1, ew = wave >> 1;
    // A staging (gW, bx): 128 slots x 2 halves
    const int aslot = tid & 127, acol = aslot & 31, ag = aslot >> 5, ahalf = tid >> 7;
    // B staging (sW, fused t0): per-wave k-group, 2 e-cols per thread
    const int bg = wave, bcol = (tid & 63) * 2;
    // frag indices
    const int fm = lane & 15, fg = lane >> 4;
    const size_t bL = (size_t)b * L_;

    float2 tw[7];
#pragma unroll
    for (int k = 0; k < 7; ++k) tw[k] = *(const float2*)&tW[k * E_ + bcol];
    const float2 tbv = *(const float2*)&tb[bcol];

    const f32x4 zv = {0.f, 0.f, 0.f, 0.f};
    f32x4 accT[4] = {zv, zv, zv, zv};
    f32x4 accH[4] = {zv, zv, zv, zv};

    for (int l0 = 0; l0 < L_; l0 += 32) {
        // ---- stage A tiles (gW / bx), bf16 ----
        {
            int lb = l0 + ahalf * 16 + ag * 4;
            float g0 = gW[(size_t)(lb + 0) * N_ + n0 + acol];
            float g1 = gW[(size_t)(lb + 1) * N_ + n0 + acol];
            float g2 = gW[(size_t)(lb + 2) * N_ + n0 + acol];
            float g3 = gW[(size_t)(lb + 3) * N_ + n0 + acol];
            uint2 pg; pg.x = f2bf2(g0, g1); pg.y = f2bf2(g2, g3);
            *(uint2*)&sGW[(ag * 32 + acol) * 8 + ahalf * 4] = pg;
            float x0 = bx[(bL + lb + 0) * N_ + n0 + acol];
            float x1 = bx[(bL + lb + 1) * N_ + n0 + acol];
            float x2 = bx[(bL + lb + 2) * N_ + n0 + acol];
            float x3 = bx[(bL + lb + 3) * N_ + n0 + acol];
            uint2 px; px.x = f2bf2(x0, x1); px.y = f2bf2(x2, x3);
            *(uint2*)&sBX[(ag * 32 + acol) * 8 + ahalf * 4] = px;
        }
        // ---- stage B tiles (sW + fused t0), bf16 ----
        {
            float swA[8], swB[8], tA[8], tB[8];
#pragma unroll
            for (int e = 0; e < 8; ++e) {
                int l = l0 + bg * 4 + (e & 3) + ((e >> 2) << 4);
                float2 wv = *(const float2*)&sW[(size_t)l * E_ + bcol];
                swA[e] = wv.x; swB[e] = wv.y;
                const float* txr = &tx[(bL + l) * 7];
                float a0 = tbv.x, a1 = tbv.y;
#pragma unroll
                for (int k = 0; k < 7; ++k) {
                    float s = txr[k];
                    a0 = fmaf(s, tw[k].x, a0);
                    a1 = fmaf(s, tw[k].y, a1);
                }
                tA[e] = a0; tB[e] = a1;
            }
            uint4 u;
            u.x = f2bf2(swA[0], swA[1]); u.y = f2bf2(swA[2], swA[3]);
            u.z = f2bf2(swA[4], swA[5]); u.w = f2bf2(swA[6], swA[7]);
            *(uint4*)&sSW[(bg * 128 + bcol) * 8] = u;
            u.x = f2bf2(swB[0], swB[1]); u.y = f2bf2(swB[2], swB[3]);
            u.z = f2bf2(swB[4], swB[5]); u.w = f2bf2(swB[6], swB[7]);
            *(uint4*)&sSW[(bg * 128 + bcol + 1) * 8] = u;
            u.x = f2bf2(tA[0], tA[1]); u.y = f2bf2(tA[2], tA[3]);
            u.z = f2bf2(tA[4], tA[5]); u.w = f2bf2(tA[6], tA[7]);
            *(uint4*)&sT0[(bg * 128 + bcol) * 8] = u;
            u.x = f2bf2(tB[0], tB[1]); u.y = f2bf2(tB[2], tB[3]);
            u.z = f2bf2(tB[4], tB[5]); u.w = f2bf2(tB[6], tB[7]);
            *(uint4*)&sT0[(bg * 128 + bcol + 1) * 8] = u;
        }
        __syncthreads();
        // ---- frags + MFMA ----
        bf16x8 fgw = *(const bf16x8*)&sGW[(fg * 32 + mw * 16 + fm) * 8];
        bf16x8 fbx = *(const bf16x8*)&sBX[(fg * 32 + mw * 16 + fm) * 8];
#pragma unroll
        for (int nt = 0; nt < 4; ++nt) {
            int ec = ew * 64 + nt * 16 + fm;
            bf16x8 ft = *(const bf16x8*)&sT0[(fg * 128 + ec) * 8];
            bf16x8 fs = *(const bf16x8*)&sSW[(fg * 128 + ec) * 8];
            accT[nt] = __builtin_amdgcn_mfma_f32_16x16x32_bf16(fgw, ft, accT[nt], 0, 0, 0);
            accH[nt] = __builtin_amdgcn_mfma_f32_16x16x32_bf16(fbx, fs, accH[nt], 0, 0, 0);
        }
        __syncthreads();
    }
    // ---- epilogue: D row = 4*fg + reg (within m-tile), col = fm ----
    float gbn[4];
#pragma unroll
    for (int r = 0; r < 4; ++r) gbn[r] = gb[n0 + mw * 16 + fg * 4 + r];
#pragma unroll
    for (int nt = 0; nt < 4; ++nt) {
        int e = ew * 64 + nt * 16 + fm;
        float sbe = sb[e];
#pragma unroll
        for (int r = 0; r < 4; ++r) {
            int n = n0 + mw * 16 + fg * 4 + r;
            size_t base = ((size_t)b * N_ + n) * E_ + e;
            float tv = accT[nt][r] + gbn[r];
            float hv = accH[nt][r] + sbe;
            t[base] = tv; h[base] = hv; hh[base] = tv + hv;
        }
    }
}

// ---------------- K_mega: proj_t + proj_h + reparam + zt chain (fp32) -------
__global__ __launch_bounds__(256) void k_mega(
    const float* __restrict__ T, const float* __restrict__ HH,
    const float* __restrict__ Wmt, const float* __restrict__ bmt_,
    const float* __restrict__ Wvt, const float* __restrict__ bvt_,
    const float* __restrict__ Wmh, const float* __restrict__ bmh,
    const float* __restrict__ Wvh, const float* __restrict__ bvh,
    const float* __restrict__ Wmht, const float* __restrict__ bmht,
    const float* __restrict__ Wvht, const float* __restrict__ bvht,
    const float* __restrict__ mlpW, const float* __restrict__ mlpb,
    const float* __restrict__ csum,
    const float* __restrict__ iW, const float* __restrict__ ib,
    const float* __restrict__ mzW, const float* __restrict__ mzb,
    const float* __restrict__ vzW, const float* __restrict__ vzb,
    float* __restrict__ Omt, float* __restrict__ Ovt,
    float* __restrict__ Omz, float* __restrict__ Ovz,
    float* __restrict__ Omzt, float* __restrict__ Ovzt,
    float* __restrict__ Zout,
    uint32_t k1a, uint32_t k1b, uint32_t k2a, uint32_t k2b) {
    __shared__ float sA[64][17];
    __shared__ __align__(16) float sW[4][16][64];
    __shared__ float sZ[64 * 65];
    __shared__ float sZT[64 * 65];
    int r0 = blockIdx.x * 64;
    int tid = threadIdx.x, ty = tid >> 4, txi = tid & 15;
    int idx = tid * 4;
    int arr = idx >> 4, akb = idx & 15;
    int wkk = idx >> 6, wc = idx & 63;

    // ---------- Phase A1: mu_t / var_t from T ----------
    {
        float am[4][4] = {}, av[4][4] = {};
        for (int k0 = 0; k0 < E_; k0 += 16) {
            {
                float4 v = *(const float4*)&T[((size_t)(r0 + arr)) * E_ + k0 + akb];
                sA[arr][akb] = v.x; sA[arr][akb + 1] = v.y; sA[arr][akb + 2] = v.z; sA[arr][akb + 3] = v.w;
                *(float4*)&sW[0][wkk][wc] = *(const float4*)&Wmt[(size_t)(k0 + wkk) * Z_ + wc];
                *(float4*)&sW[1][wkk][wc] = *(const float4*)&Wvt[(size_t)(k0 + wkk) * Z_ + wc];
            }
            __syncthreads();
#pragma unroll
            for (int k = 0; k < 16; ++k) {
                float a_[4];
#pragma unroll
                for (int i = 0; i < 4; ++i) a_[i] = sA[ty * 4 + i][k];
                float4 wm4 = *(const float4*)&sW[0][k][txi * 4];
                float4 wv4 = *(const float4*)&sW[1][k][txi * 4];
                float wm[4] = {wm4.x, wm4.y, wm4.z, wm4.w};
                float wv[4] = {wv4.x, wv4.y, wv4.z, wv4.w};
#pragma unroll
                for (int i = 0; i < 4; ++i)
#pragma unroll
                    for (int j = 0; j < 4; ++j) {
                        am[i][j] = fmaf(a_[i], wm[j], am[i][j]);
                        av[i][j] = fmaf(a_[i], wv[j], av[i][j]);
                    }
            }
            __syncthreads();
        }
#pragma unroll
        for (int i = 0; i < 4; ++i) {
            int r = r0 + ty * 4 + i;
            size_t base = (size_t)r * Z_ + txi * 4;
            float4 m4, v4; float* pm = (float*)&m4; float* pv = (float*)&v4;
#pragma unroll
            for (int j = 0; j < 4; ++j) {
                int zc = txi * 4 + j;
                pm[j] = am[i][j] + bmt_[zc];
                pv[j] = av[i][j] + bvt_[zc];
            }
            *(float4*)&Omt[base] = m4;
            *(float4*)&Ovt[base] = v4;
        }
    }

    // ---------- Phase A2: 4 GEMMs from HH ----------
    float a1[4][4] = {}, a2[4][4] = {}, a3[4][4] = {}, a4[4][4] = {};
    for (int k0 = 0; k0 < E_; k0 += 16) {
        {
            float4 v = *(const float4*)&HH[((size_t)(r0 + arr)) * E_ + k0 + akb];
            sA[arr][akb] = v.x; sA[arr][akb + 1] = v.y; sA[arr][akb + 2] = v.z; sA[arr][akb + 3] = v.w;
            *(float4*)&sW[0][wkk][wc] = *(const float4*)&Wmh[(size_t)(k0 + wkk) * Z_ + wc];
            *(float4*)&sW[1][wkk][wc] = *(const float4*)&Wvh[(size_t)(k0 + wkk) * Z_ + wc];
            *(float4*)&sW[2][wkk][wc] = *(const float4*)&Wmht[(size_t)(k0 + wkk) * Z_ + wc];
            *(float4*)&sW[3][wkk][wc] = *(const float4*)&Wvht[(size_t)(k0 + wkk) * Z_ + wc];
        }
        __syncthreads();
#pragma unroll
        for (int k = 0; k < 16; ++k) {
            float a_[4];
#pragma unroll
            for (int i = 0; i < 4; ++i) a_[i] = sA[ty * 4 + i][k];
            float4 w1 = *(const float4*)&sW[0][k][txi * 4];
            float4 w2 = *(const float4*)&sW[1][k][txi * 4];
            float4 w3 = *(const float4*)&sW[2][k][txi * 4];
            float4 w4 = *(const float4*)&sW[3][k][txi * 4];
            float p1[4] = {w1.x, w1.y, w1.z, w1.w};
            float p2[4] = {w2.x, w2.y, w2.z, w2.w};
            float p3[4] = {w3.x, w3.y, w3.z, w3.w};
            float p4[4] = {w4.x, w4.y, w4.z, w4.w};
#pragma unroll
            for (int i = 0; i < 4; ++i)
#pragma unroll
                for (int j = 0; j < 4; ++j) {
                    a1[i][j] = fmaf(a_[i], p1[j], a1[i][j]);
                    a2[i][j] = fmaf(a_[i], p2[j], a2[i][j]);
                    a3[i][j] = fmaf(a_[i], p3[j], a3[i][j]);
                    a4[i][j] = fmaf(a_[i], p4[j], a4[i][j]);
                }
        }
        __syncthreads();
    }

    // ---------- Phase B: reparam + blend ----------
    {
        float w0 = mlpW[0], b0 = mlpb[0];
#pragma unroll
        for (int i = 0; i < 4; ++i) {
            int row = ty * 4 + i;
            int r = r0 + row;
            size_t base = (size_t)r * Z_ + txi * 4;
            float4 zf, mf, vf;
            float* pz = (float*)&zf; float* pm = (float*)&mf; float* pv = (float*)&vf;
#pragma unroll
            for (int j = 0; j < 4; ++j) {
                int zc = txi * 4 + j;
                float m1 = a1[i][j] + bmh[zc];
                float v1 = a2[i][j] + bvh[zc];
                float m2 = fmaf(w0, a3[i][j], fmaf(b0, csum[zc], bmht[zc]));
                float v2 = fmaf(w0, a4[i][j], fmaf(b0, csum[64 + zc], bvht[zc]));
                uint32_t flat = (uint32_t)r * 64u + (uint32_t)zc;
                uint32_t o0, o1;
                tf2x32(k1a, k1b, 0u, flat, o0, o1);
                float e1 = bits_to_normal(o0 ^ o1);
                tf2x32(k2a, k2b, 0u, flat, o0, o1);
                float e2 = bits_to_normal(o0 ^ o1);
                float zh = m1 + e1 * expf(0.5f * v1);
                float zt = m2 + e2 * expf(0.5f * v2);
                float zvv = 0.5f * (zh + zt);
                pz[j] = zvv; pm[j] = 0.5f * (m1 + m2); pv[j] = 0.5f * (v1 + v2);
                sZ[row * 65 + zc] = zvv;
            }
            *(float4*)&Zout[base] = zf;
            *(float4*)&Omz[base] = mf;
            *(float4*)&Ovz[base] = vf;
        }
    }

    // ---------- Phase C1: zt = z @ inf_W + ib ----------
    {
        float ac[4][4] = {};
        for (int k0 = 0; k0 < Z_; k0 += 16) {
            *(float4*)&sW[0][wkk][wc] = *(const float4*)&iW[(size_t)(k0 + wkk) * Z_ + wc];
            __syncthreads();
#pragma unroll
            for (int k = 0; k < 16; ++k) {
                float a_[4];
#pragma unroll
                for (int i = 0; i < 4; ++i) a_[i] = sZ[(ty * 4 + i) * 65 + k0 + k];
                float4 w4 = *(const float4*)&sW[0][k][txi * 4];
                float w[4] = {w4.x, w4.y, w4.z, w4.w};
#pragma unroll
                for (int i = 0; i < 4; ++i)
#pragma unroll
                    for (int j = 0; j < 4; ++j) ac[i][j] = fmaf(a_[i], w[j], ac[i][j]);
            }
            __syncthreads();
        }
#pragma unroll
        for (int i = 0; i < 4; ++i)
#pragma unroll
            for (int j = 0; j < 4; ++j)
                sZT[(ty * 4 + i) * 65 + txi * 4 + j] = ac[i][j] + ib[txi * 4 + j];
        __syncthreads();
    }

    // ---------- Phase C2: mu_zt / var_zt ----------
    {
        float cm[4][4] = {}, cv[4][4] = {};
        for (int k0 = 0; k0 < Z_; k0 += 16) {
            *(float4*)&sW[0][wkk][wc] = *(const float4*)&mzW[(size_t)(k0 + wkk) * Z_ + wc];
            *(float4*)&sW[1][wkk][wc] = *(const float4*)&vzW[(size_t)(k0 + wkk) * Z_ + wc];
            __syncthreads();
#pragma unroll
            for (int k = 0; k < 16; ++k) {
                float a_[4];
#pragma unroll
                for (int i = 0; i < 4; ++i) a_[i] = sZT[(ty * 4 + i) * 65 + k0 + k];
                float4 wm4 = *(const float4*)&sW[0][k][txi * 4];
                float4 wv4 = *(const float4*)&sW[1][k][txi * 4];
                float wm[4] = {wm4.x, wm4.y, wm4.z, wm4.w};
                float wv[4] = {wv4.x, wv4.y, wv4.z, wv4.w};
#pragma unroll
                for (int i = 0; i < 4; ++i)
#pragma unroll
                    for (int j = 0; j < 4; ++j) {
                        cm[i][j] = fmaf(a_[i], wm[j], cm[i][j]);
                        cv[i][j] = fmaf(a_[i], wv[j], cv[i][j]);
                    }
            }
            __syncthreads();
        }
#pragma unroll
        for (int i = 0; i < 4; ++i) {
            int r = r0 + ty * 4 + i;
            size_t base = (size_t)r * Z_ + txi * 4;
            float4 m4, v4; float* pm = (float*)&m4; float* pv = (float*)&v4;
#pragma unroll
            for (int j = 0; j < 4; ++j) {
                int zc = txi * 4 + j;
                pm[j] = cm[i][j] + mzb[zc];
                pv[j] = cv[i][j] + vzb[zc];
            }
            *(float4*)&Omzt[base] = m4;
            *(float4*)&Ovzt[base] = v4;
        }
    }
}

// ---------------- K_tmp: tmp = leaky(z@W1+b1, .01) + h  (both heads) --------
__global__ __launch_bounds__(256) void k_tmp(
    const float* __restrict__ z, const float* __restrict__ h,
    const float* __restrict__ fW1, const float* __restrict__ fb1,
    const float* __restrict__ rW1, const float* __restrict__ rb1,
    float* __restrict__ tmpF, float* __restrict__ tmpR) {
    const float* W1 = blockIdx.y ? rW1 : fW1;
    const float* b1 = blockIdx.y ? rb1 : fb1;
    float* outp = blockIdx.y ? tmpR : tmpF;
    __shared__ float sZp[64][17];
    __shared__ __align__(16) float sW[16][128];
    int r0 = blockIdx.x * 64;
    int tid = threadIdx.x, ty = tid >> 4, txi = tid & 15;
    int idx = tid * 4;
    int arr = idx >> 4, akb = idx & 15;
    float acc[4][8] = {};
    for (int k0 = 0; k0 < Z_; k0 += 16) {
        {
            float4 v = *(const float4*)&z[((size_t)(r0 + arr)) * Z_ + k0 + akb];
            sZp[arr][akb] = v.x; sZp[arr][akb + 1] = v.y; sZp[arr][akb + 2] = v.z; sZp[arr][akb + 3] = v.w;
        }
        for (int i = idx; i < 2048; i += 1024) {
            int kk = i >> 7, c = i & 127;
            *(float4*)&sW[kk][c] = *(const float4*)&W1[(size_t)(k0 + kk) * E_ + c];
        }
        __syncthreads();
#pragma unroll
        for (int k = 0; k < 16; ++k) {
            float a_[4];
#pragma unroll
            for (int i = 0; i < 4; ++i) a_[i] = sZp[ty * 4 + i][k];
            float4 wA4 = *(const float4*)&sW[k][txi * 4];
            float4 wB4 = *(const float4*)&sW[k][64 + txi * 4];
            float wA[4] = {wA4.x, wA4.y, wA4.z, wA4.w};
            float wB[4] = {wB4.x, wB4.y, wB4.z, wB4.w};
#pragma unroll
            for (int i = 0; i < 4; ++i)
#pragma unroll
                for (int j = 0; j < 4; ++j) {
                    acc[i][j] = fmaf(a_[i], wA[j], acc[i][j]);
                    acc[i][4 + j] = fmaf(a_[i], wB[j], acc[i][4 + j]);
                }
        }
        __syncthreads();
    }
#pragma unroll
    for (int i = 0; i < 4; ++i) {
        size_t r = (size_t)(r0 + ty * 4 + i);
#pragma unroll
        for (int half = 0; half < 2; ++half) {
            size_t base = r * E_ + half * 64 + txi * 4;
            float4 hv = *(const float4*)&h[base];
            float* ph = (float*)&hv;
            float4 ov; float* po = (float*)&ov;
#pragma unroll
            for (int j = 0; j < 4; ++j) {
                int c = half * 64 + txi * 4 + j;
                float v = acc[i][half * 4 + j] + b1[c];
                v = (v > 0.0f) ? v : 0.01f * v;
                po[j] = v + ph[j];
            }
            *(float4*)&outp[base] = ov;
        }
    }
}

// ---------------- K_out_mfma: out[b,d,n] = tmp @ W2 + b2 --------------------
// A = W2^T (m=d), B = tmp (col=n). Full K=128 staged once; one barrier.
// Tile: 64 d x 64 n. 256 thr / 4 waves; wave w owns d-subtile w*16..+15.
__global__ __launch_bounds__(256) void k_out_mfma(
    const float* __restrict__ tmp, const float* __restrict__ W2,
    const float* __restrict__ b2, float* __restrict__ out, int Dout) {
    __shared__ __align__(16) short sA[4 * 4 * 64 * 8];  // [kc][g][dcol][8]
    __shared__ __align__(16) short sB[4 * 4 * 64 * 8];  // [kc][g][ncol][8]
    const int r0 = blockIdx.x * 64;
    const int d0 = blockIdx.y * 64;
    const int b = r0 >> 9, nbase = r0 & 511;
    const int tid = threadIdx.x, lane = tid & 63, wave = tid >> 6;
    const int fm = lane & 15, fg = lane >> 4;
    const int col = tid & 63, sg = tid >> 6;
#pragma unroll
    for (int kc = 0; kc < 4; ++kc) {
        float av[8];
#pragma unroll
        for (int e = 0; e < 8; ++e) {
            int k = kc * 32 + sg * 4 + (e & 3) + ((e >> 2) << 4);
            av[e] = W2[(size_t)k * Dout + d0 + col];
        }
        uint4 u;
        u.x = f2bf2(av[0], av[1]); u.y = f2bf2(av[2], av[3]);
        u.z = f2bf2(av[4], av[5]); u.w = f2bf2(av[6], av[7]);
        *(uint4*)&sA[((kc * 4 + sg) * 64 + col) * 8] = u;
        float4 b0 = *(const float4*)&tmp[(size_t)(r0 + col) * E_ + kc * 32 + sg * 4];
        float4 b1 = *(const float4*)&tmp[(size_t)(r0 + col) * E_ + kc * 32 + 16 + sg * 4];
        uint4 v;
        v.x = f2bf2(b0.x, b0.y); v.y = f2bf2(b0.z, b0.w);
        v.z = f2bf2(b1.x, b1.y); v.w = f2bf2(b1.z, b1.w);
        *(uint4*)&sB[((kc * 4 + sg) * 64 + col) * 8] = v;
    }
    __syncthreads();
    const f32x4 zv = {0.f, 0.f, 0.f, 0.f};
    f32x4 acc[4] = {zv, zv, zv, zv};
#pragma unroll
    for (int kc = 0; kc < 4; ++kc) {
        bf16x8 fa = *(const bf16x8*)&sA[((kc * 4 + fg) * 64 + wave * 16 + fm) * 8];
#pragma unroll
        for (int nt = 0; nt < 4; ++nt) {
            bf16x8 fb = *(const bf16x8*)&sB[((kc * 4 + fg) * 64 + nt * 16 + fm) * 8];
            acc[nt] = __builtin_amdgcn_mfma_f32_16x16x32_bf16(fa, fb, acc[nt], 0, 0, 0);
        }
    }
#pragma unroll
    for (int r = 0; r < 4; ++r) {
        int d = d0 + wave * 16 + fg * 4 + r;
        float bb = b2[d];
#pragma unroll
        for (int nt = 0; nt < 4; ++nt) {
            int n = nbase + nt * 16 + fm;
            out[((size_t)b * Dout + d) * N_ + n] = acc[nt][r] + bb;
        }
    }
}

// ---------------- launch ----------------------------------------------------
extern "C" void kernel_launch(void* const* d_in, const int* in_sizes, int n_in,
                              void* d_out, int out_size, void* d_ws, size_t ws_size,
                              hipStream_t stream) {
    (void)in_sizes; (void)n_in; (void)out_size; (void)ws_size;
    const float* batch_x = (const float*)d_in[0];
    const float* time_x  = (const float*)d_in[1];
    const float* time_W  = (const float*)d_in[2];
    const float* time_b  = (const float*)d_in[3];
    const float* gate_W  = (const float*)d_in[4];
    const float* gate_b  = (const float*)d_in[5];
    const float* mu_t_W  = (const float*)d_in[6];
    const float* mu_t_b  = (const float*)d_in[7];
    const float* var_t_W = (const float*)d_in[8];
    const float* var_t_b = (const float*)d_in[9];
    const float* ser_W   = (const float*)d_in[10];
    const float* ser_b   = (const float*)d_in[11];
    const float* mu_h_W  = (const float*)d_in[12];
    const float* mu_h_b  = (const float*)d_in[13];
    const float* var_h_W = (const float*)d_in[14];
    const float* var_h_b = (const float*)d_in[15];
    const float* mlp_W   = (const float*)d_in[18];
    const float* mlp_b   = (const float*)d_in[19];
    const float* mu_ht_W = (const float*)d_in[20];
    const float* mu_ht_b = (const float*)d_in[21];
    const float* var_ht_W = (const float*)d_in[22];
    const float* var_ht_b = (const float*)d_in[23];
    const float* inf_W   = (const float*)d_in[24];
    const float* inf_b   = (const float*)d_in[25];
    const float* mu_zt_W = (const float*)d_in[26];
    const float* mu_zt_b = (const float*)d_in[27];
    const float* var_zt_W = (const float*)d_in[28];
    const float* var_zt_b = (const float*)d_in[29];
    const float* fW1 = (const float*)d_in[30];
    const float* fb1 = (const float*)d_in[31];
    const float* fW2 = (const float*)d_in[32];
    const float* fb2 = (const float*)d_in[33];
    const float* rW1 = (const float*)d_in[34];
    const float* rb1 = (const float*)d_in[35];
    const float* rW2 = (const float*)d_in[36];
    const float* rb2 = (const float*)d_in[37];

    float* out = (float*)d_out;
    float* ws = (float*)d_ws;

    // ws layout (floats), lifetime-overlapped:
    const size_t off_z    = 0;         // [1M] written by k_mega
    const size_t off_t    = 2097152;   // [2M] dead after k_mega phase A1
    const size_t off_tmpF = 2097152;   // [2M] overlays t
    const size_t off_h    = 4194304;   // [2M] live until k_tmp done
    const size_t off_hh   = 6291456;   // [2M] dead after k_mega
    const size_t off_tmpR = 6291456;   // [2M] overlays hh
    const size_t off_csum = 8388608;   // [128]

    // out layout (floats): x, y, mu_t, var_t, mu_zt, var_zt, mu_z, var_z
    float* o_x     = out;
    float* o_y     = out + 8388608;
    float* o_mu_t  = out + 11534336;
    float* o_var_t = out + 12582912;
    float* o_mu_zt = out + 13631488;
    float* o_var_zt= out + 14680064;
    float* o_mu_z  = out + 15728640;
    float* o_var_z = out + 16777216;

    uint32_t kz1a, kz1b, kz2a, kz2b;
    tf2x32(0u, 42u, 0u, 0u, kz1a, kz1b);
    tf2x32(0u, 42u, 0u, 1u, kz2a, kz2b);

    k_colsum<<<1, 128, 0, stream>>>(mu_ht_W, var_ht_W, ws + off_csum);
    k_gate_mfma<<<dim3(16, B_), 256, 0, stream>>>(time_x, time_W, time_b,
                                                  gate_W, gate_b,
                                                  batch_x, ser_W, ser_b,
                                                  ws + off_t, ws + off_h, ws + off_hh);
    k_mega<<<256, 256, 0, stream>>>(ws + off_t, ws + off_hh,
                                    mu_t_W, mu_t_b, var_t_W, var_t_b,
                                    mu_h_W, mu_h_b, var_h_W, var_h_b,
                                    mu_ht_W, mu_ht_b, var_ht_W, var_ht_b,
                                    mlp_W, mlp_b, ws + off_csum,
                                    inf_W, inf_b, mu_zt_W, mu_zt_b, var_zt_W, var_zt_b,
                                    o_mu_t, o_var_t, o_mu_z, o_var_z, o_mu_zt, o_var_zt,
                                    ws + off_z, kz1a, kz1b, kz2a, kz2b);
    k_tmp<<<dim3(256, 2), 256, 0, stream>>>(ws + off_z, ws + off_h,
                                            fW1, fb1, rW1, rb1,
                                            ws + off_tmpF, ws + off_tmpR);
    k_out_mfma<<<dim3(256, HP_ / 64), 256, 0, stream>>>(ws + off_tmpF, fW2, fb2, o_y, HP_);
    k_out_mfma<<<dim3(256, L_ / 64), 256, 0, stream>>>(ws + off_tmpR, rW2, rb2, o_x, L_);
}

// Round 4
// 262.762 us; speedup vs baseline: 1.7335x; 1.2207x over previous
//
#include <hip/hip_runtime.h>
#include <cstdint>
#include <cstddef>

#define B_ 32
#define L_ 512
#define HP_ 192
#define N_ 512
#define E_ 128
#define Z_ 64

typedef short bf16x8 __attribute__((ext_vector_type(8)));
typedef float f32x4 __attribute__((ext_vector_type(4)));

// ---------------- threefry2x32 (JAX-compatible) ----------------
__host__ __device__ __forceinline__ uint32_t rotl32(uint32_t v, int r) {
    return (v << r) | (v >> (32 - r));
}

__host__ __device__ __forceinline__ void tf2x32(uint32_t k0, uint32_t k1,
                                                uint32_t c0, uint32_t c1,
                                                uint32_t& o0, uint32_t& o1) {
    uint32_t ks2 = k0 ^ k1 ^ 0x1BD11BDAu;
    uint32_t x0 = c0 + k0, x1 = c1 + k1;
    x0 += x1; x1 = rotl32(x1, 13); x1 ^= x0;
    x0 += x1; x1 = rotl32(x1, 15); x1 ^= x0;
    x0 += x1; x1 = rotl32(x1, 26); x1 ^= x0;
    x0 += x1; x1 = rotl32(x1, 6);  x1 ^= x0;
    x0 += k1; x1 += ks2 + 1u;
    x0 += x1; x1 = rotl32(x1, 17); x1 ^= x0;
    x0 += x1; x1 = rotl32(x1, 29); x1 ^= x0;
    x0 += x1; x1 = rotl32(x1, 16); x1 ^= x0;
    x0 += x1; x1 = rotl32(x1, 24); x1 ^= x0;
    x0 += ks2; x1 += k0 + 2u;
    x0 += x1; x1 = rotl32(x1, 13); x1 ^= x0;
    x0 += x1; x1 = rotl32(x1, 15); x1 ^= x0;
    x0 += x1; x1 = rotl32(x1, 26); x1 ^= x0;
    x0 += x1; x1 = rotl32(x1, 6);  x1 ^= x0;
    x0 += k0; x1 += k1 + 3u;
    x0 += x1; x1 = rotl32(x1, 17); x1 ^= x0;
    x0 += x1; x1 = rotl32(x1, 29); x1 ^= x0;
    x0 += x1; x1 = rotl32(x1, 16); x1 ^= x0;
    x0 += x1; x1 = rotl32(x1, 24); x1 ^= x0;
    x0 += k1; x1 += ks2 + 4u;
    x0 += x1; x1 = rotl32(x1, 13); x1 ^= x0;
    x0 += x1; x1 = rotl32(x1, 15); x1 ^= x0;
    x0 += x1; x1 = rotl32(x1, 26); x1 ^= x0;
    x0 += x1; x1 = rotl32(x1, 6);  x1 ^= x0;
    x0 += ks2; x1 += k0 + 5u;
    o0 = x0; o1 = x1;
}

// XLA ErfInv32 (Giles polynomial)
__device__ __forceinline__ float erfinv_f(float x) {
    float w = -log1pf(-x * x);
    float p;
    if (w < 5.0f) {
        w = w - 2.5f;
        p = 2.81022636e-08f;
        p = fmaf(p, w, 3.43273939e-07f);
        p = fmaf(p, w, -3.5233877e-06f);
        p = fmaf(p, w, -4.39150654e-06f);
        p = fmaf(p, w, 0.00021858087f);
        p = fmaf(p, w, -0.00125372503f);
        p = fmaf(p, w, -0.00417768164f);
        p = fmaf(p, w, 0.246640727f);
        p = fmaf(p, w, 1.50140941f);
    } else {
        w = sqrtf(w) - 3.0f;
        p = -0.000200214257f;
        p = fmaf(p, w, 0.000100950558f);
        p = fmaf(p, w, 0.00134934322f);
        p = fmaf(p, w, -0.00367342844f);
        p = fmaf(p, w, 0.00573950773f);
        p = fmaf(p, w, -0.0076224613f);
        p = fmaf(p, w, 0.00943887047f);
        p = fmaf(p, w, 1.00167406f);
        p = fmaf(p, w, 2.83297682f);
    }
    return p * x;
}

__device__ __forceinline__ float bits_to_normal(uint32_t bits) {
    float f = __uint_as_float((bits >> 9) | 0x3f800000u) - 1.0f;  // [0,1)
    const float lo = -0.99999994f;
    float u = fmaxf(lo, f * 2.0f + lo);
    return 1.41421354f * erfinv_f(u);
}

// fp32 -> bf16 (RNE), packed helpers
__device__ __forceinline__ uint32_t f2bf1(float x) {
    uint32_t u = __float_as_uint(x);
    return (u + 0x7fffu + ((u >> 16) & 1u)) >> 16;
}
__device__ __forceinline__ uint32_t f2bf2(float lo, float hi) {
    return f2bf1(lo) | (f2bf1(hi) << 16);
}

// bf16 frag pool offsets (shorts)
#define PO_WT   0        // [128][128]  mu_t|var_t
#define PO_WH   16384    // [128][256]  mu_h|var_h|mu_ht|var_ht
#define PO_WI   49152    // [64][64]    inf_W
#define PO_WZZ  53248    // [64][128]   mu_zt|var_zt
#define PO_W1F  61440    // [64][128]   fW1
#define PO_W1R  69632    // [64][128]   rW1
#define PO_W2F  77824    // [128][192]  fW2
#define PO_W2R  102400   // [128][512]  rW2

struct PrepSrcs { const float* p[13]; };

// pack fp32 weight [K][Ns] into bf16 MFMA B-frag layout at dst cols [c0,c0+Ns)
// frag addr: (((k>>5)*4 + fg)*Nd + n)*8 + e, k32=k&31, fg=(k32>>2)&3,
//            e=(k32&3)+4*(k32>>4)
__global__ void k_prep(PrepSrcs S, short* pool) {
    static const int Kt[13]  = {128,128,128,128,128,128,64,64,64,64,64,128,128};
    static const int Nst[13] = {64,64,64,64,64,64,64,64,64,128,128,192,512};
    static const int Ndt[13] = {128,128,256,256,256,256,64,128,128,128,128,192,512};
    static const int c0t[13] = {0,64,0,64,128,192,0,0,64,0,0,0,0};
    static const int offt[13]= {PO_WT,PO_WT,PO_WH,PO_WH,PO_WH,PO_WH,PO_WI,
                                PO_WZZ,PO_WZZ,PO_W1F,PO_W1R,PO_W2F,PO_W2R};
    int j = blockIdx.y;
    int Ns = Nst[j];
    int total = Kt[j] * Ns;
    int idx = blockIdx.x * 256 + threadIdx.x;
    if (idx >= total) return;
    int k = idx / Ns, nc = idx - k * Ns;
    float v = S.p[j][idx];
    int kc = k >> 5, k32 = k & 31;
    int fg = (k32 >> 2) & 3, e = (k32 & 3) + ((k32 >> 4) << 2);
    pool[offt[j] + (size_t)((kc * 4 + fg) * Ndt[j] + c0t[j] + nc) * 8 + e] = (short)f2bf1(v);
}

// ---------------- K_colsum -------------------------------------------------
__global__ void k_colsum(const float* __restrict__ mW, const float* __restrict__ vW,
                         float* __restrict__ csum) {
    int t = threadIdx.x;  // 128
    const float* W = (t < 64) ? mW : vW;
    int zc = t & 63;
    float s = 0.0f;
    for (int e = 0; e < E_; ++e) s += W[e * Z_ + zc];
    csum[t] = s;
}

// ---------------- K_gate_mfma: fused time-embed + gate + series GEMMs -------
__global__ __launch_bounds__(256) void k_gate_mfma(
    const float* __restrict__ tx, const float* __restrict__ tW, const float* __restrict__ tb,
    const float* __restrict__ gW, const float* __restrict__ gb,
    const float* __restrict__ bx, const float* __restrict__ sW, const float* __restrict__ sb,
    float* __restrict__ t, float* __restrict__ h, float* __restrict__ hh) {
    __shared__ __align__(16) short sGW[4 * 32 * 8];    // [g][ncol][8]
    __shared__ __align__(16) short sBX[4 * 32 * 8];
    __shared__ __align__(16) short sT0[4 * 128 * 8];   // [g][ecol][8]
    __shared__ __align__(16) short sSW[4 * 128 * 8];
    const int b = blockIdx.y, n0 = blockIdx.x * 32;
    const int tid = threadIdx.x;
    const int lane = tid & 63, wave = tid >> 6;
    const int mw = wave & 1, ew = wave >> 1;
    const int aslot = tid & 127, acol = aslot & 31, ag = aslot >> 5, ahalf = tid >> 7;
    const int bg = wave, bcol = (tid & 63) * 2;
    const int fm = lane & 15, fg = lane >> 4;
    const size_t bL = (size_t)b * L_;

    float2 tw[7];
#pragma unroll
    for (int k = 0; k < 7; ++k) tw[k] = *(const float2*)&tW[k * E_ + bcol];
    const float2 tbv = *(const float2*)&tb[bcol];

    const f32x4 zv = {0.f, 0.f, 0.f, 0.f};
    f32x4 accT[4] = {zv, zv, zv, zv};
    f32x4 accH[4] = {zv, zv, zv, zv};

    for (int l0 = 0; l0 < L_; l0 += 32) {
        {
            int lb = l0 + ahalf * 16 + ag * 4;
            float g0 = gW[(size_t)(lb + 0) * N_ + n0 + acol];
            float g1 = gW[(size_t)(lb + 1) * N_ + n0 + acol];
            float g2 = gW[(size_t)(lb + 2) * N_ + n0 + acol];
            float g3 = gW[(size_t)(lb + 3) * N_ + n0 + acol];
            uint2 pg; pg.x = f2bf2(g0, g1); pg.y = f2bf2(g2, g3);
            *(uint2*)&sGW[(ag * 32 + acol) * 8 + ahalf * 4] = pg;
            float x0 = bx[(bL + lb + 0) * N_ + n0 + acol];
            float x1 = bx[(bL + lb + 1) * N_ + n0 + acol];
            float x2 = bx[(bL + lb + 2) * N_ + n0 + acol];
            float x3 = bx[(bL + lb + 3) * N_ + n0 + acol];
            uint2 px; px.x = f2bf2(x0, x1); px.y = f2bf2(x2, x3);
            *(uint2*)&sBX[(ag * 32 + acol) * 8 + ahalf * 4] = px;
        }
        {
            float swA[8], swB[8], tA[8], tB[8];
#pragma unroll
            for (int e = 0; e < 8; ++e) {
                int l = l0 + bg * 4 + (e & 3) + ((e >> 2) << 4);
                float2 wv = *(const float2*)&sW[(size_t)l * E_ + bcol];
                swA[e] = wv.x; swB[e] = wv.y;
                const float* txr = &tx[(bL + l) * 7];
                float a0 = tbv.x, a1 = tbv.y;
#pragma unroll
                for (int k = 0; k < 7; ++k) {
                    float s = txr[k];
                    a0 = fmaf(s, tw[k].x, a0);
                    a1 = fmaf(s, tw[k].y, a1);
                }
                tA[e] = a0; tB[e] = a1;
            }
            uint4 u;
            u.x = f2bf2(swA[0], swA[1]); u.y = f2bf2(swA[2], swA[3]);
            u.z = f2bf2(swA[4], swA[5]); u.w = f2bf2(swA[6], swA[7]);
            *(uint4*)&sSW[(bg * 128 + bcol) * 8] = u;
            u.x = f2bf2(swB[0], swB[1]); u.y = f2bf2(swB[2], swB[3]);
            u.z = f2bf2(swB[4], swB[5]); u.w = f2bf2(swB[6], swB[7]);
            *(uint4*)&sSW[(bg * 128 + bcol + 1) * 8] = u;
            u.x = f2bf2(tA[0], tA[1]); u.y = f2bf2(tA[2], tA[3]);
            u.z = f2bf2(tA[4], tA[5]); u.w = f2bf2(tA[6], tA[7]);
            *(uint4*)&sT0[(bg * 128 + bcol) * 8] = u;
            u.x = f2bf2(tB[0], tB[1]); u.y = f2bf2(tB[2], tB[3]);
            u.z = f2bf2(tB[4], tB[5]); u.w = f2bf2(tB[6], tB[7]);
            *(uint4*)&sT0[(bg * 128 + bcol + 1) * 8] = u;
        }
        __syncthreads();
        bf16x8 fgw = *(const bf16x8*)&sGW[(fg * 32 + mw * 16 + fm) * 8];
        bf16x8 fbx = *(const bf16x8*)&sBX[(fg * 32 + mw * 16 + fm) * 8];
#pragma unroll
        for (int nt = 0; nt < 4; ++nt) {
            int ec = ew * 64 + nt * 16 + fm;
            bf16x8 ft = *(const bf16x8*)&sT0[(fg * 128 + ec) * 8];
            bf16x8 fs = *(const bf16x8*)&sSW[(fg * 128 + ec) * 8];
            accT[nt] = __builtin_amdgcn_mfma_f32_16x16x32_bf16(fgw, ft, accT[nt], 0, 0, 0);
            accH[nt] = __builtin_amdgcn_mfma_f32_16x16x32_bf16(fbx, fs, accH[nt], 0, 0, 0);
        }
        __syncthreads();
    }
    float gbn[4];
#pragma unroll
    for (int r = 0; r < 4; ++r) gbn[r] = gb[n0 + mw * 16 + fg * 4 + r];
#pragma unroll
    for (int nt = 0; nt < 4; ++nt) {
        int e = ew * 64 + nt * 16 + fm;
        float sbe = sb[e];
#pragma unroll
        for (int r = 0; r < 4; ++r) {
            int n = n0 + mw * 16 + fg * 4 + r;
            size_t base = ((size_t)b * N_ + n) * E_ + e;
            float tv = accT[nt][r] + gbn[r];
            float hv = accH[nt][r] + sbe;
            t[base] = tv; h[base] = hv; hh[base] = tv + hv;
        }
    }
}

// ---------------- K_mega2: MFMA projection chain + reparam + tmp fusion -----
// 32-row tiles, 512 blocks, 4 waves. Weights read as pre-packed bf16 frags.
__global__ __launch_bounds__(256) void k_mega2(
    const float* __restrict__ T, const float* __restrict__ HH,
    const float* __restrict__ h,
    const short* __restrict__ pool,
    const float* __restrict__ bmt_, const float* __restrict__ bvt_,
    const float* __restrict__ bmh, const float* __restrict__ bvh,
    const float* __restrict__ bmht, const float* __restrict__ bvht,
    const float* __restrict__ mlpW, const float* __restrict__ mlpb,
    const float* __restrict__ csum,
    const float* __restrict__ ib,
    const float* __restrict__ mzb, const float* __restrict__ vzb,
    const float* __restrict__ fb1, const float* __restrict__ rb1,
    float* __restrict__ Omt, float* __restrict__ Ovt,
    float* __restrict__ Omz, float* __restrict__ Ovz,
    float* __restrict__ Omzt, float* __restrict__ Ovzt,
    float* __restrict__ tmpF, float* __restrict__ tmpR,
    uint32_t k1a, uint32_t k1b, uint32_t k2a, uint32_t k2b) {
    __shared__ __align__(16) short sAT[4 * 4 * 32 * 8];   // T frags
    __shared__ __align__(16) short sAH[4 * 4 * 32 * 8];   // HH frags
    __shared__ __align__(16) short sZf[2 * 4 * 32 * 8];   // z frags
    __shared__ __align__(16) short sZTf[2 * 4 * 32 * 8];  // zt frags
    __shared__ float sOut[32][260];                       // G2 results

    const short* Wt  = pool + PO_WT;
    const short* Wh  = pool + PO_WH;
    const short* Wi  = pool + PO_WI;
    const short* Wzz = pool + PO_WZZ;
    const short* W1f = pool + PO_W1F;
    const short* W1r = pool + PO_W1R;

    const int r0 = blockIdx.x * 32;
    const int tid = threadIdx.x;
    const int lane = tid & 63, wv = tid >> 6;
    const int fm = lane & 15, flane = lane >> 4;
    const int m = wv & 1, nb = wv >> 1;
    const f32x4 z4 = {0.f, 0.f, 0.f, 0.f};

    // ---- stage T / HH as A-frags ----
#pragma unroll
    for (int it = 0; it < 4; ++it) {
        int idx = tid + it * 256;
        int row = idx >> 5, c4 = idx & 31;
        int k0 = c4 * 4;
        int kc = k0 >> 5, k32 = k0 & 31;
        int fg = (k32 >> 2) & 3, e0 = (k32 >= 16) ? 4 : 0;
        int base = ((kc * 4 + fg) * 32 + row) * 8 + e0;
        float4 v = *(const float4*)&T[(size_t)(r0 + row) * E_ + k0];
        uint2 u; u.x = f2bf2(v.x, v.y); u.y = f2bf2(v.z, v.w);
        *(uint2*)&sAT[base] = u;
        float4 w = *(const float4*)&HH[(size_t)(r0 + row) * E_ + k0];
        uint2 p; p.x = f2bf2(w.x, w.y); p.y = f2bf2(w.z, w.w);
        *(uint2*)&sAH[base] = p;
    }
    __syncthreads();

    // ---- G1: [32,128] x Wt[128,128] -> mu_t | var_t (direct global write) ----
    {
        bf16x8 fa[4];
#pragma unroll
        for (int kc = 0; kc < 4; ++kc)
            fa[kc] = *(const bf16x8*)&sAT[((kc * 4 + flane) * 32 + m * 16 + fm) * 8];
        f32x4 acc[4] = {z4, z4, z4, z4};
#pragma unroll
        for (int j = 0; j < 4; ++j) {
            int nt = nb + 2 * j;
#pragma unroll
            for (int kc = 0; kc < 4; ++kc) {
                bf16x8 fb = *(const bf16x8*)&Wt[(size_t)((kc * 4 + flane) * 128 + nt * 16 + fm) * 8];
                acc[j] = __builtin_amdgcn_mfma_f32_16x16x32_bf16(fa[kc], fb, acc[j], 0, 0, 0);
            }
        }
#pragma unroll
        for (int j = 0; j < 4; ++j) {
            int ncol = (nb + 2 * j) * 16 + fm;
            float* dst = (ncol < 64) ? Omt : Ovt;
            int zc = ncol & 63;
            float bias = (ncol < 64) ? bmt_[zc] : bvt_[zc];
#pragma unroll
            for (int r = 0; r < 4; ++r) {
                int row = m * 16 + flane * 4 + r;
                dst[(size_t)(r0 + row) * Z_ + zc] = acc[j][r] + bias;
            }
        }
    }

    // ---- G2: [32,128] x Wh[128,256] -> sOut ----
    {
        bf16x8 fa[4];
#pragma unroll
        for (int kc = 0; kc < 4; ++kc)
            fa[kc] = *(const bf16x8*)&sAH[((kc * 4 + flane) * 32 + m * 16 + fm) * 8];
        f32x4 acc[8] = {z4, z4, z4, z4, z4, z4, z4, z4};
#pragma unroll
        for (int j = 0; j < 8; ++j) {
            int nt = nb + 2 * j;
#pragma unroll
            for (int kc = 0; kc < 4; ++kc) {
                bf16x8 fb = *(const bf16x8*)&Wh[(size_t)((kc * 4 + flane) * 256 + nt * 16 + fm) * 8];
                acc[j] = __builtin_amdgcn_mfma_f32_16x16x32_bf16(fa[kc], fb, acc[j], 0, 0, 0);
            }
        }
#pragma unroll
        for (int j = 0; j < 8; ++j) {
            int ncol = (nb + 2 * j) * 16 + fm;
#pragma unroll
            for (int r = 0; r < 4; ++r)
                sOut[m * 16 + flane * 4 + r][ncol] = acc[j][r];
        }
    }
    __syncthreads();

    // ---- Phase B: reparam + blend; z -> LDS frags + mu_z/var_z out ----
    {
        float w0 = mlpW[0], b0 = mlpb[0];
        int row = tid >> 3;
        int zc0 = (tid & 7) * 8;
        int r = r0 + row;
        float zm[8], zvv[8];
        uint32_t zb[8];
#pragma unroll
        for (int j = 0; j < 8; ++j) {
            int zc = zc0 + j;
            float m1 = sOut[row][zc] + bmh[zc];
            float v1 = sOut[row][64 + zc] + bvh[zc];
            float m2 = fmaf(w0, sOut[row][128 + zc], fmaf(b0, csum[zc], bmht[zc]));
            float v2 = fmaf(w0, sOut[row][192 + zc], fmaf(b0, csum[64 + zc], bvht[zc]));
            uint32_t flat = (uint32_t)r * 64u + (uint32_t)zc;
            uint32_t o0, o1;
            tf2x32(k1a, k1b, 0u, flat, o0, o1);
            float e1 = bits_to_normal(o0 ^ o1);
            tf2x32(k2a, k2b, 0u, flat, o0, o1);
            float e2 = bits_to_normal(o0 ^ o1);
            float zh = m1 + e1 * expf(0.5f * v1);
            float zt = m2 + e2 * expf(0.5f * v2);
            float zval = 0.5f * (zh + zt);
            zb[j] = f2bf1(zval);
            zm[j] = 0.5f * (m1 + m2);
            zvv[j] = 0.5f * (v1 + v2);
        }
        size_t base = (size_t)r * Z_ + zc0;
        *(float4*)&Omz[base]     = make_float4(zm[0], zm[1], zm[2], zm[3]);
        *(float4*)&Omz[base + 4] = make_float4(zm[4], zm[5], zm[6], zm[7]);
        *(float4*)&Ovz[base]     = make_float4(zvv[0], zvv[1], zvv[2], zvv[3]);
        *(float4*)&Ovz[base + 4] = make_float4(zvv[4], zvv[5], zvv[6], zvv[7]);
        // z bf16 frag writes: zc0..zc0+3 one fg, +4..+7 next fg
        int kc = zc0 >> 5, z32 = zc0 & 31;
        int fgA = (z32 >> 2) & 3, eA = (z32 >= 16) ? 4 : 0;
        uint2 u;
        u.x = zb[0] | (zb[1] << 16); u.y = zb[2] | (zb[3] << 16);
        *(uint2*)&sZf[((kc * 4 + fgA) * 32 + row) * 8 + eA] = u;
        u.x = zb[4] | (zb[5] << 16); u.y = zb[6] | (zb[7] << 16);
        *(uint2*)&sZf[((kc * 4 + fgA + 1) * 32 + row) * 8 + eA] = u;
    }
    __syncthreads();

    // ---- G3: z[32,64] x Wi[64,64] -> zt frags (LDS) ----
    {
        bf16x8 fa[2];
#pragma unroll
        for (int kc = 0; kc < 2; ++kc)
            fa[kc] = *(const bf16x8*)&sZf[((kc * 4 + flane) * 32 + m * 16 + fm) * 8];
        f32x4 acc[2] = {z4, z4};
#pragma unroll
        for (int j = 0; j < 2; ++j) {
            int nt = nb + 2 * j;
#pragma unroll
            for (int kc = 0; kc < 2; ++kc) {
                bf16x8 fb = *(const bf16x8*)&Wi[(size_t)((kc * 4 + flane) * 64 + nt * 16 + fm) * 8];
                acc[j] = __builtin_amdgcn_mfma_f32_16x16x32_bf16(fa[kc], fb, acc[j], 0, 0, 0);
            }
        }
#pragma unroll
        for (int j = 0; j < 2; ++j) {
            int col = (nb + 2 * j) * 16 + fm;
            float bias = ib[col];
            int kc2 = col >> 5, c32 = col & 31;
            int fg2 = (c32 >> 2) & 3, e2 = (c32 & 3) + ((c32 >> 4) << 2);
#pragma unroll
            for (int r = 0; r < 4; ++r) {
                int row2 = m * 16 + flane * 4 + r;
                sZTf[((kc2 * 4 + fg2) * 32 + row2) * 8 + e2] = (short)f2bf1(acc[j][r] + bias);
            }
        }
    }
    __syncthreads();

    // ---- G4: zt[32,64] x Wzz[64,128] -> mu_zt | var_zt ----
    {
        bf16x8 fa[2];
#pragma unroll
        for (int kc = 0; kc < 2; ++kc)
            fa[kc] = *(const bf16x8*)&sZTf[((kc * 4 + flane) * 32 + m * 16 + fm) * 8];
        f32x4 acc[4] = {z4, z4, z4, z4};
#pragma unroll
        for (int j = 0; j < 4; ++j) {
            int nt = nb + 2 * j;
#pragma unroll
            for (int kc = 0; kc < 2; ++kc) {
                bf16x8 fb = *(const bf16x8*)&Wzz[(size_t)((kc * 4 + flane) * 128 + nt * 16 + fm) * 8];
                acc[j] = __builtin_amdgcn_mfma_f32_16x16x32_bf16(fa[kc], fb, acc[j], 0, 0, 0);
            }
        }
#pragma unroll
        for (int j = 0; j < 4; ++j) {
            int ncol = (nb + 2 * j) * 16 + fm;
            float* dst = (ncol < 64) ? Omzt : Ovzt;
            int zc = ncol & 63;
            float bias = (ncol < 64) ? mzb[zc] : vzb[zc];
#pragma unroll
            for (int r = 0; r < 4; ++r) {
                int row = m * 16 + flane * 4 + r;
                dst[(size_t)(r0 + row) * Z_ + zc] = acc[j][r] + bias;
            }
        }
    }

    // ---- G5/G6: tmp = leaky(z @ W1 + b1) + h  (both heads) ----
    {
        bf16x8 fa[2];
#pragma unroll
        for (int kc = 0; kc < 2; ++kc)
            fa[kc] = *(const bf16x8*)&sZf[((kc * 4 + flane) * 32 + m * 16 + fm) * 8];
#pragma unroll
        for (int head = 0; head < 2; ++head) {
            const short* W1 = head ? W1r : W1f;
            const float* b1 = head ? rb1 : fb1;
            float* outp = head ? tmpR : tmpF;
            f32x4 acc[4] = {z4, z4, z4, z4};
#pragma unroll
            for (int j = 0; j < 4; ++j) {
                int nt = nb + 2 * j;
#pragma unroll
                for (int kc = 0; kc < 2; ++kc) {
                    bf16x8 fb = *(const bf16x8*)&W1[(size_t)((kc * 4 + flane) * 128 + nt * 16 + fm) * 8];
                    acc[j] = __builtin_amdgcn_mfma_f32_16x16x32_bf16(fa[kc], fb, acc[j], 0, 0, 0);
                }
            }
#pragma unroll
            for (int j = 0; j < 4; ++j) {
                int col = (nb + 2 * j) * 16 + fm;
                float bias = b1[col];
#pragma unroll
                for (int r = 0; r < 4; ++r) {
                    int row = m * 16 + flane * 4 + r;
                    size_t gi = (size_t)(r0 + row) * E_ + col;
                    float v = acc[j][r] + bias;
                    v = (v > 0.0f) ? v : 0.01f * v;
                    outp[gi] = v + h[gi];
                }
            }
        }
    }
}

// ---------------- K_out_mfma: out[b,d,n] = tmp @ W2 + b2 --------------------
// A = pre-packed bf16 W2 frags (global). B = tmp (fp32->bf16 LDS staging).
__global__ __launch_bounds__(256) void k_out_mfma(
    const float* __restrict__ tmp, const short* __restrict__ Wpack,
    const float* __restrict__ b2, float* __restrict__ out, int Dout) {
    __shared__ __align__(16) short sB[4 * 4 * 64 * 8];  // [kc][g][ncol][8]
    const int r0 = blockIdx.x * 64;
    const int d0 = blockIdx.y * 64;
    const int b = r0 >> 9, nbase = r0 & 511;
    const int tid = threadIdx.x, lane = tid & 63, wave = tid >> 6;
    const int fm = lane & 15, fg = lane >> 4;
    const int col = tid & 63, sg = tid >> 6;
#pragma unroll
    for (int kc = 0; kc < 4; ++kc) {
        float4 b0 = *(const float4*)&tmp[(size_t)(r0 + col) * E_ + kc * 32 + sg * 4];
        float4 b1 = *(const float4*)&tmp[(size_t)(r0 + col) * E_ + kc * 32 + 16 + sg * 4];
        uint4 v;
        v.x = f2bf2(b0.x, b0.y); v.y = f2bf2(b0.z, b0.w);
        v.z = f2bf2(b1.x, b1.y); v.w = f2bf2(b1.z, b1.w);
        *(uint4*)&sB[((kc * 4 + sg) * 64 + col) * 8] = v;
    }
    __syncthreads();
    const f32x4 zv = {0.f, 0.f, 0.f, 0.f};
    f32x4 acc[4] = {zv, zv, zv, zv};
#pragma unroll
    for (int kc = 0; kc < 4; ++kc) {
        bf16x8 fa = *(const bf16x8*)&Wpack[(size_t)((kc * 4 + fg) * Dout + d0 + wave * 16 + fm) * 8];
#pragma unroll
        for (int nt = 0; nt < 4; ++nt) {
            bf16x8 fb = *(const bf16x8*)&sB[((kc * 4 + fg) * 64 + nt * 16 + fm) * 8];
            acc[nt] = __builtin_amdgcn_mfma_f32_16x16x32_bf16(fa, fb, acc[nt], 0, 0, 0);
        }
    }
#pragma unroll
    for (int r = 0; r < 4; ++r) {
        int d = d0 + wave * 16 + fg * 4 + r;
        float bb = b2[d];
#pragma unroll
        for (int nt = 0; nt < 4; ++nt) {
            int n = nbase + nt * 16 + fm;
            out[((size_t)b * Dout + d) * N_ + n] = acc[nt][r] + bb;
        }
    }
}

// ---------------- launch ----------------------------------------------------
extern "C" void kernel_launch(void* const* d_in, const int* in_sizes, int n_in,
                              void* d_out, int out_size, void* d_ws, size_t ws_size,
                              hipStream_t stream) {
    (void)in_sizes; (void)n_in; (void)out_size; (void)ws_size;
    const float* batch_x = (const float*)d_in[0];
    const float* time_x  = (const float*)d_in[1];
    const float* time_W  = (const float*)d_in[2];
    const float* time_b  = (const float*)d_in[3];
    const float* gate_W  = (const float*)d_in[4];
    const float* gate_b  = (const float*)d_in[5];
    const float* mu_t_W  = (const float*)d_in[6];
    const float* mu_t_b  = (const float*)d_in[7];
    const float* var_t_W = (const float*)d_in[8];
    const float* var_t_b = (const float*)d_in[9];
    const float* ser_W   = (const float*)d_in[10];
    const float* ser_b   = (const float*)d_in[11];
    const float* mu_h_W  = (const float*)d_in[12];
    const float* mu_h_b  = (const float*)d_in[13];
    const float* var_h_W = (const float*)d_in[14];
    const float* var_h_b = (const float*)d_in[15];
    const float* mlp_W   = (const float*)d_in[18];
    const float* mlp_b   = (const float*)d_in[19];
    const float* mu_ht_W = (const float*)d_in[20];
    const float* mu_ht_b = (const float*)d_in[21];
    const float* var_ht_W = (const float*)d_in[22];
    const float* var_ht_b = (const float*)d_in[23];
    const float* inf_W   = (const float*)d_in[24];
    const float* inf_b   = (const float*)d_in[25];
    const float* mu_zt_W = (const float*)d_in[26];
    const float* mu_zt_b = (const float*)d_in[27];
    const float* var_zt_W = (const float*)d_in[28];
    const float* var_zt_b = (const float*)d_in[29];
    const float* fW1 = (const float*)d_in[30];
    const float* fb1 = (const float*)d_in[31];
    const float* fW2 = (const float*)d_in[32];
    const float* fb2 = (const float*)d_in[33];
    const float* rW1 = (const float*)d_in[34];
    const float* rb1 = (const float*)d_in[35];
    const float* rW2 = (const float*)d_in[36];
    const float* rb2 = (const float*)d_in[37];

    float* out = (float*)d_out;
    float* ws = (float*)d_ws;

    // ws layout (floats):
    const size_t off_pool = 1048576;   // bf16 frag pool (336KB) in [1M,2M)
    const size_t off_t    = 2097152;   // t; overlaid by tmpF (row-disjoint safe)
    const size_t off_tmpF = 2097152;
    const size_t off_h    = 4194304;
    const size_t off_hh   = 6291456;   // hh; overlaid by tmpR
    const size_t off_tmpR = 6291456;
    const size_t off_csum = 8388608;

    short* pool = (short*)(ws + off_pool);

    // out layout (floats): x, y, mu_t, var_t, mu_zt, var_zt, mu_z, var_z
    float* o_x     = out;
    float* o_y     = out + 8388608;
    float* o_mu_t  = out + 11534336;
    float* o_var_t = out + 12582912;
    float* o_mu_zt = out + 13631488;
    float* o_var_zt= out + 14680064;
    float* o_mu_z  = out + 15728640;
    float* o_var_z = out + 16777216;

    uint32_t kz1a, kz1b, kz2a, kz2b;
    tf2x32(0u, 42u, 0u, 0u, kz1a, kz1b);
    tf2x32(0u, 42u, 0u, 1u, kz2a, kz2b);

    PrepSrcs S;
    S.p[0] = mu_t_W;  S.p[1] = var_t_W;
    S.p[2] = mu_h_W;  S.p[3] = var_h_W; S.p[4] = mu_ht_W; S.p[5] = var_ht_W;
    S.p[6] = inf_W;   S.p[7] = mu_zt_W; S.p[8] = var_zt_W;
    S.p[9] = fW1;     S.p[10] = rW1;    S.p[11] = fW2;    S.p[12] = rW2;

    k_colsum<<<1, 128, 0, stream>>>(mu_ht_W, var_ht_W, ws + off_csum);
    k_prep<<<dim3(256, 13), 256, 0, stream>>>(S, pool);
    k_gate_mfma<<<dim3(16, B_), 256, 0, stream>>>(time_x, time_W, time_b,
                                                  gate_W, gate_b,
                                                  batch_x, ser_W, ser_b,
                                                  ws + off_t, ws + off_h, ws + off_hh);
    k_mega2<<<512, 256, 0, stream>>>(ws + off_t, ws + off_hh, ws + off_h, pool,
                                     mu_t_b, var_t_b, mu_h_b, var_h_b,
                                     mu_ht_b, var_ht_b, mlp_W, mlp_b,
                                     ws + off_csum, inf_b, mu_zt_b, var_zt_b,
                                     fb1, rb1,
                                     o_mu_t, o_var_t, o_mu_z, o_var_z,
                                     o_mu_zt, o_var_zt,
                                     ws + off_tmpF, ws + off_tmpR,
                                     kz1a, kz1b, kz2a, kz2b);
    k_out_mfma<<<dim3(256, HP_ / 64), 256, 0, stream>>>(ws + off_tmpF, pool + PO_W2F,
                                                        fb2, o_y, HP_);
    k_out_mfma<<<dim3(256, L_ / 64), 256, 0, stream>>>(ws + off_tmpR, pool + PO_W2R,
                                                       rb2, o_x, L_);
}

// Round 5
// 245.107 us; speedup vs baseline: 1.8584x; 1.0720x over previous
//
#include <hip/hip_runtime.h>
#include <cstdint>
#include <cstddef>

#define B_ 32
#define L_ 512
#define HP_ 192
#define N_ 512
#define E_ 128
#define Z_ 64

typedef short bf16x8 __attribute__((ext_vector_type(8)));
typedef float f32x4 __attribute__((ext_vector_type(4)));

// ---------------- threefry2x32 (JAX-compatible) ----------------
__host__ __device__ __forceinline__ uint32_t rotl32(uint32_t v, int r) {
    return (v << r) | (v >> (32 - r));
}

__host__ __device__ __forceinline__ void tf2x32(uint32_t k0, uint32_t k1,
                                                uint32_t c0, uint32_t c1,
                                                uint32_t& o0, uint32_t& o1) {
    uint32_t ks2 = k0 ^ k1 ^ 0x1BD11BDAu;
    uint32_t x0 = c0 + k0, x1 = c1 + k1;
    x0 += x1; x1 = rotl32(x1, 13); x1 ^= x0;
    x0 += x1; x1 = rotl32(x1, 15); x1 ^= x0;
    x0 += x1; x1 = rotl32(x1, 26); x1 ^= x0;
    x0 += x1; x1 = rotl32(x1, 6);  x1 ^= x0;
    x0 += k1; x1 += ks2 + 1u;
    x0 += x1; x1 = rotl32(x1, 17); x1 ^= x0;
    x0 += x1; x1 = rotl32(x1, 29); x1 ^= x0;
    x0 += x1; x1 = rotl32(x1, 16); x1 ^= x0;
    x0 += x1; x1 = rotl32(x1, 24); x1 ^= x0;
    x0 += ks2; x1 += k0 + 2u;
    x0 += x1; x1 = rotl32(x1, 13); x1 ^= x0;
    x0 += x1; x1 = rotl32(x1, 15); x1 ^= x0;
    x0 += x1; x1 = rotl32(x1, 26); x1 ^= x0;
    x0 += x1; x1 = rotl32(x1, 6);  x1 ^= x0;
    x0 += k0; x1 += k1 + 3u;
    x0 += x1; x1 = rotl32(x1, 17); x1 ^= x0;
    x0 += x1; x1 = rotl32(x1, 29); x1 ^= x0;
    x0 += x1; x1 = rotl32(x1, 16); x1 ^= x0;
    x0 += x1; x1 = rotl32(x1, 24); x1 ^= x0;
    x0 += k1; x1 += ks2 + 4u;
    x0 += x1; x1 = rotl32(x1, 13); x1 ^= x0;
    x0 += x1; x1 = rotl32(x1, 15); x1 ^= x0;
    x0 += x1; x1 = rotl32(x1, 26); x1 ^= x0;
    x0 += x1; x1 = rotl32(x1, 6);  x1 ^= x0;
    x0 += ks2; x1 += k0 + 5u;
    o0 = x0; o1 = x1;
}

// XLA ErfInv32 (Giles polynomial)
__device__ __forceinline__ float erfinv_f(float x) {
    float w = -log1pf(-x * x);
    float p;
    if (w < 5.0f) {
        w = w - 2.5f;
        p = 2.81022636e-08f;
        p = fmaf(p, w, 3.43273939e-07f);
        p = fmaf(p, w, -3.5233877e-06f);
        p = fmaf(p, w, -4.39150654e-06f);
        p = fmaf(p, w, 0.00021858087f);
        p = fmaf(p, w, -0.00125372503f);
        p = fmaf(p, w, -0.00417768164f);
        p = fmaf(p, w, 0.246640727f);
        p = fmaf(p, w, 1.50140941f);
    } else {
        w = sqrtf(w) - 3.0f;
        p = -0.000200214257f;
        p = fmaf(p, w, 0.000100950558f);
        p = fmaf(p, w, 0.00134934322f);
        p = fmaf(p, w, -0.00367342844f);
        p = fmaf(p, w, 0.00573950773f);
        p = fmaf(p, w, -0.0076224613f);
        p = fmaf(p, w, 0.00943887047f);
        p = fmaf(p, w, 1.00167406f);
        p = fmaf(p, w, 2.83297682f);
    }
    return p * x;
}

__device__ __forceinline__ float bits_to_normal(uint32_t bits) {
    float f = __uint_as_float((bits >> 9) | 0x3f800000u) - 1.0f;  // [0,1)
    const float lo = -0.99999994f;
    float u = fmaxf(lo, f * 2.0f + lo);
    return 1.41421354f * erfinv_f(u);
}

// fp32 -> bf16 (RNE), packed helpers
__device__ __forceinline__ uint32_t f2bf1(float x) {
    uint32_t u = __float_as_uint(x);
    return (u + 0x7fffu + ((u >> 16) & 1u)) >> 16;
}
__device__ __forceinline__ uint32_t f2bf2(float lo, float hi) {
    return f2bf1(lo) | (f2bf1(hi) << 16);
}

union U4BF8 { uint4 u; bf16x8 v; };

// bf16 frag pool offsets (shorts)
#define PO_WT   0        // [128][128]  mu_t|var_t
#define PO_WH   16384    // [128][256]  mu_h|var_h|mu_ht|var_ht
#define PO_WI   49152    // [64][64]    inf_W
#define PO_WZZ  53248    // [64][128]   mu_zt|var_zt
#define PO_W1F  61440    // [64][128]   fW1
#define PO_W1R  69632    // [64][128]   rW1
#define PO_W2F  77824    // [128][192]  fW2
#define PO_W2R  102400   // [128][512]  rW2

struct PrepSrcs { const float* p[13]; };

// pack fp32 weight [K][Ns] into bf16 MFMA B-frag layout
__global__ void k_prep(PrepSrcs S, short* pool) {
    static const int Kt[13]  = {128,128,128,128,128,128,64,64,64,64,64,128,128};
    static const int Nst[13] = {64,64,64,64,64,64,64,64,64,128,128,192,512};
    static const int Ndt[13] = {128,128,256,256,256,256,64,128,128,128,128,192,512};
    static const int c0t[13] = {0,64,0,64,128,192,0,0,64,0,0,0,0};
    static const int offt[13]= {PO_WT,PO_WT,PO_WH,PO_WH,PO_WH,PO_WH,PO_WI,
                                PO_WZZ,PO_WZZ,PO_W1F,PO_W1R,PO_W2F,PO_W2R};
    int j = blockIdx.y;
    int Ns = Nst[j];
    int total = Kt[j] * Ns;
    int idx = blockIdx.x * 256 + threadIdx.x;
    if (idx >= total) return;
    int k = idx / Ns, nc = idx - k * Ns;
    float v = S.p[j][idx];
    int kc = k >> 5, k32 = k & 31;
    int fg = (k32 >> 2) & 3, e = (k32 & 3) + ((k32 >> 4) << 2);
    pool[offt[j] + (size_t)((kc * 4 + fg) * Ndt[j] + c0t[j] + nc) * 8 + e] = (short)f2bf1(v);
}

// ---------------- K_pack: gate operand prep (gW/sW/t0 frags + colsum) -------
// mode 0: gW [512][512] -> A-frags [nt16][kc16][fg4][n32][8]
// mode 1: sW [512][128] -> B-frags [kc16][fg4][e128][8]
// mode 2: t0 = tx@tW+tb computed + packed -> B-frags per b [b][kc][fg][e][8]
// mode 3: colsum
__global__ void k_pack(const float* __restrict__ gW, const float* __restrict__ sW,
                       const float* __restrict__ tx, const float* __restrict__ tW,
                       const float* __restrict__ tb,
                       const float* __restrict__ mW, const float* __restrict__ vW,
                       short* __restrict__ gfp, short* __restrict__ swp,
                       short* __restrict__ t0p, float* __restrict__ csum) {
    int mode = blockIdx.y;
    int idx = blockIdx.x * 256 + threadIdx.x;
    if (mode == 0) {
        if (idx >= 32768) return;            // (kc*4+fg)*512 + n
        int n = idx & 511, r = idx >> 9;
        int kc = r >> 2, fg = r & 3;
        int lb = kc * 32 + fg * 4;
        float v[8];
#pragma unroll
        for (int j = 0; j < 8; ++j)
            v[j] = gW[(size_t)(lb + (j & 3) + ((j >> 2) << 4)) * N_ + n];
        U4BF8 u;
        u.u.x = f2bf2(v[0], v[1]); u.u.y = f2bf2(v[2], v[3]);
        u.u.z = f2bf2(v[4], v[5]); u.u.w = f2bf2(v[6], v[7]);
        *(uint4*)&gfp[(size_t)((((n >> 5) * 16 + kc) * 4 + fg) * 32 + (n & 31)) * 8] = u.u;
    } else if (mode == 1) {
        if (idx >= 8192) return;             // (kc*4+fg)*128 + e
        int e = idx & 127, r = idx >> 7;
        int kc = r >> 2, fg = r & 3;
        int lb = kc * 32 + fg * 4;
        float v[8];
#pragma unroll
        for (int j = 0; j < 8; ++j)
            v[j] = sW[(size_t)(lb + (j & 3) + ((j >> 2) << 4)) * E_ + e];
        U4BF8 u;
        u.u.x = f2bf2(v[0], v[1]); u.u.y = f2bf2(v[2], v[3]);
        u.u.z = f2bf2(v[4], v[5]); u.u.w = f2bf2(v[6], v[7]);
        *(uint4*)&swp[(size_t)(r * 128 + e) * 8] = u.u;
    } else if (mode == 2) {
        if (idx >= 262144) return;           // r2*128 + e ; r2 = b*64+kc*4+fg
        int e = idx & 127, r2 = idx >> 7;
        int b = r2 >> 6, kf = r2 & 63;
        int kc = kf >> 2, fg = kf & 3;
        int lb = kc * 32 + fg * 4;
        float tbe = tb[e];
        float twc[7];
#pragma unroll
        for (int k = 0; k < 7; ++k) twc[k] = tW[k * E_ + e];
        float v[8];
#pragma unroll
        for (int j = 0; j < 8; ++j) {
            int l = lb + (j & 3) + ((j >> 2) << 4);
            const float* txr = &tx[((size_t)b * L_ + l) * 7];
            float a = tbe;
#pragma unroll
            for (int k = 0; k < 7; ++k) a = fmaf(txr[k], twc[k], a);
            v[j] = a;
        }
        U4BF8 u;
        u.u.x = f2bf2(v[0], v[1]); u.u.y = f2bf2(v[2], v[3]);
        u.u.z = f2bf2(v[4], v[5]); u.u.w = f2bf2(v[6], v[7]);
        *(uint4*)&t0p[(size_t)(r2 * 128 + e) * 8] = u.u;
    } else {
        if (idx >= 128) return;
        const float* W = (idx < 64) ? mW : vW;
        int zc = idx & 63;
        float s = 0.0f;
        for (int e = 0; e < E_; ++e) s += W[e * Z_ + zc];
        csum[idx] = s;
    }
}

// ---------------- K_gate4: barrier-free MFMA gate+series GEMMs --------------
// grid (16 ntile, 2 ehalf, 32 b), 256 thr = 4 waves (2m x 2e), no LDS.
__global__ __launch_bounds__(256) void k_gate4(
    const float* __restrict__ bx,
    const short* __restrict__ gfp, const short* __restrict__ swp,
    const short* __restrict__ t0p,
    const float* __restrict__ gb, const float* __restrict__ sb,
    float* __restrict__ t, float* __restrict__ h, float* __restrict__ hh) {
    const int ntile = blockIdx.x, eh = blockIdx.y, b = blockIdx.z;
    const int tid = threadIdx.x, lane = tid & 63, wv = tid >> 6;
    const int mw = wv & 1, ew = wv >> 1;
    const int fm = lane & 15, fl = lane >> 4;
    const int n0 = ntile * 32;
    const int e0 = eh * 64 + ew * 32;
    const int n = n0 + mw * 16 + fm;
    const float* bxp = &bx[(size_t)b * L_ * N_ + n];

    const f32x4 z4 = {0.f, 0.f, 0.f, 0.f};
    f32x4 accT[2] = {z4, z4}, accH[2] = {z4, z4};

    for (int kc = 0; kc < 16; ++kc) {
        // batch_x A-frag: gather 8 rows (l) at fixed n, cvt to bf16
        int lb = kc * 32 + fl * 4;
        float xv[8];
#pragma unroll
        for (int j = 0; j < 8; ++j)
            xv[j] = bxp[(size_t)(lb + (j & 3) + ((j >> 2) << 4)) * N_];
        U4BF8 ux;
        ux.u.x = f2bf2(xv[0], xv[1]); ux.u.y = f2bf2(xv[2], xv[3]);
        ux.u.z = f2bf2(xv[4], xv[5]); ux.u.w = f2bf2(xv[6], xv[7]);
        bf16x8 fbx = ux.v;
        bf16x8 fgw = *(const bf16x8*)&gfp[(size_t)(((ntile * 16 + kc) * 4 + fl) * 32 + mw * 16 + fm) * 8];
#pragma unroll
        for (int nt = 0; nt < 2; ++nt) {
            int ec = e0 + nt * 16 + fm;
            bf16x8 ft = *(const bf16x8*)&t0p[(size_t)(((b * 16 + kc) * 4 + fl) * 128 + ec) * 8];
            bf16x8 fs = *(const bf16x8*)&swp[(size_t)((kc * 4 + fl) * 128 + ec) * 8];
            accT[nt] = __builtin_amdgcn_mfma_f32_16x16x32_bf16(fgw, ft, accT[nt], 0, 0, 0);
            accH[nt] = __builtin_amdgcn_mfma_f32_16x16x32_bf16(fbx, fs, accH[nt], 0, 0, 0);
        }
    }
    // epilogue: row = n0 + mw*16 + fl*4 + r ; col = e
    float gbn[4];
#pragma unroll
    for (int r = 0; r < 4; ++r) gbn[r] = gb[n0 + mw * 16 + fl * 4 + r];
#pragma unroll
    for (int nt = 0; nt < 2; ++nt) {
        int e = e0 + nt * 16 + fm;
        float sbe = sb[e];
#pragma unroll
        for (int r = 0; r < 4; ++r) {
            int nr = n0 + mw * 16 + fl * 4 + r;
            size_t base = ((size_t)b * N_ + nr) * E_ + e;
            float tv = accT[nt][r] + gbn[r];
            float hv = accH[nt][r] + sbe;
            t[base] = tv; h[base] = hv; hh[base] = tv + hv;
        }
    }
}

// ---------------- K_mega2: MFMA projection chain + reparam + tmp fusion -----
__global__ __launch_bounds__(256) void k_mega2(
    const float* __restrict__ T, const float* __restrict__ HH,
    const float* __restrict__ h,
    const short* __restrict__ pool,
    const float* __restrict__ bmt_, const float* __restrict__ bvt_,
    const float* __restrict__ bmh, const float* __restrict__ bvh,
    const float* __restrict__ bmht, const float* __restrict__ bvht,
    const float* __restrict__ mlpW, const float* __restrict__ mlpb,
    const float* __restrict__ csum,
    const float* __restrict__ ib,
    const float* __restrict__ mzb, const float* __restrict__ vzb,
    const float* __restrict__ fb1, const float* __restrict__ rb1,
    float* __restrict__ Omt, float* __restrict__ Ovt,
    float* __restrict__ Omz, float* __restrict__ Ovz,
    float* __restrict__ Omzt, float* __restrict__ Ovzt,
    float* __restrict__ tmpF, float* __restrict__ tmpR,
    uint32_t k1a, uint32_t k1b, uint32_t k2a, uint32_t k2b) {
    __shared__ __align__(16) short sAT[4 * 4 * 32 * 8];
    __shared__ __align__(16) short sAH[4 * 4 * 32 * 8];
    __shared__ __align__(16) short sZf[2 * 4 * 32 * 8];
    __shared__ __align__(16) short sZTf[2 * 4 * 32 * 8];
    __shared__ float sOut[32][260];

    const short* Wt  = pool + PO_WT;
    const short* Wh  = pool + PO_WH;
    const short* Wi  = pool + PO_WI;
    const short* Wzz = pool + PO_WZZ;
    const short* W1f = pool + PO_W1F;
    const short* W1r = pool + PO_W1R;

    const int r0 = blockIdx.x * 32;
    const int tid = threadIdx.x;
    const int lane = tid & 63, wv = tid >> 6;
    const int fm = lane & 15, flane = lane >> 4;
    const int m = wv & 1, nb = wv >> 1;
    const f32x4 z4 = {0.f, 0.f, 0.f, 0.f};

#pragma unroll
    for (int it = 0; it < 4; ++it) {
        int idx = tid + it * 256;
        int row = idx >> 5, c4 = idx & 31;
        int k0 = c4 * 4;
        int kc = k0 >> 5, k32 = k0 & 31;
        int fg = (k32 >> 2) & 3, e0 = (k32 >= 16) ? 4 : 0;
        int base = ((kc * 4 + fg) * 32 + row) * 8 + e0;
        float4 v = *(const float4*)&T[(size_t)(r0 + row) * E_ + k0];
        uint2 u; u.x = f2bf2(v.x, v.y); u.y = f2bf2(v.z, v.w);
        *(uint2*)&sAT[base] = u;
        float4 w = *(const float4*)&HH[(size_t)(r0 + row) * E_ + k0];
        uint2 p; p.x = f2bf2(w.x, w.y); p.y = f2bf2(w.z, w.w);
        *(uint2*)&sAH[base] = p;
    }
    __syncthreads();

    // ---- G1: T x Wt -> mu_t | var_t ----
    {
        bf16x8 fa[4];
#pragma unroll
        for (int kc = 0; kc < 4; ++kc)
            fa[kc] = *(const bf16x8*)&sAT[((kc * 4 + flane) * 32 + m * 16 + fm) * 8];
        f32x4 acc[4] = {z4, z4, z4, z4};
#pragma unroll
        for (int j = 0; j < 4; ++j) {
            int nt = nb + 2 * j;
#pragma unroll
            for (int kc = 0; kc < 4; ++kc) {
                bf16x8 fb = *(const bf16x8*)&Wt[(size_t)((kc * 4 + flane) * 128 + nt * 16 + fm) * 8];
                acc[j] = __builtin_amdgcn_mfma_f32_16x16x32_bf16(fa[kc], fb, acc[j], 0, 0, 0);
            }
        }
#pragma unroll
        for (int j = 0; j < 4; ++j) {
            int ncol = (nb + 2 * j) * 16 + fm;
            float* dst = (ncol < 64) ? Omt : Ovt;
            int zc = ncol & 63;
            float bias = (ncol < 64) ? bmt_[zc] : bvt_[zc];
#pragma unroll
            for (int r = 0; r < 4; ++r) {
                int row = m * 16 + flane * 4 + r;
                dst[(size_t)(r0 + row) * Z_ + zc] = acc[j][r] + bias;
            }
        }
    }

    // ---- G2: HH x Wh -> sOut ----
    {
        bf16x8 fa[4];
#pragma unroll
        for (int kc = 0; kc < 4; ++kc)
            fa[kc] = *(const bf16x8*)&sAH[((kc * 4 + flane) * 32 + m * 16 + fm) * 8];
        f32x4 acc[8] = {z4, z4, z4, z4, z4, z4, z4, z4};
#pragma unroll
        for (int j = 0; j < 8; ++j) {
            int nt = nb + 2 * j;
#pragma unroll
            for (int kc = 0; kc < 4; ++kc) {
                bf16x8 fb = *(const bf16x8*)&Wh[(size_t)((kc * 4 + flane) * 256 + nt * 16 + fm) * 8];
                acc[j] = __builtin_amdgcn_mfma_f32_16x16x32_bf16(fa[kc], fb, acc[j], 0, 0, 0);
            }
        }
#pragma unroll
        for (int j = 0; j < 8; ++j) {
            int ncol = (nb + 2 * j) * 16 + fm;
#pragma unroll
            for (int r = 0; r < 4; ++r)
                sOut[m * 16 + flane * 4 + r][ncol] = acc[j][r];
        }
    }
    __syncthreads();

    // ---- Phase B: reparam + blend ----
    {
        float w0 = mlpW[0], b0 = mlpb[0];
        int row = tid >> 3;
        int zc0 = (tid & 7) * 8;
        int r = r0 + row;
        float zm[8], zvv[8];
        uint32_t zb[8];
#pragma unroll
        for (int j = 0; j < 8; ++j) {
            int zc = zc0 + j;
            float m1 = sOut[row][zc] + bmh[zc];
            float v1 = sOut[row][64 + zc] + bvh[zc];
            float m2 = fmaf(w0, sOut[row][128 + zc], fmaf(b0, csum[zc], bmht[zc]));
            float v2 = fmaf(w0, sOut[row][192 + zc], fmaf(b0, csum[64 + zc], bvht[zc]));
            uint32_t flat = (uint32_t)r * 64u + (uint32_t)zc;
            uint32_t o0, o1;
            tf2x32(k1a, k1b, 0u, flat, o0, o1);
            float e1 = bits_to_normal(o0 ^ o1);
            tf2x32(k2a, k2b, 0u, flat, o0, o1);
            float e2 = bits_to_normal(o0 ^ o1);
            float zh = m1 + e1 * expf(0.5f * v1);
            float zt = m2 + e2 * expf(0.5f * v2);
            float zval = 0.5f * (zh + zt);
            zb[j] = f2bf1(zval);
            zm[j] = 0.5f * (m1 + m2);
            zvv[j] = 0.5f * (v1 + v2);
        }
        size_t base = (size_t)r * Z_ + zc0;
        *(float4*)&Omz[base]     = make_float4(zm[0], zm[1], zm[2], zm[3]);
        *(float4*)&Omz[base + 4] = make_float4(zm[4], zm[5], zm[6], zm[7]);
        *(float4*)&Ovz[base]     = make_float4(zvv[0], zvv[1], zvv[2], zvv[3]);
        *(float4*)&Ovz[base + 4] = make_float4(zvv[4], zvv[5], zvv[6], zvv[7]);
        int kc = zc0 >> 5, z32 = zc0 & 31;
        int fgA = (z32 >> 2) & 3, eA = (z32 >= 16) ? 4 : 0;
        uint2 u;
        u.x = zb[0] | (zb[1] << 16); u.y = zb[2] | (zb[3] << 16);
        *(uint2*)&sZf[((kc * 4 + fgA) * 32 + row) * 8 + eA] = u;
        u.x = zb[4] | (zb[5] << 16); u.y = zb[6] | (zb[7] << 16);
        *(uint2*)&sZf[((kc * 4 + fgA + 1) * 32 + row) * 8 + eA] = u;
    }
    __syncthreads();

    // ---- G3: z x Wi -> zt frags ----
    {
        bf16x8 fa[2];
#pragma unroll
        for (int kc = 0; kc < 2; ++kc)
            fa[kc] = *(const bf16x8*)&sZf[((kc * 4 + flane) * 32 + m * 16 + fm) * 8];
        f32x4 acc[2] = {z4, z4};
#pragma unroll
        for (int j = 0; j < 2; ++j) {
            int nt = nb + 2 * j;
#pragma unroll
            for (int kc = 0; kc < 2; ++kc) {
                bf16x8 fb = *(const bf16x8*)&Wi[(size_t)((kc * 4 + flane) * 64 + nt * 16 + fm) * 8];
                acc[j] = __builtin_amdgcn_mfma_f32_16x16x32_bf16(fa[kc], fb, acc[j], 0, 0, 0);
            }
        }
#pragma unroll
        for (int j = 0; j < 2; ++j) {
            int col = (nb + 2 * j) * 16 + fm;
            float bias = ib[col];
            int kc2 = col >> 5, c32 = col & 31;
            int fg2 = (c32 >> 2) & 3, e2 = (c32 & 3) + ((c32 >> 4) << 2);
#pragma unroll
            for (int r = 0; r < 4; ++r) {
                int row2 = m * 16 + flane * 4 + r;
                sZTf[((kc2 * 4 + fg2) * 32 + row2) * 8 + e2] = (short)f2bf1(acc[j][r] + bias);
            }
        }
    }
    __syncthreads();

    // ---- G4: zt x Wzz -> mu_zt | var_zt ----
    {
        bf16x8 fa[2];
#pragma unroll
        for (int kc = 0; kc < 2; ++kc)
            fa[kc] = *(const bf16x8*)&sZTf[((kc * 4 + flane) * 32 + m * 16 + fm) * 8];
        f32x4 acc[4] = {z4, z4, z4, z4};
#pragma unroll
        for (int j = 0; j < 4; ++j) {
            int nt = nb + 2 * j;
#pragma unroll
            for (int kc = 0; kc < 2; ++kc) {
                bf16x8 fb = *(const bf16x8*)&Wzz[(size_t)((kc * 4 + flane) * 128 + nt * 16 + fm) * 8];
                acc[j] = __builtin_amdgcn_mfma_f32_16x16x32_bf16(fa[kc], fb, acc[j], 0, 0, 0);
            }
        }
#pragma unroll
        for (int j = 0; j < 4; ++j) {
            int ncol = (nb + 2 * j) * 16 + fm;
            float* dst = (ncol < 64) ? Omzt : Ovzt;
            int zc = ncol & 63;
            float bias = (ncol < 64) ? mzb[zc] : vzb[zc];
#pragma unroll
            for (int r = 0; r < 4; ++r) {
                int row = m * 16 + flane * 4 + r;
                dst[(size_t)(r0 + row) * Z_ + zc] = acc[j][r] + bias;
            }
        }
    }

    // ---- G5/G6: tmp = leaky(z @ W1 + b1) + h ----
    {
        bf16x8 fa[2];
#pragma unroll
        for (int kc = 0; kc < 2; ++kc)
            fa[kc] = *(const bf16x8*)&sZf[((kc * 4 + flane) * 32 + m * 16 + fm) * 8];
#pragma unroll
        for (int head = 0; head < 2; ++head) {
            const short* W1 = head ? W1r : W1f;
            const float* b1 = head ? rb1 : fb1;
            float* outp = head ? tmpR : tmpF;
            f32x4 acc[4] = {z4, z4, z4, z4};
#pragma unroll
            for (int j = 0; j < 4; ++j) {
                int nt = nb + 2 * j;
#pragma unroll
                for (int kc = 0; kc < 2; ++kc) {
                    bf16x8 fb = *(const bf16x8*)&W1[(size_t)((kc * 4 + flane) * 128 + nt * 16 + fm) * 8];
                    acc[j] = __builtin_amdgcn_mfma_f32_16x16x32_bf16(fa[kc], fb, acc[j], 0, 0, 0);
                }
            }
#pragma unroll
            for (int j = 0; j < 4; ++j) {
                int col = (nb + 2 * j) * 16 + fm;
                float bias = b1[col];
#pragma unroll
                for (int r = 0; r < 4; ++r) {
                    int row = m * 16 + flane * 4 + r;
                    size_t gi = (size_t)(r0 + row) * E_ + col;
                    float v = acc[j][r] + bias;
                    v = (v > 0.0f) ? v : 0.01f * v;
                    outp[gi] = v + h[gi];
                }
            }
        }
    }
}

// ---------------- K_out_mfma ------------------------------------------------
__global__ __launch_bounds__(256) void k_out_mfma(
    const float* __restrict__ tmp, const short* __restrict__ Wpack,
    const float* __restrict__ b2, float* __restrict__ out, int Dout) {
    __shared__ __align__(16) short sB[4 * 4 * 64 * 8];
    const int r0 = blockIdx.x * 64;
    const int d0 = blockIdx.y * 64;
    const int b = r0 >> 9, nbase = r0 & 511;
    const int tid = threadIdx.x, lane = tid & 63, wave = tid >> 6;
    const int fm = lane & 15, fg = lane >> 4;
    const int col = tid & 63, sg = tid >> 6;
#pragma unroll
    for (int kc = 0; kc < 4; ++kc) {
        float4 b0 = *(const float4*)&tmp[(size_t)(r0 + col) * E_ + kc * 32 + sg * 4];
        float4 b1 = *(const float4*)&tmp[(size_t)(r0 + col) * E_ + kc * 32 + 16 + sg * 4];
        uint4 v;
        v.x = f2bf2(b0.x, b0.y); v.y = f2bf2(b0.z, b0.w);
        v.z = f2bf2(b1.x, b1.y); v.w = f2bf2(b1.z, b1.w);
        *(uint4*)&sB[((kc * 4 + sg) * 64 + col) * 8] = v;
    }
    __syncthreads();
    const f32x4 zv = {0.f, 0.f, 0.f, 0.f};
    f32x4 acc[4] = {zv, zv, zv, zv};
#pragma unroll
    for (int kc = 0; kc < 4; ++kc) {
        bf16x8 fa = *(const bf16x8*)&Wpack[(size_t)((kc * 4 + fg) * Dout + d0 + wave * 16 + fm) * 8];
#pragma unroll
        for (int nt = 0; nt < 4; ++nt) {
            bf16x8 fb = *(const bf16x8*)&sB[((kc * 4 + fg) * 64 + nt * 16 + fm) * 8];
            acc[nt] = __builtin_amdgcn_mfma_f32_16x16x32_bf16(fa, fb, acc[nt], 0, 0, 0);
        }
    }
#pragma unroll
    for (int r = 0; r < 4; ++r) {
        int d = d0 + wave * 16 + fg * 4 + r;
        float bb = b2[d];
#pragma unroll
        for (int nt = 0; nt < 4; ++nt) {
            int n = nbase + nt * 16 + fm;
            out[((size_t)b * Dout + d) * N_ + n] = acc[nt][r] + bb;
        }
    }
}

// ---------------- launch ----------------------------------------------------
extern "C" void kernel_launch(void* const* d_in, const int* in_sizes, int n_in,
                              void* d_out, int out_size, void* d_ws, size_t ws_size,
                              hipStream_t stream) {
    (void)in_sizes; (void)n_in; (void)out_size; (void)ws_size;
    const float* batch_x = (const float*)d_in[0];
    const float* time_x  = (const float*)d_in[1];
    const float* time_W  = (const float*)d_in[2];
    const float* time_b  = (const float*)d_in[3];
    const float* gate_W  = (const float*)d_in[4];
    const float* gate_b  = (const float*)d_in[5];
    const float* mu_t_W  = (const float*)d_in[6];
    const float* mu_t_b  = (const float*)d_in[7];
    const float* var_t_W = (const float*)d_in[8];
    const float* var_t_b = (const float*)d_in[9];
    const float* ser_W   = (const float*)d_in[10];
    const float* ser_b   = (const float*)d_in[11];
    const float* mu_h_W  = (const float*)d_in[12];
    const float* mu_h_b  = (const float*)d_in[13];
    const float* var_h_W = (const float*)d_in[14];
    const float* var_h_b = (const float*)d_in[15];
    const float* mlp_W   = (const float*)d_in[18];
    const float* mlp_b   = (const float*)d_in[19];
    const float* mu_ht_W = (const float*)d_in[20];
    const float* mu_ht_b = (const float*)d_in[21];
    const float* var_ht_W = (const float*)d_in[22];
    const float* var_ht_b = (const float*)d_in[23];
    const float* inf_W   = (const float*)d_in[24];
    const float* inf_b   = (const float*)d_in[25];
    const float* mu_zt_W = (const float*)d_in[26];
    const float* mu_zt_b = (const float*)d_in[27];
    const float* var_zt_W = (const float*)d_in[28];
    const float* var_zt_b = (const float*)d_in[29];
    const float* fW1 = (const float*)d_in[30];
    const float* fb1 = (const float*)d_in[31];
    const float* fW2 = (const float*)d_in[32];
    const float* fb2 = (const float*)d_in[33];
    const float* rW1 = (const float*)d_in[34];
    const float* rb1 = (const float*)d_in[35];
    const float* rW2 = (const float*)d_in[36];
    const float* rb2 = (const float*)d_in[37];

    float* out = (float*)d_out;
    float* ws = (float*)d_ws;

    // ws layout (floats):
    const size_t off_t0p  = 0;         // t0 B-frags: 2M shorts = 1M floats
    const size_t off_pool = 1048576;   // weight frag pool (~84K floats)
    const size_t off_gfp  = 1245184;   // gW A-frags: 262144 shorts = 128K floats
    const size_t off_swp  = 1376256;   // sW B-frags: 65536 shorts = 32K floats
    const size_t off_t    = 2097152;   // t; overlaid by tmpF
    const size_t off_tmpF = 2097152;
    const size_t off_h    = 4194304;
    const size_t off_hh   = 6291456;   // hh; overlaid by tmpR
    const size_t off_tmpR = 6291456;
    const size_t off_csum = 8388608;

    short* pool = (short*)(ws + off_pool);
    short* gfp  = (short*)(ws + off_gfp);
    short* swp  = (short*)(ws + off_swp);
    short* t0p  = (short*)(ws + off_t0p);

    // out layout (floats): x, y, mu_t, var_t, mu_zt, var_zt, mu_z, var_z
    float* o_x     = out;
    float* o_y     = out + 8388608;
    float* o_mu_t  = out + 11534336;
    float* o_var_t = out + 12582912;
    float* o_mu_zt = out + 13631488;
    float* o_var_zt= out + 14680064;
    float* o_mu_z  = out + 15728640;
    float* o_var_z = out + 16777216;

    uint32_t kz1a, kz1b, kz2a, kz2b;
    tf2x32(0u, 42u, 0u, 0u, kz1a, kz1b);
    tf2x32(0u, 42u, 0u, 1u, kz2a, kz2b);

    PrepSrcs S;
    S.p[0] = mu_t_W;  S.p[1] = var_t_W;
    S.p[2] = mu_h_W;  S.p[3] = var_h_W; S.p[4] = mu_ht_W; S.p[5] = var_ht_W;
    S.p[6] = inf_W;   S.p[7] = mu_zt_W; S.p[8] = var_zt_W;
    S.p[9] = fW1;     S.p[10] = rW1;    S.p[11] = fW2;    S.p[12] = rW2;

    k_prep<<<dim3(256, 13), 256, 0, stream>>>(S, pool);
    k_pack<<<dim3(1024, 4), 256, 0, stream>>>(gate_W, ser_W, time_x, time_W, time_b,
                                              mu_ht_W, var_ht_W,
                                              gfp, swp, t0p, ws + off_csum);
    k_gate4<<<dim3(16, 2, B_), 256, 0, stream>>>(batch_x, gfp, swp, t0p,
                                                 gate_b, ser_b,
                                                 ws + off_t, ws + off_h, ws + off_hh);
    k_mega2<<<512, 256, 0, stream>>>(ws + off_t, ws + off_hh, ws + off_h, pool,
                                     mu_t_b, var_t_b, mu_h_b, var_h_b,
                                     mu_ht_b, var_ht_b, mlp_W, mlp_b,
                                     ws + off_csum, inf_b, mu_zt_b, var_zt_b,
                                     fb1, rb1,
                                     o_mu_t, o_var_t, o_mu_z, o_var_z,
                                     o_mu_zt, o_var_zt,
                                     ws + off_tmpF, ws + off_tmpR,
                                     kz1a, kz1b, kz2a, kz2b);
    k_out_mfma<<<dim3(256, HP_ / 64), 256, 0, stream>>>(ws + off_tmpF, pool + PO_W2F,
                                                        fb2, o_y, HP_);
    k_out_mfma<<<dim3(256, L_ / 64), 256, 0, stream>>>(ws + off_tmpR, pool + PO_W2R,
                                                       rb2, o_x, L_);
}

// Round 7
// 243.538 us; speedup vs baseline: 1.8704x; 1.0064x over previous
//
#include <hip/hip_runtime.h>
#include <cstdint>
#include <cstddef>

#define B_ 32
#define L_ 512
#define HP_ 192
#define N_ 512
#define E_ 128
#define Z_ 64

typedef short bf16x8 __attribute__((ext_vector_type(8)));
typedef float f32x4 __attribute__((ext_vector_type(4)));

// ---------------- threefry2x32 (JAX-compatible) ----------------
__host__ __device__ __forceinline__ uint32_t rotl32(uint32_t v, int r) {
    return (v << r) | (v >> (32 - r));
}

__host__ __device__ __forceinline__ void tf2x32(uint32_t k0, uint32_t k1,
                                                uint32_t c0, uint32_t c1,
                                                uint32_t& o0, uint32_t& o1) {
    uint32_t ks2 = k0 ^ k1 ^ 0x1BD11BDAu;
    uint32_t x0 = c0 + k0, x1 = c1 + k1;
    x0 += x1; x1 = rotl32(x1, 13); x1 ^= x0;
    x0 += x1; x1 = rotl32(x1, 15); x1 ^= x0;
    x0 += x1; x1 = rotl32(x1, 26); x1 ^= x0;
    x0 += x1; x1 = rotl32(x1, 6);  x1 ^= x0;
    x0 += k1; x1 += ks2 + 1u;
    x0 += x1; x1 = rotl32(x1, 17); x1 ^= x0;
    x0 += x1; x1 = rotl32(x1, 29); x1 ^= x0;
    x0 += x1; x1 = rotl32(x1, 16); x1 ^= x0;
    x0 += x1; x1 = rotl32(x1, 24); x1 ^= x0;
    x0 += ks2; x1 += k0 + 2u;
    x0 += x1; x1 = rotl32(x1, 13); x1 ^= x0;
    x0 += x1; x1 = rotl32(x1, 15); x1 ^= x0;
    x0 += x1; x1 = rotl32(x1, 26); x1 ^= x0;
    x0 += x1; x1 = rotl32(x1, 6);  x1 ^= x0;
    x0 += k0; x1 += k1 + 3u;
    x0 += x1; x1 = rotl32(x1, 17); x1 ^= x0;
    x0 += x1; x1 = rotl32(x1, 29); x1 ^= x0;
    x0 += x1; x1 = rotl32(x1, 16); x1 ^= x0;
    x0 += x1; x1 = rotl32(x1, 24); x1 ^= x0;
    x0 += k1; x1 += ks2 + 4u;
    x0 += x1; x1 = rotl32(x1, 13); x1 ^= x0;
    x0 += x1; x1 = rotl32(x1, 15); x1 ^= x0;
    x0 += x1; x1 = rotl32(x1, 26); x1 ^= x0;
    x0 += x1; x1 = rotl32(x1, 6);  x1 ^= x0;
    x0 += ks2; x1 += k0 + 5u;
    o0 = x0; o1 = x1;
}

// XLA ErfInv32 (Giles polynomial)
__device__ __forceinline__ float erfinv_f(float x) {
    float w = -log1pf(-x * x);
    float p;
    if (w < 5.0f) {
        w = w - 2.5f;
        p = 2.81022636e-08f;
        p = fmaf(p, w, 3.43273939e-07f);
        p = fmaf(p, w, -3.5233877e-06f);
        p = fmaf(p, w, -4.39150654e-06f);
        p = fmaf(p, w, 0.00021858087f);
        p = fmaf(p, w, -0.00125372503f);
        p = fmaf(p, w, -0.00417768164f);
        p = fmaf(p, w, 0.246640727f);
        p = fmaf(p, w, 1.50140941f);
    } else {
        w = sqrtf(w) - 3.0f;
        p = -0.000200214257f;
        p = fmaf(p, w, 0.000100950558f);
        p = fmaf(p, w, 0.00134934322f);
        p = fmaf(p, w, -0.00367342844f);
        p = fmaf(p, w, 0.00573950773f);
        p = fmaf(p, w, -0.0076224613f);
        p = fmaf(p, w, 0.00943887047f);
        p = fmaf(p, w, 1.00167406f);
        p = fmaf(p, w, 2.83297682f);
    }
    return p * x;
}

__device__ __forceinline__ float bits_to_normal(uint32_t bits) {
    float f = __uint_as_float((bits >> 9) | 0x3f800000u) - 1.0f;  // [0,1)
    const float lo = -0.99999994f;
    float u = fmaxf(lo, f * 2.0f + lo);
    return 1.41421354f * erfinv_f(u);
}

// fp32 -> bf16 (RNE), packed helpers
__device__ __forceinline__ uint32_t f2bf1(float x) {
    uint32_t u = __float_as_uint(x);
    return (u + 0x7fffu + ((u >> 16) & 1u)) >> 16;
}
__device__ __forceinline__ uint32_t f2bf2(float lo, float hi) {
    return f2bf1(lo) | (f2bf1(hi) << 16);
}

union U4BF8 { uint4 u; bf16x8 v; };

// bf16 frag pool offsets (shorts)
#define PO_WT   0        // [128][128]  mu_t|var_t
#define PO_WH   16384    // [128][256]  mu_h|var_h|mu_ht|var_ht
#define PO_WI   49152    // [64][64]    inf_W
#define PO_WZZ  53248    // [64][128]   mu_zt|var_zt
#define PO_W1F  61440    // [64][128]   fW1
#define PO_W1R  69632    // [64][128]   rW1
#define PO_W2F  77824    // [128][192]  fW2
#define PO_W2R  102400   // [128][512]  rW2

struct PrepSrcs { const float* p[13]; };

// ---------------- K_pack: ALL operand prep (17 y-slices) --------------------
// y=0: gW A-frags; y=1: sW B-frags; y=2: t0 compute+pack; y=3: colsum;
// y=4..16: weight j=y-4 -> B-frag pool
__global__ void k_pack(PrepSrcs S, short* __restrict__ pool,
                       const float* __restrict__ gW, const float* __restrict__ sW,
                       const float* __restrict__ tx, const float* __restrict__ tW,
                       const float* __restrict__ tb,
                       const float* __restrict__ mW, const float* __restrict__ vW,
                       short* __restrict__ gfp, short* __restrict__ swp,
                       short* __restrict__ t0p, float* __restrict__ csum) {
    static const int Kt[13]  = {128,128,128,128,128,128,64,64,64,64,64,128,128};
    static const int Nst[13] = {64,64,64,64,64,64,64,64,64,128,128,192,512};
    static const int Ndt[13] = {128,128,256,256,256,256,64,128,128,128,128,192,512};
    static const int c0t[13] = {0,64,0,64,128,192,0,0,64,0,0,0,0};
    static const int offt[13]= {PO_WT,PO_WT,PO_WH,PO_WH,PO_WH,PO_WH,PO_WI,
                                PO_WZZ,PO_WZZ,PO_W1F,PO_W1R,PO_W2F,PO_W2R};
    int mode = blockIdx.y;
    int idx = blockIdx.x * 256 + threadIdx.x;
    if (mode == 0) {
        if (idx >= 32768) return;            // (kc*4+fg)*512 + n
        int n = idx & 511, r = idx >> 9;
        int kc = r >> 2, fg = r & 3;
        int lb = kc * 32 + fg * 4;
        float v[8];
#pragma unroll
        for (int j = 0; j < 8; ++j)
            v[j] = gW[(size_t)(lb + (j & 3) + ((j >> 2) << 4)) * N_ + n];
        U4BF8 u;
        u.u.x = f2bf2(v[0], v[1]); u.u.y = f2bf2(v[2], v[3]);
        u.u.z = f2bf2(v[4], v[5]); u.u.w = f2bf2(v[6], v[7]);
        *(uint4*)&gfp[(size_t)((((n >> 5) * 16 + kc) * 4 + fg) * 32 + (n & 31)) * 8] = u.u;
    } else if (mode == 1) {
        if (idx >= 8192) return;             // (kc*4+fg)*128 + e
        int e = idx & 127, r = idx >> 7;
        int kc = r >> 2, fg = r & 3;
        int lb = kc * 32 + fg * 4;
        float v[8];
#pragma unroll
        for (int j = 0; j < 8; ++j)
            v[j] = sW[(size_t)(lb + (j & 3) + ((j >> 2) << 4)) * E_ + e];
        U4BF8 u;
        u.u.x = f2bf2(v[0], v[1]); u.u.y = f2bf2(v[2], v[3]);
        u.u.z = f2bf2(v[4], v[5]); u.u.w = f2bf2(v[6], v[7]);
        *(uint4*)&swp[(size_t)(r * 128 + e) * 8] = u.u;
    } else if (mode == 2) {
        if (idx >= 262144) return;           // r2*128 + e ; r2 = b*64+kc*4+fg
        int e = idx & 127, r2 = idx >> 7;
        int b = r2 >> 6, kf = r2 & 63;
        int kc = kf >> 2, fg = kf & 3;
        int lb = kc * 32 + fg * 4;
        float tbe = tb[e];
        float twc[7];
#pragma unroll
        for (int k = 0; k < 7; ++k) twc[k] = tW[k * E_ + e];
        float v[8];
#pragma unroll
        for (int j = 0; j < 8; ++j) {
            int l = lb + (j & 3) + ((j >> 2) << 4);
            const float* txr = &tx[((size_t)b * L_ + l) * 7];
            float a = tbe;
#pragma unroll
            for (int k = 0; k < 7; ++k) a = fmaf(txr[k], twc[k], a);
            v[j] = a;
        }
        U4BF8 u;
        u.u.x = f2bf2(v[0], v[1]); u.u.y = f2bf2(v[2], v[3]);
        u.u.z = f2bf2(v[4], v[5]); u.u.w = f2bf2(v[6], v[7]);
        *(uint4*)&t0p[(size_t)(r2 * 128 + e) * 8] = u.u;
    } else if (mode == 3) {
        if (idx >= 128) return;
        const float* W = (idx < 64) ? mW : vW;
        int zc = idx & 63;
        float s = 0.0f;
        for (int e = 0; e < E_; ++e) s += W[e * Z_ + zc];
        csum[idx] = s;
    } else {
        int j = mode - 4;
        int Ns = Nst[j];
        int total = Kt[j] * Ns;
        if (idx >= total) return;
        int k = idx / Ns, nc = idx - k * Ns;
        float v = S.p[j][idx];
        int kc = k >> 5, k32 = k & 31;
        int fg = (k32 >> 2) & 3, e = (k32 & 3) + ((k32 >> 4) << 2);
        pool[offt[j] + (size_t)((kc * 4 + fg) * Ndt[j] + c0t[j] + nc) * 8 + e] = (short)f2bf1(v);
    }
}

// ---------------- K_gate4: barrier-free MFMA gate+series GEMMs --------------
__global__ __launch_bounds__(256) void k_gate4(
    const float* __restrict__ bx,
    const short* __restrict__ gfp, const short* __restrict__ swp,
    const short* __restrict__ t0p,
    const float* __restrict__ gb, const float* __restrict__ sb,
    float* __restrict__ t, float* __restrict__ h, float* __restrict__ hh) {
    const int ntile = blockIdx.x, eh = blockIdx.y, b = blockIdx.z;
    const int tid = threadIdx.x, lane = tid & 63, wv = tid >> 6;
    const int mw = wv & 1, ew = wv >> 1;
    const int fm = lane & 15, fl = lane >> 4;
    const int n0 = ntile * 32;
    const int e0 = eh * 64 + ew * 32;
    const int n = n0 + mw * 16 + fm;
    const float* bxp = &bx[(size_t)b * L_ * N_ + n];

    const f32x4 z4 = {0.f, 0.f, 0.f, 0.f};
    f32x4 accT[2] = {z4, z4}, accH[2] = {z4, z4};

    for (int kc = 0; kc < 16; ++kc) {
        int lb = kc * 32 + fl * 4;
        float xv[8];
#pragma unroll
        for (int j = 0; j < 8; ++j)
            xv[j] = bxp[(size_t)(lb + (j & 3) + ((j >> 2) << 4)) * N_];
        U4BF8 ux;
        ux.u.x = f2bf2(xv[0], xv[1]); ux.u.y = f2bf2(xv[2], xv[3]);
        ux.u.z = f2bf2(xv[4], xv[5]); ux.u.w = f2bf2(xv[6], xv[7]);
        bf16x8 fbx = ux.v;
        bf16x8 fgw = *(const bf16x8*)&gfp[(size_t)(((ntile * 16 + kc) * 4 + fl) * 32 + mw * 16 + fm) * 8];
#pragma unroll
        for (int nt = 0; nt < 2; ++nt) {
            int ec = e0 + nt * 16 + fm;
            bf16x8 ft = *(const bf16x8*)&t0p[(size_t)(((b * 16 + kc) * 4 + fl) * 128 + ec) * 8];
            bf16x8 fs = *(const bf16x8*)&swp[(size_t)((kc * 4 + fl) * 128 + ec) * 8];
            accT[nt] = __builtin_amdgcn_mfma_f32_16x16x32_bf16(fgw, ft, accT[nt], 0, 0, 0);
            accH[nt] = __builtin_amdgcn_mfma_f32_16x16x32_bf16(fbx, fs, accH[nt], 0, 0, 0);
        }
    }
    float gbn[4];
#pragma unroll
    for (int r = 0; r < 4; ++r) gbn[r] = gb[n0 + mw * 16 + fl * 4 + r];
#pragma unroll
    for (int nt = 0; nt < 2; ++nt) {
        int e = e0 + nt * 16 + fm;
        float sbe = sb[e];
#pragma unroll
        for (int r = 0; r < 4; ++r) {
            int nr = n0 + mw * 16 + fl * 4 + r;
            size_t base = ((size_t)b * N_ + nr) * E_ + e;
            float tv = accT[nt][r] + gbn[r];
            float hv = accH[nt][r] + sbe;
            t[base] = tv; h[base] = hv; hh[base] = tv + hv;
        }
    }
}

// ---------------- K_mega3: projection chain + reparam + W1 + W2 heads -------
__global__ __launch_bounds__(256) void k_mega3(
    const float* __restrict__ T, const float* __restrict__ HH,
    const float* __restrict__ h,
    const short* __restrict__ pool,
    const float* __restrict__ bmt_, const float* __restrict__ bvt_,
    const float* __restrict__ bmh, const float* __restrict__ bvh,
    const float* __restrict__ bmht, const float* __restrict__ bvht,
    const float* __restrict__ mlpW, const float* __restrict__ mlpb,
    const float* __restrict__ csum,
    const float* __restrict__ ib,
    const float* __restrict__ mzb, const float* __restrict__ vzb,
    const float* __restrict__ fb1, const float* __restrict__ rb1,
    const float* __restrict__ fb2, const float* __restrict__ rb2,
    float* __restrict__ Omt, float* __restrict__ Ovt,
    float* __restrict__ Omz, float* __restrict__ Ovz,
    float* __restrict__ Omzt, float* __restrict__ Ovzt,
    float* __restrict__ Oy, float* __restrict__ Ox,
    uint32_t k1a, uint32_t k1b, uint32_t k2a, uint32_t k2b) {
    __shared__ __align__(16) short sAT[4 * 4 * 32 * 8];
    __shared__ __align__(16) short sAH[4 * 4 * 32 * 8];
    __shared__ __align__(16) short sZf[2 * 4 * 32 * 8];
    __shared__ __align__(16) short sZTf[2 * 4 * 32 * 8];
    __shared__ __align__(16) float sOut[32][260];   // dead after Phase B; aliased by sTmp
    short* sTmp = (short*)&sOut[0][0];              // [kc4][fg4][ncol32][8] bf16

    const short* Wt  = pool + PO_WT;
    const short* Wh  = pool + PO_WH;
    const short* Wi  = pool + PO_WI;
    const short* Wzz = pool + PO_WZZ;
    const short* W1f = pool + PO_W1F;
    const short* W1r = pool + PO_W1R;
    const short* W2f = pool + PO_W2F;
    const short* W2r = pool + PO_W2R;

    const int r0 = blockIdx.x * 32;
    const int bb = r0 >> 9, nbase = r0 & 511;
    const int tid = threadIdx.x;
    const int lane = tid & 63, wv = tid >> 6;
    const int fm = lane & 15, flane = lane >> 4;
    const int m = wv & 1, nb = wv >> 1;
    const f32x4 z4 = {0.f, 0.f, 0.f, 0.f};

#pragma unroll
    for (int it = 0; it < 4; ++it) {
        int idx = tid + it * 256;
        int row = idx >> 5, c4 = idx & 31;
        int k0 = c4 * 4;
        int kc = k0 >> 5, k32 = k0 & 31;
        int fg = (k32 >> 2) & 3, e0 = (k32 >= 16) ? 4 : 0;
        int base = ((kc * 4 + fg) * 32 + row) * 8 + e0;
        float4 v = *(const float4*)&T[(size_t)(r0 + row) * E_ + k0];
        uint2 u; u.x = f2bf2(v.x, v.y); u.y = f2bf2(v.z, v.w);
        *(uint2*)&sAT[base] = u;
        float4 w = *(const float4*)&HH[(size_t)(r0 + row) * E_ + k0];
        uint2 p; p.x = f2bf2(w.x, w.y); p.y = f2bf2(w.z, w.w);
        *(uint2*)&sAH[base] = p;
    }
    __syncthreads();

    // ---- G1: T x Wt -> mu_t | var_t ----
    {
        bf16x8 fa[4];
#pragma unroll
        for (int kc = 0; kc < 4; ++kc)
            fa[kc] = *(const bf16x8*)&sAT[((kc * 4 + flane) * 32 + m * 16 + fm) * 8];
        f32x4 acc[4] = {z4, z4, z4, z4};
#pragma unroll
        for (int j = 0; j < 4; ++j) {
            int nt = nb + 2 * j;
#pragma unroll
            for (int kc = 0; kc < 4; ++kc) {
                bf16x8 fb = *(const bf16x8*)&Wt[(size_t)((kc * 4 + flane) * 128 + nt * 16 + fm) * 8];
                acc[j] = __builtin_amdgcn_mfma_f32_16x16x32_bf16(fa[kc], fb, acc[j], 0, 0, 0);
            }
        }
#pragma unroll
        for (int j = 0; j < 4; ++j) {
            int ncol = (nb + 2 * j) * 16 + fm;
            float* dst = (ncol < 64) ? Omt : Ovt;
            int zc = ncol & 63;
            float bias = (ncol < 64) ? bmt_[zc] : bvt_[zc];
#pragma unroll
            for (int r = 0; r < 4; ++r) {
                int row = m * 16 + flane * 4 + r;
                dst[(size_t)(r0 + row) * Z_ + zc] = acc[j][r] + bias;
            }
        }
    }

    // ---- G2: HH x Wh -> sOut ----
    {
        bf16x8 fa[4];
#pragma unroll
        for (int kc = 0; kc < 4; ++kc)
            fa[kc] = *(const bf16x8*)&sAH[((kc * 4 + flane) * 32 + m * 16 + fm) * 8];
        f32x4 acc[8] = {z4, z4, z4, z4, z4, z4, z4, z4};
#pragma unroll
        for (int j = 0; j < 8; ++j) {
            int nt = nb + 2 * j;
#pragma unroll
            for (int kc = 0; kc < 4; ++kc) {
                bf16x8 fb = *(const bf16x8*)&Wh[(size_t)((kc * 4 + flane) * 256 + nt * 16 + fm) * 8];
                acc[j] = __builtin_amdgcn_mfma_f32_16x16x32_bf16(fa[kc], fb, acc[j], 0, 0, 0);
            }
        }
#pragma unroll
        for (int j = 0; j < 8; ++j) {
            int ncol = (nb + 2 * j) * 16 + fm;
#pragma unroll
            for (int r = 0; r < 4; ++r)
                sOut[m * 16 + flane * 4 + r][ncol] = acc[j][r];
        }
    }
    __syncthreads();

    // ---- Phase B: reparam + blend ----
    {
        float w0 = mlpW[0], b0 = mlpb[0];
        int row = tid >> 3;
        int zc0 = (tid & 7) * 8;
        int r = r0 + row;
        float zm[8], zvv[8];
        uint32_t zb[8];
#pragma unroll
        for (int j = 0; j < 8; ++j) {
            int zc = zc0 + j;
            float m1 = sOut[row][zc] + bmh[zc];
            float v1 = sOut[row][64 + zc] + bvh[zc];
            float m2 = fmaf(w0, sOut[row][128 + zc], fmaf(b0, csum[zc], bmht[zc]));
            float v2 = fmaf(w0, sOut[row][192 + zc], fmaf(b0, csum[64 + zc], bvht[zc]));
            uint32_t flat = (uint32_t)r * 64u + (uint32_t)zc;
            uint32_t o0, o1;
            tf2x32(k1a, k1b, 0u, flat, o0, o1);
            float e1 = bits_to_normal(o0 ^ o1);
            tf2x32(k2a, k2b, 0u, flat, o0, o1);
            float e2 = bits_to_normal(o0 ^ o1);
            float zh = m1 + e1 * expf(0.5f * v1);
            float zt = m2 + e2 * expf(0.5f * v2);
            float zval = 0.5f * (zh + zt);
            zb[j] = f2bf1(zval);
            zm[j] = 0.5f * (m1 + m2);
            zvv[j] = 0.5f * (v1 + v2);
        }
        __syncthreads();   // all sOut reads done before sZf write (and later sTmp alias)
        size_t base = (size_t)r * Z_ + zc0;
        *(float4*)&Omz[base]     = make_float4(zm[0], zm[1], zm[2], zm[3]);
        *(float4*)&Omz[base + 4] = make_float4(zm[4], zm[5], zm[6], zm[7]);
        *(float4*)&Ovz[base]     = make_float4(zvv[0], zvv[1], zvv[2], zvv[3]);
        *(float4*)&Ovz[base + 4] = make_float4(zvv[4], zvv[5], zvv[6], zvv[7]);
        int kc = zc0 >> 5, z32 = zc0 & 31;
        int fgA = (z32 >> 2) & 3, eA = (z32 >= 16) ? 4 : 0;
        uint2 u;
        u.x = zb[0] | (zb[1] << 16); u.y = zb[2] | (zb[3] << 16);
        *(uint2*)&sZf[((kc * 4 + fgA) * 32 + row) * 8 + eA] = u;
        u.x = zb[4] | (zb[5] << 16); u.y = zb[6] | (zb[7] << 16);
        *(uint2*)&sZf[((kc * 4 + fgA + 1) * 32 + row) * 8 + eA] = u;
    }
    __syncthreads();

    // ---- G3: z x Wi -> zt frags ----
    {
        bf16x8 fa[2];
#pragma unroll
        for (int kc = 0; kc < 2; ++kc)
            fa[kc] = *(const bf16x8*)&sZf[((kc * 4 + flane) * 32 + m * 16 + fm) * 8];
        f32x4 acc[2] = {z4, z4};
#pragma unroll
        for (int j = 0; j < 2; ++j) {
            int nt = nb + 2 * j;
#pragma unroll
            for (int kc = 0; kc < 2; ++kc) {
                bf16x8 fb = *(const bf16x8*)&Wi[(size_t)((kc * 4 + flane) * 64 + nt * 16 + fm) * 8];
                acc[j] = __builtin_amdgcn_mfma_f32_16x16x32_bf16(fa[kc], fb, acc[j], 0, 0, 0);
            }
        }
#pragma unroll
        for (int j = 0; j < 2; ++j) {
            int col = (nb + 2 * j) * 16 + fm;
            float bias = ib[col];
            int kc2 = col >> 5, c32 = col & 31;
            int fg2 = (c32 >> 2) & 3, e2 = (c32 & 3) + ((c32 >> 4) << 2);
#pragma unroll
            for (int r = 0; r < 4; ++r) {
                int row2 = m * 16 + flane * 4 + r;
                sZTf[((kc2 * 4 + fg2) * 32 + row2) * 8 + e2] = (short)f2bf1(acc[j][r] + bias);
            }
        }
    }
    __syncthreads();

    // ---- G4: zt x Wzz -> mu_zt | var_zt ----
    {
        bf16x8 fa[2];
#pragma unroll
        for (int kc = 0; kc < 2; ++kc)
            fa[kc] = *(const bf16x8*)&sZTf[((kc * 4 + flane) * 32 + m * 16 + fm) * 8];
        f32x4 acc[4] = {z4, z4, z4, z4};
#pragma unroll
        for (int j = 0; j < 4; ++j) {
            int nt = nb + 2 * j;
#pragma unroll
            for (int kc = 0; kc < 2; ++kc) {
                bf16x8 fb = *(const bf16x8*)&Wzz[(size_t)((kc * 4 + flane) * 128 + nt * 16 + fm) * 8];
                acc[j] = __builtin_amdgcn_mfma_f32_16x16x32_bf16(fa[kc], fb, acc[j], 0, 0, 0);
            }
        }
#pragma unroll
        for (int j = 0; j < 4; ++j) {
            int ncol = (nb + 2 * j) * 16 + fm;
            float* dst = (ncol < 64) ? Omzt : Ovzt;
            int zc = ncol & 63;
            float bias = (ncol < 64) ? mzb[zc] : vzb[zc];
#pragma unroll
            for (int r = 0; r < 4; ++r) {
                int row = m * 16 + flane * 4 + r;
                dst[(size_t)(r0 + row) * Z_ + zc] = acc[j][r] + bias;
            }
        }
    }

    // ---- G5 + W2: both heads, tmp kept in LDS frags ----
    {
        bf16x8 fa[2];
#pragma unroll
        for (int kc = 0; kc < 2; ++kc)
            fa[kc] = *(const bf16x8*)&sZf[((kc * 4 + flane) * 32 + m * 16 + fm) * 8];

        // ===== head 0 (f -> y, Dout=192) =====
        {
            f32x4 acc[4] = {z4, z4, z4, z4};
#pragma unroll
            for (int j = 0; j < 4; ++j) {
                int nt = nb + 2 * j;
#pragma unroll
                for (int kc = 0; kc < 2; ++kc) {
                    bf16x8 fb = *(const bf16x8*)&W1f[(size_t)((kc * 4 + flane) * 128 + nt * 16 + fm) * 8];
                    acc[j] = __builtin_amdgcn_mfma_f32_16x16x32_bf16(fa[kc], fb, acc[j], 0, 0, 0);
                }
            }
            // pack tmp = leaky(acc+b1)+h into sTmp B-frags (kc=j, fg=fm>>2, elem=(fm&3)+4*nb)
#pragma unroll
            for (int j = 0; j < 4; ++j) {
                int col = (nb + 2 * j) * 16 + fm;
                float bias = fb1[col];
#pragma unroll
                for (int r = 0; r < 4; ++r) {
                    int row = m * 16 + flane * 4 + r;
                    float v = acc[j][r] + bias;
                    v = (v > 0.0f) ? v : 0.01f * v;
                    v += h[(size_t)(r0 + row) * E_ + col];
                    sTmp[((j * 4 + (fm >> 2)) * 32 + row) * 8 + (fm & 3) + 4 * nb] = (short)f2bf1(v);
                }
            }
        }
        __syncthreads();
        {   // W2-y: wave wv owns d range [wv*48, wv*48+48)
            int d0w = wv * 48;
#pragma unroll
            for (int ntile = 0; ntile < 2; ++ntile) {
                f32x4 acc2[3] = {z4, z4, z4};
#pragma unroll
                for (int dt = 0; dt < 3; ++dt)
#pragma unroll
                    for (int kc = 0; kc < 4; ++kc) {
                        bf16x8 fA = *(const bf16x8*)&W2f[(size_t)((kc * 4 + flane) * HP_ + d0w + dt * 16 + fm) * 8];
                        bf16x8 fB = *(const bf16x8*)&sTmp[((kc * 4 + flane) * 32 + ntile * 16 + fm) * 8];
                        acc2[dt] = __builtin_amdgcn_mfma_f32_16x16x32_bf16(fA, fB, acc2[dt], 0, 0, 0);
                    }
#pragma unroll
                for (int dt = 0; dt < 3; ++dt)
#pragma unroll
                    for (int r = 0; r < 4; ++r) {
                        int d = d0w + dt * 16 + flane * 4 + r;
                        Oy[((size_t)bb * HP_ + d) * N_ + nbase + ntile * 16 + fm] = acc2[dt][r] + fb2[d];
                    }
            }
        }
        __syncthreads();

        // ===== head 1 (r -> x, Dout=512) =====
        {
            f32x4 acc[4] = {z4, z4, z4, z4};
#pragma unroll
            for (int j = 0; j < 4; ++j) {
                int nt = nb + 2 * j;
#pragma unroll
                for (int kc = 0; kc < 2; ++kc) {
                    bf16x8 fb = *(const bf16x8*)&W1r[(size_t)((kc * 4 + flane) * 128 + nt * 16 + fm) * 8];
                    acc[j] = __builtin_amdgcn_mfma_f32_16x16x32_bf16(fa[kc], fb, acc[j], 0, 0, 0);
                }
            }
#pragma unroll
            for (int j = 0; j < 4; ++j) {
                int col = (nb + 2 * j) * 16 + fm;
                float bias = rb1[col];
#pragma unroll
                for (int r = 0; r < 4; ++r) {
                    int row = m * 16 + flane * 4 + r;
                    float v = acc[j][r] + bias;
                    v = (v > 0.0f) ? v : 0.01f * v;
                    v += h[(size_t)(r0 + row) * E_ + col];
                    sTmp[((j * 4 + (fm >> 2)) * 32 + row) * 8 + (fm & 3) + 4 * nb] = (short)f2bf1(v);
                }
            }
        }
        __syncthreads();
        {   // W2-x: wave wv owns d range [wv*128, wv*128+128)
            int d0w = wv * 128;
#pragma unroll
            for (int ntile = 0; ntile < 2; ++ntile) {
                f32x4 acc2[8] = {z4, z4, z4, z4, z4, z4, z4, z4};
#pragma unroll
                for (int dt = 0; dt < 8; ++dt)
#pragma unroll
                    for (int kc = 0; kc < 4; ++kc) {
                        bf16x8 fA = *(const bf16x8*)&W2r[(size_t)((kc * 4 + flane) * L_ + d0w + dt * 16 + fm) * 8];
                        bf16x8 fB = *(const bf16x8*)&sTmp[((kc * 4 + flane) * 32 + ntile * 16 + fm) * 8];
                        acc2[dt] = __builtin_amdgcn_mfma_f32_16x16x32_bf16(fA, fB, acc2[dt], 0, 0, 0);
                    }
#pragma unroll
                for (int dt = 0; dt < 8; ++dt)
#pragma unroll
                    for (int r = 0; r < 4; ++r) {
                        int d = d0w + dt * 16 + flane * 4 + r;
                        Ox[((size_t)bb * L_ + d) * N_ + nbase + ntile * 16 + fm] = acc2[dt][r] + rb2[d];
                    }
            }
        }
    }
}

// ---------------- launch ----------------------------------------------------
extern "C" void kernel_launch(void* const* d_in, const int* in_sizes, int n_in,
                              void* d_out, int out_size, void* d_ws, size_t ws_size,
                              hipStream_t stream) {
    (void)in_sizes; (void)n_in; (void)out_size; (void)ws_size;
    const float* batch_x = (const float*)d_in[0];
    const float* time_x  = (const float*)d_in[1];
    const float* time_W  = (const float*)d_in[2];
    const float* time_b  = (const float*)d_in[3];
    const float* gate_W  = (const float*)d_in[4];
    const float* gate_b  = (const float*)d_in[5];
    const float* mu_t_W  = (const float*)d_in[6];
    const float* mu_t_b  = (const float*)d_in[7];
    const float* var_t_W = (const float*)d_in[8];
    const float* var_t_b = (const float*)d_in[9];
    const float* ser_W   = (const float*)d_in[10];
    const float* ser_b   = (const float*)d_in[11];
    const float* mu_h_W  = (const float*)d_in[12];
    const float* mu_h_b  = (const float*)d_in[13];
    const float* var_h_W = (const float*)d_in[14];
    const float* var_h_b = (const float*)d_in[15];
    const float* mlp_W   = (const float*)d_in[18];
    const float* mlp_b   = (const float*)d_in[19];
    const float* mu_ht_W = (const float*)d_in[20];
    const float* mu_ht_b = (const float*)d_in[21];
    const float* var_ht_W = (const float*)d_in[22];
    const float* var_ht_b = (const float*)d_in[23];
    const float* inf_W   = (const float*)d_in[24];
    const float* inf_b   = (const float*)d_in[25];
    const float* mu_zt_W = (const float*)d_in[26];
    const float* mu_zt_b = (const float*)d_in[27];
    const float* var_zt_W = (const float*)d_in[28];
    const float* var_zt_b = (const float*)d_in[29];
    const float* fW1 = (const float*)d_in[30];
    const float* fb1 = (const float*)d_in[31];
    const float* fW2 = (const float*)d_in[32];
    const float* fb2 = (const float*)d_in[33];
    const float* rW1 = (const float*)d_in[34];
    const float* rb1 = (const float*)d_in[35];
    const float* rW2 = (const float*)d_in[36];
    const float* rb2 = (const float*)d_in[37];

    float* out = (float*)d_out;
    float* ws = (float*)d_ws;

    // ws layout (floats):
    const size_t off_t0p  = 0;         // t0 B-frags: 2M shorts = 1M floats
    const size_t off_pool = 1048576;   // weight frag pool (~84K floats)
    const size_t off_gfp  = 1245184;   // gW A-frags
    const size_t off_swp  = 1376256;   // sW B-frags
    const size_t off_t    = 2097152;
    const size_t off_h    = 4194304;
    const size_t off_hh   = 6291456;
    const size_t off_csum = 8388608;

    short* pool = (short*)(ws + off_pool);
    short* gfp  = (short*)(ws + off_gfp);
    short* swp  = (short*)(ws + off_swp);
    short* t0p  = (short*)(ws + off_t0p);

    // out layout (floats): x, y, mu_t, var_t, mu_zt, var_zt, mu_z, var_z
    float* o_x     = out;
    float* o_y     = out + 8388608;
    float* o_mu_t  = out + 11534336;
    float* o_var_t = out + 12582912;
    float* o_mu_zt = out + 13631488;
    float* o_var_zt= out + 14680064;
    float* o_mu_z  = out + 15728640;
    float* o_var_z = out + 16777216;

    uint32_t kz1a, kz1b, kz2a, kz2b;
    tf2x32(0u, 42u, 0u, 0u, kz1a, kz1b);
    tf2x32(0u, 42u, 0u, 1u, kz2a, kz2b);

    PrepSrcs S;
    S.p[0] = mu_t_W;  S.p[1] = var_t_W;
    S.p[2] = mu_h_W;  S.p[3] = var_h_W; S.p[4] = mu_ht_W; S.p[5] = var_ht_W;
    S.p[6] = inf_W;   S.p[7] = mu_zt_W; S.p[8] = var_zt_W;
    S.p[9] = fW1;     S.p[10] = rW1;    S.p[11] = fW2;    S.p[12] = rW2;

    k_pack<<<dim3(1024, 17), 256, 0, stream>>>(S, pool, gate_W, ser_W,
                                               time_x, time_W, time_b,
                                               mu_ht_W, var_ht_W,
                                               gfp, swp, t0p, ws + off_csum);
    k_gate4<<<dim3(16, 2, B_), 256, 0, stream>>>(batch_x, gfp, swp, t0p,
                                                 gate_b, ser_b,
                                                 ws + off_t, ws + off_h, ws + off_hh);
    k_mega3<<<512, 256, 0, stream>>>(ws + off_t, ws + off_hh, ws + off_h, pool,
                                     mu_t_b, var_t_b, mu_h_b, var_h_b,
                                     mu_ht_b, var_ht_b, mlp_W, mlp_b,
                                     ws + off_csum, inf_b, mu_zt_b, var_zt_b,
                                     fb1, rb1, fb2, rb2,
                                     o_mu_t, o_var_t, o_mu_z, o_var_z,
                                     o_mu_zt, o_var_zt,
                                     o_y, o_x,
                                     kz1a, kz1b, kz2a, kz2b);
}